// Round 2
// 2198.784 us; speedup vs baseline: 1.7298x; 1.7298x over previous
//
#include <hip/hip_runtime.h>
#include <math.h>

#define Bdim 4
#define Tdim 1024
#define Ddim 1024
#define Hdim 16
#define DHdim 64
#define FFNdim 4096
#define KSEL 256
#define EPSf 1e-6f

typedef __attribute__((ext_vector_type(8))) short bf16x8;   // 8 bf16 = 4 VGPR
typedef __attribute__((ext_vector_type(4))) float f32x4;
typedef __attribute__((ext_vector_type(4))) unsigned int u32x4;

#define MFMA_BF16(a,b,c) __builtin_amdgcn_mfma_f32_16x16x32_bf16(a,b,c,0,0,0)

__device__ __forceinline__ int clamp_row(int r){ return r < 0 ? 0 : (r > Tdim-1 ? Tdim-1 : r); }

// split 8 fp32 into bf16 hi (truncate) + bf16 lo (exact remainder, truncated).
// hi+lo carries ~16 mantissa bits; dropped lo*lo term in the 3-mfma product is ~2^-16 rel.
__device__ __forceinline__ void split8(const float* xs, u32x4* hi, u32x4* lo){
  unsigned int hm[8], lm[8];
  #pragma unroll
  for (int i=0;i<8;i++){
    unsigned int b = __float_as_uint(xs[i]);
    hm[i] = b & 0xFFFF0000u;
    lm[i] = __float_as_uint(xs[i] - __uint_as_float(hm[i]));
  }
  u32x4 h, l;
  #pragma unroll
  for (int i=0;i<4;i++){
    h[i] = (hm[2*i] >> 16) | hm[2*i+1];
    l[i] = (lm[2*i] >> 16) | (lm[2*i+1] & 0xFFFF0000u);
  }
  *hi = h; *lo = l;
}

// ---------------- fallback (diagnostic): out = hidden ----------------
__global__ void k_fallback(const float* __restrict__ in, float* __restrict__ out, int n){
  int i = blockIdx.x*blockDim.x + threadIdx.x;
  if (i < n) out[i] = in[i];
}

__global__ void k_init_sel(int* __restrict__ selidx, float* __restrict__ selsc, int n){
  int i = blockIdx.x*blockDim.x + threadIdx.x;
  if (i < n){ selidx[i] = i & (KSEL-1); selsc[i] = 0.f; }
}

// ---------------- rmsnorm ----------------
__global__ __launch_bounds__(256) void k_rmsnorm(const float* __restrict__ x, const float* __restrict__ w,
                          float* __restrict__ y){
  int tok = blockIdx.x;
  const float* xp = x + (size_t)tok*Ddim;
  float* yp = y + (size_t)tok*Ddim;
  int tid = threadIdx.x;
  float s = 0.f;
  float xv[4];
  #pragma unroll
  for (int u = 0; u < 4; u++){ xv[u] = xp[tid + 256*u]; s += xv[u]*xv[u]; }
  __shared__ float red[256];
  red[tid]=s; __syncthreads();
  for (int st=128; st>0; st>>=1){ if (tid<st) red[tid]+=red[tid+st]; __syncthreads(); }
  float r = 1.0f/sqrtf(red[0]/(float)Ddim + EPSf);
  #pragma unroll
  for (int u = 0; u < 4; u++) yp[tid + 256*u] = xv[u]*r*w[tid + 256*u];
}

// rope in-place on (b,S,H,64); posidx==nullptr -> pos=t else pos=posidx[b*S+t]
__global__ void k_rope(float* __restrict__ x, const int* __restrict__ posidx, int S, int n){
  int e = blockIdx.x*blockDim.x + threadIdx.x;
  if (e >= n) return;
  int j = e & 31;
  int q = e >> 9;
  int t = q % S;
  float pos = posidx ? (float)clamp_row(posidx[q]) : (float)t;
  // 10000^(-j/32) = exp2(-j * log2(10000)/32)
  float inv = exp2f(-0.4152410118609203f * (float)j);
  float ang = pos * inv;
  float c = cosf(ang), s = sinf(ang);
  size_t base = ((size_t)(e >> 5)) * 64;
  float x1 = x[base + j], x2 = x[base + 32 + j];
  x[base + j]      = x1*c - x2*s;
  x[base + 32 + j] = x2*c + x1*s;
}

// ---------------- flash-style tiled attention (fp32, unchanged) ----------------
__global__ __launch_bounds__(256) void k_attn_tile(const float* __restrict__ q, const float* __restrict__ k,
                       const float* __restrict__ v, float* __restrict__ o, int S){
  int qt = blockIdx.x, h = blockIdx.y, b = blockIdx.z;
  int q0 = qt*64;
  int tid = threadIdx.x;
  int tr = tid >> 4, tc = tid & 15;
  __shared__ float qs[64][65];
  __shared__ float ks[64][65];
  __shared__ float vs[64][65];
  #pragma unroll
  for (int i = 0; i < 16; i++){
    int idx = tid + 256*i;
    int r = idx >> 6, c = idx & 63;
    qs[r][c] = q[(((size_t)b*S + q0 + r)*Hdim + h)*64 + c];
  }
  float m_i[4], l_i[4], acc[4][4];
  #pragma unroll
  for (int ii=0; ii<4; ii++){
    m_i[ii] = -3.4e38f; l_i[ii] = 0.f;
    #pragma unroll
    for (int jj=0; jj<4; jj++) acc[ii][jj] = 0.f;
  }
  for (int j0 = 0; j0 <= q0; j0 += 64){
    __syncthreads();
    #pragma unroll
    for (int i = 0; i < 16; i++){
      int idx = tid + 256*i;
      int r = idx >> 6, c = idx & 63;
      size_t g = (((size_t)b*S + j0 + r)*Hdim + h)*64 + c;
      ks[r][c] = k[g];
      vs[r][c] = v[g];
    }
    __syncthreads();
    float s[4][4];
    #pragma unroll
    for (int ii=0;ii<4;ii++)
      #pragma unroll
      for (int jj=0;jj<4;jj++) s[ii][jj]=0.f;
    for (int d=0; d<64; d++){
      float a[4], bb[4];
      #pragma unroll
      for (int ii=0;ii<4;ii++) a[ii]=qs[4*tr+ii][d];
      #pragma unroll
      for (int jj=0;jj<4;jj++) bb[jj]=ks[4*tc+jj][d];
      #pragma unroll
      for (int ii=0;ii<4;ii++)
        #pragma unroll
        for (int jj=0;jj<4;jj++) s[ii][jj] += a[ii]*bb[jj];
    }
    #pragma unroll
    for (int ii=0;ii<4;ii++)
      #pragma unroll
      for (int jj=0;jj<4;jj++){
        s[ii][jj] *= 0.125f;
        if (j0 + 4*tc + jj > q0 + 4*tr + ii) s[ii][jj] = -3.4e38f;
      }
    float rm[4];
    #pragma unroll
    for (int ii=0;ii<4;ii++){
      rm[ii] = fmaxf(fmaxf(s[ii][0],s[ii][1]), fmaxf(s[ii][2],s[ii][3]));
      for (int off=1; off<16; off<<=1) rm[ii] = fmaxf(rm[ii], __shfl_xor(rm[ii], off));
    }
    float p[4][4], rs[4];
    #pragma unroll
    for (int ii=0;ii<4;ii++){
      float m_new = fmaxf(m_i[ii], rm[ii]);
      float alpha = expf(m_i[ii] - m_new);
      rs[ii] = 0.f;
      #pragma unroll
      for (int jj=0;jj<4;jj++){
        p[ii][jj] = expf(s[ii][jj] - m_new);
        rs[ii] += p[ii][jj];
      }
      for (int off=1; off<16; off<<=1) rs[ii] += __shfl_xor(rs[ii], off);
      l_i[ii] = l_i[ii]*alpha + rs[ii];
      m_i[ii] = m_new;
      #pragma unroll
      for (int jj=0;jj<4;jj++) acc[ii][jj] *= alpha;
    }
    __syncthreads();
    #pragma unroll
    for (int ii=0;ii<4;ii++)
      #pragma unroll
      for (int jj=0;jj<4;jj++) ks[4*tr+ii][4*tc+jj] = p[ii][jj];
    __syncthreads();
    for (int j=0;j<64;j++){
      float pv[4], vv[4];
      #pragma unroll
      for (int ii=0;ii<4;ii++) pv[ii]=ks[4*tr+ii][j];
      #pragma unroll
      for (int jj=0;jj<4;jj++) vv[jj]=vs[j][4*tc+jj];
      #pragma unroll
      for (int ii=0;ii<4;ii++)
        #pragma unroll
        for (int jj=0;jj<4;jj++) acc[ii][jj] += pv[ii]*vv[jj];
    }
  }
  #pragma unroll
  for (int ii=0;ii<4;ii++){
    float inv_l = 1.0f/l_i[ii];
    #pragma unroll
    for (int jj=0;jj<4;jj++){
      o[(((size_t)b*S + q0 + 4*tr + ii)*Hdim + h)*64 + 4*tc + jj] = acc[ii][jj]*inv_l;
    }
  }
}

// ---- MFMA GEMM: C[128x128 tile] = A(f32,lda=K) @ W(f32,ldw) (+addv), bf16x3 split ----
// 4 waves (2x2), each 64x64 = 4x4 fragments of 16x16x32 MFMA.
// LDS: A and B^T as [row][k] bf16 hi/lo, BK=32, 16B-slot XOR swizzle (slot ^= (row>>1)&3)
// -> both ds_write_b128 staging and ds_read_b128 fragment reads are bank-optimal.
__global__ __launch_bounds__(256) void k_gemm_mfma(
    const float* __restrict__ A, const float* __restrict__ W,
    float* __restrict__ C, const float* __restrict__ addv,
    int K, int ldw, int ldc){
  __shared__ unsigned short Ah[128*32], Al[128*32], Bh[128*32], Bl[128*32];
  const int tid = threadIdx.x;
  const int row0 = blockIdx.y*128, col0 = blockIdx.x*128;
  const int lane = tid & 63;
  const int ln15 = lane & 15, lk = lane >> 4;
  const int wv = tid >> 6;
  const int wrow0 = (wv >> 1)*64, wcol0 = (wv & 1)*64;
  const int arow = tid >> 2;   // rows arow, arow+64
  const int aks  = tid & 3;
  const int bcol = tid & 127;
  const int bks0 = tid >> 7;   // kslots bks0, bks0+2

  f32x4 acc[4][4];
  #pragma unroll
  for (int i=0;i<4;i++)
    #pragma unroll
    for (int j=0;j<4;j++){ f32x4 z = {0.f,0.f,0.f,0.f}; acc[i][j] = z; }

  for (int k0 = 0; k0 < K; k0 += 32){
    // ---- stage A (128x32) : 8 contiguous k per thread-group ----
    #pragma unroll
    for (int g=0; g<2; g++){
      int row = g*64 + arow;
      const float* ap = A + (size_t)(row0+row)*K + k0 + aks*8;
      float xs[8];
      #pragma unroll
      for (int i=0;i<8;i++) xs[i] = ap[i];
      u32x4 hi, lo; split8(xs, &hi, &lo);
      int base = row*32 + ((aks ^ ((row>>1)&3))*8);
      *(u32x4*)&Ah[base] = hi;
      *(u32x4*)&Al[base] = lo;
    }
    // ---- stage B (32x128) transposed to [col][k]; wave-coalesced column gather ----
    #pragma unroll
    for (int g=0; g<2; g++){
      int ks = bks0 + 2*g;
      const float* wp = W + (size_t)(k0 + ks*8)*ldw + col0 + bcol;
      float xs[8];
      #pragma unroll
      for (int i=0;i<8;i++) xs[i] = wp[(size_t)i*ldw];
      u32x4 hi, lo; split8(xs, &hi, &lo);
      int base = bcol*32 + ((ks ^ ((bcol>>1)&3))*8);
      *(u32x4*)&Bh[base] = hi;
      *(u32x4*)&Bl[base] = lo;
    }
    __syncthreads();
    // ---- fragments + 3-term MFMA ----
    bf16x8 ah[4], al[4];
    #pragma unroll
    for (int fi=0;fi<4;fi++){
      int r = wrow0 + fi*16 + ln15;
      int idx = r*32 + ((lk ^ ((r>>1)&3))*8);
      ah[fi] = *(const bf16x8*)&Ah[idx];
      al[fi] = *(const bf16x8*)&Al[idx];
    }
    #pragma unroll
    for (int fj=0;fj<4;fj++){
      int c = wcol0 + fj*16 + ln15;
      int idx = c*32 + ((lk ^ ((c>>1)&3))*8);
      bf16x8 bh = *(const bf16x8*)&Bh[idx];
      bf16x8 bl = *(const bf16x8*)&Bl[idx];
      #pragma unroll
      for (int fi=0;fi<4;fi++){
        acc[fi][fj] = MFMA_BF16(ah[fi], bh, acc[fi][fj]);
        acc[fi][fj] = MFMA_BF16(ah[fi], bl, acc[fi][fj]);
        acc[fi][fj] = MFMA_BF16(al[fi], bh, acc[fi][fj]);
      }
    }
    __syncthreads();
  }
  // epilogue: C/D mapping col=lane&15, row=(lane>>4)*4+reg (m89-verified)
  #pragma unroll
  for (int fi=0;fi<4;fi++){
    #pragma unroll
    for (int fj=0;fj<4;fj++){
      f32x4 v = acc[fi][fj];
      int cc = col0 + wcol0 + fj*16 + ln15;
      #pragma unroll
      for (int r=0;r<4;r++){
        size_t cix = (size_t)(row0 + wrow0 + fi*16 + lk*4 + r)*ldc + cc;
        float val = v[r];
        if (addv) val += addv[cix];
        C[cix] = val;
      }
    }
  }
}

// ---- fused SwiGLU MFMA: C = silu(A@Wg) * (A@Wu), 128x64 tile (reg pressure) ----
__global__ __launch_bounds__(256) void k_gemm_dual_mfma(
    const float* __restrict__ A, const float* __restrict__ Wg,
    const float* __restrict__ Wu, float* __restrict__ C,
    int K, int ldw, int ldc){
  __shared__ unsigned short Ah[128*32], Al[128*32];
  __shared__ unsigned short Gh[64*32], Gl[64*32], Uh[64*32], Ul[64*32];
  const int tid = threadIdx.x;
  const int row0 = blockIdx.y*128, col0 = blockIdx.x*64;
  const int lane = tid & 63;
  const int ln15 = lane & 15, lk = lane >> 4;
  const int wv = tid >> 6;
  const int wrow0 = (wv >> 1)*64, wcol0 = (wv & 1)*32;
  const int arow = tid >> 2;
  const int aks  = tid & 3;
  const int bcol = tid & 63;
  const int bks  = tid >> 6;   // 0..3

  f32x4 ag[4][2], au[4][2];
  #pragma unroll
  for (int i=0;i<4;i++)
    #pragma unroll
    for (int j=0;j<2;j++){ f32x4 z = {0.f,0.f,0.f,0.f}; ag[i][j] = z; au[i][j] = z; }

  for (int k0 = 0; k0 < K; k0 += 32){
    #pragma unroll
    for (int g=0; g<2; g++){
      int row = g*64 + arow;
      const float* ap = A + (size_t)(row0+row)*K + k0 + aks*8;
      float xs[8];
      #pragma unroll
      for (int i=0;i<8;i++) xs[i] = ap[i];
      u32x4 hi, lo; split8(xs, &hi, &lo);
      int base = row*32 + ((aks ^ ((row>>1)&3))*8);
      *(u32x4*)&Ah[base] = hi;
      *(u32x4*)&Al[base] = lo;
    }
    {
      int wbase = bcol*32 + ((bks ^ ((bcol>>1)&3))*8);
      const float* gp = Wg + (size_t)(k0 + bks*8)*ldw + col0 + bcol;
      float xs[8];
      #pragma unroll
      for (int i=0;i<8;i++) xs[i] = gp[(size_t)i*ldw];
      u32x4 hi, lo; split8(xs, &hi, &lo);
      *(u32x4*)&Gh[wbase] = hi;
      *(u32x4*)&Gl[wbase] = lo;
      const float* up = Wu + (size_t)(k0 + bks*8)*ldw + col0 + bcol;
      #pragma unroll
      for (int i=0;i<8;i++) xs[i] = up[(size_t)i*ldw];
      split8(xs, &hi, &lo);
      *(u32x4*)&Uh[wbase] = hi;
      *(u32x4*)&Ul[wbase] = lo;
    }
    __syncthreads();
    bf16x8 ah[4], al[4];
    #pragma unroll
    for (int fi=0;fi<4;fi++){
      int r = wrow0 + fi*16 + ln15;
      int idx = r*32 + ((lk ^ ((r>>1)&3))*8);
      ah[fi] = *(const bf16x8*)&Ah[idx];
      al[fi] = *(const bf16x8*)&Al[idx];
    }
    #pragma unroll
    for (int fj=0;fj<2;fj++){
      int c = wcol0 + fj*16 + ln15;
      int idx = c*32 + ((lk ^ ((c>>1)&3))*8);
      bf16x8 gh = *(const bf16x8*)&Gh[idx];
      bf16x8 gl = *(const bf16x8*)&Gl[idx];
      bf16x8 uh = *(const bf16x8*)&Uh[idx];
      bf16x8 ul = *(const bf16x8*)&Ul[idx];
      #pragma unroll
      for (int fi=0;fi<4;fi++){
        ag[fi][fj] = MFMA_BF16(ah[fi], gh, ag[fi][fj]);
        ag[fi][fj] = MFMA_BF16(ah[fi], gl, ag[fi][fj]);
        ag[fi][fj] = MFMA_BF16(al[fi], gh, ag[fi][fj]);
        au[fi][fj] = MFMA_BF16(ah[fi], uh, au[fi][fj]);
        au[fi][fj] = MFMA_BF16(ah[fi], ul, au[fi][fj]);
        au[fi][fj] = MFMA_BF16(al[fi], uh, au[fi][fj]);
      }
    }
    __syncthreads();
  }
  #pragma unroll
  for (int fi=0;fi<4;fi++){
    #pragma unroll
    for (int fj=0;fj<2;fj++){
      f32x4 vg = ag[fi][fj];
      f32x4 vu = au[fi][fj];
      int cc = col0 + wcol0 + fj*16 + ln15;
      #pragma unroll
      for (int r=0;r<4;r++){
        size_t cix = (size_t)(row0 + wrow0 + fi*16 + lk*4 + r)*ldc + cc;
        float gg = vg[r];
        C[cix] = (gg/(1.0f+expf(-gg))) * vu[r];
      }
    }
  }
}

// ---------------- prior / gating ----------------
__global__ __launch_bounds__(256) void k_dstch(const float* __restrict__ proc, const float* __restrict__ x0,
                        const float* __restrict__ ml, float* __restrict__ dst, float* __restrict__ dch){
  int tok = blockIdx.x, tid = threadIdx.x;
  const float* pp = proc + (size_t)tok*Ddim;
  const float* xp = x0 + (size_t)tok*Ddim;
  const float* mu = ml + (size_t)tok*2*Ddim;
  const float* lv = mu + Ddim;
  float s1=0.f, s2=0.f;
  for (int i=tid;i<Ddim;i+=256){
    float r = pp[i]-xp[i];
    s1 += r*r;
    float t = r - mu[i];
    float l = lv[i];
    s2 += 0.5f*(l + (1.0f + t*t)*expf(-l) - 1.0f);
  }
  __shared__ float red[256], red2[256];
  red[tid]=s1; red2[tid]=s2; __syncthreads();
  for (int st=128; st>0; st>>=1){ if (tid<st){red[tid]+=red[tid+st]; red2[tid]+=red2[tid+st];} __syncthreads(); }
  if (tid==0){ dst[tok]=red[0]/(float)Ddim; dch[tok]=red2[0]/(float)Ddim; }
}

__global__ __launch_bounds__(1024) void k_gate(const float* __restrict__ dst, const float* __restrict__ dch,
                        float* __restrict__ g){
  int tid = threadIdx.x;
  float s1=0.f, s2=0.f;
  for (int i=tid; i<Bdim*Tdim; i+=1024){ s1+=dst[i]; s2+=dch[i]; }
  __shared__ float r1[1024], r2[1024];
  r1[tid]=s1; r2[tid]=s2; __syncthreads();
  for (int st=512; st>0; st>>=1){ if(tid<st){r1[tid]+=r1[tid+st]; r2[tid]+=r2[tid+st];} __syncthreads(); }
  float m1 = r1[0]/(float)(Bdim*Tdim), m2 = r2[0]/(float)(Bdim*Tdim);
  for (int i=tid; i<Bdim*Tdim; i+=1024){
    float z = (dst[i]-m1) + (dch[i]-m2);
    g[i] = 1.0f/(1.0f+expf(-z));
  }
}

__global__ __launch_bounds__(1024) void k_select(const float* __restrict__ g, int* __restrict__ selidx,
                         float* __restrict__ selsc){
  int b = blockIdx.x, t = threadIdx.x;
  __shared__ float gs[1024];
  __shared__ int flag[1024];
  float gv = g[b*Tdim + t];
  if (!(gv == gv)) gv = -3.4e38f;
  gs[t] = gv; __syncthreads();
  float gi = gs[t];
  int rank = 0;
  for (int j=0;j<Tdim;j++){
    float gj = gs[j];
    rank += (gj > gi) || (gj == gi && j < t);
  }
  int sel = (rank < KSEL) ? 1 : 0;
  flag[t] = sel; __syncthreads();
  if (sel){
    int pos = 0;
    for (int j=0;j<t;j++) pos += flag[j];
    if (pos < KSEL){
      selidx[b*KSEL+pos] = t;
      selsc[b*KSEL+pos] = gi;
    }
  }
}

__global__ __launch_bounds__(256) void k_gather(const float* __restrict__ proc, const int* __restrict__ selidx,
                         float* __restrict__ sel){
  int j = blockIdx.x, b = blockIdx.y, tid = threadIdx.x;
  int row = clamp_row(selidx[b*KSEL+j]);
  const float* src = proc + ((size_t)b*Tdim + row)*Ddim;
  float* dst = sel + ((size_t)b*KSEL + j)*Ddim;
  for (int d=tid; d<Ddim; d+=256) dst[d]=src[d];
}

__global__ void k_out(const float* __restrict__ proc, float* __restrict__ out, int n){
  int i = blockIdx.x*blockDim.x + threadIdx.x;
  if (i<n) out[i] = proc[i];
}

__global__ __launch_bounds__(256) void k_scatter(const float* __restrict__ sel, const float* __restrict__ y,
                          const float* __restrict__ selsc, const int* __restrict__ selidx,
                          float* __restrict__ out){
  int j = blockIdx.x, b = blockIdx.y, tid = threadIdx.x;
  int row = clamp_row(selidx[b*KSEL+j]);
  float s = selsc[b*KSEL+j];
  const float* sp = sel + ((size_t)b*KSEL + j)*Ddim;
  const float* yp = y + ((size_t)b*KSEL + j)*Ddim;
  float* op = out + ((size_t)b*Tdim + row)*Ddim;
  for (int d=tid; d<Ddim; d+=256){
    op[d] = sp[d] + s*(yp[d]-sp[d]);
  }
}

// ---------------- driver ----------------
extern "C" void kernel_launch(void* const* d_in, const int* in_sizes, int n_in,
                              void* d_out, int out_size, void* d_ws, size_t ws_size,
                              hipStream_t stream){
  (void)in_sizes; (void)n_in; (void)out_size;
  const float* hidden = (const float*)d_in[0];
  const float* wq1 = (const float*)d_in[1];
  const float* wk1 = (const float*)d_in[2];
  const float* wv1 = (const float*)d_in[3];
  const float* wo1 = (const float*)d_in[4];
  const float* wq2 = (const float*)d_in[5];
  const float* wk2 = (const float*)d_in[6];
  const float* wv2 = (const float*)d_in[7];
  const float* wo2 = (const float*)d_in[8];
  const float* wg1 = (const float*)d_in[9];
  const float* wu1 = (const float*)d_in[10];
  const float* wd1 = (const float*)d_in[11];
  const float* wg2 = (const float*)d_in[12];
  const float* wu2 = (const float*)d_in[13];
  const float* wd2 = (const float*)d_in[14];
  const float* ln1_1 = (const float*)d_in[15];
  const float* ln2_1 = (const float*)d_in[16];
  const float* ln1_2 = (const float*)d_in[17];
  const float* ln2_2 = (const float*)d_in[18];
  const float* prior_norm = (const float*)d_in[19];
  const float* prior_w = (const float*)d_in[20];

  const size_t A = (size_t)Bdim*Tdim*Ddim;      // 4M floats
  const size_t Q = (size_t)Bdim*KSEL*Ddim;      // 1M floats
  const int n = (int)A;
  const int MT = Bdim*Tdim;    // 4096
  const int M2 = Bdim*KSEL;    // 1024

  size_t need = (4*A + 16384) * sizeof(float);
  if (ws_size < need){
    k_fallback<<<(n+255)/256,256,0,stream>>>(hidden, (float*)d_out, n);
    return;
  }

  float* ws = (float*)d_ws;
  float* R0 = ws;
  float* R1 = ws + 1*A;
  float* R2 = ws + 2*A;
  float* R3 = ws + 3*A;
  float* dstb = ws + 4*A;
  float* dchb = dstb + 4096;
  float* gb   = dchb + 4096;
  float* selsc= gb + 4096;
  int*   selidx = (int*)(selsc + 1024);

  k_init_sel<<<4,256,0,stream>>>(selidx, selsc, Bdim*KSEL);

  // ---- layer 1 ----
  k_rmsnorm<<<MT,256,0,stream>>>(hidden, ln1_1, R0);                       // h = R0
  dim3 gD(Ddim/128, MT/128);
  k_gemm_mfma<<<gD,256,0,stream>>>(R0, wq1, R1, nullptr, Ddim, Ddim, Ddim); // q=R1
  k_gemm_mfma<<<gD,256,0,stream>>>(R0, wk1, R2, nullptr, Ddim, Ddim, Ddim); // k=R2
  k_gemm_mfma<<<gD,256,0,stream>>>(R0, wv1, R3, nullptr, Ddim, Ddim, Ddim); // v=R3
  int nr = MT*Hdim*32;
  k_rope<<<(nr+255)/256,256,0,stream>>>(R1, nullptr, Tdim, nr);
  k_rope<<<(nr+255)/256,256,0,stream>>>(R2, nullptr, Tdim, nr);
  k_attn_tile<<<dim3(Tdim/64,Hdim,Bdim),256,0,stream>>>(R1, R2, R3, R0, Tdim); // ob=R0
  k_gemm_mfma<<<gD,256,0,stream>>>(R0, wo1, R1, hidden, Ddim, Ddim, Ddim);   // x1=R1 (+hidden)
  k_rmsnorm<<<MT,256,0,stream>>>(R1, ln2_1, R2);                             // h2=R2
  // FFN in 4 column-chunks of 1024
  for (int c = 0; c < 4; c++){
    k_gemm_dual_mfma<<<dim3(1024/64, MT/128),256,0,stream>>>(R2, wg1 + (size_t)c*1024, wu1 + (size_t)c*1024,
                                                  R3, Ddim, FFNdim, 1024);
    k_gemm_mfma<<<dim3(Ddim/128, MT/128),256,0,stream>>>(R3, wd1 + (size_t)c*1024*Ddim, R0,
                                             (c==0 ? R1 : R0), 1024, Ddim, Ddim);
  }
  // proc = R0

  // ---- prior / gate / select ----
  k_rmsnorm<<<MT,256,0,stream>>>(hidden, prior_norm, R1);                  // ph=R1
  k_gemm_mfma<<<dim3(2*Ddim/128, MT/128),256,0,stream>>>(R1, prior_w, R2, nullptr, Ddim, 2*Ddim, 2*Ddim); // ml
  k_dstch<<<MT,256,0,stream>>>(R0, hidden, R2, dstb, dchb);
  k_gate<<<1,1024,0,stream>>>(dstb, dchb, gb);
  k_select<<<Bdim,1024,0,stream>>>(gb, selidx, selsc);
  k_gather<<<dim3(KSEL,Bdim),256,0,stream>>>(R0, selidx, R1);              // selx = R1[0..Q)

  // ---- layer 2 (4x256 selected tokens) ----
  k_rmsnorm<<<M2,256,0,stream>>>(R1, ln1_2, R2);                            // h = R2[0..Q)
  dim3 gD2(Ddim/128, M2/128);
  k_gemm_mfma<<<gD2,256,0,stream>>>(R2, wq2, R2+Q,   nullptr, Ddim, Ddim, Ddim); // q2
  k_gemm_mfma<<<gD2,256,0,stream>>>(R2, wk2, R2+2*Q, nullptr, Ddim, Ddim, Ddim); // k2
  k_gemm_mfma<<<gD2,256,0,stream>>>(R2, wv2, R2+3*Q, nullptr, Ddim, Ddim, Ddim); // v2
  int nr2 = M2*Hdim*32;
  k_rope<<<(nr2+255)/256,256,0,stream>>>(R2+Q,   selidx, KSEL, nr2);
  k_rope<<<(nr2+255)/256,256,0,stream>>>(R2+2*Q, selidx, KSEL, nr2);
  k_attn_tile<<<dim3(KSEL/64,Hdim,Bdim),256,0,stream>>>(R2+Q, R2+2*Q, R2+3*Q, R3, KSEL); // o2=R3
  k_gemm_mfma<<<gD2,256,0,stream>>>(R3, wo2, R3+Q, R1, Ddim, Ddim, Ddim);            // x12 (+selx)
  k_rmsnorm<<<M2,256,0,stream>>>(R3+Q, ln2_2, R3+2*Q);                               // h22
  for (int c = 0; c < 4; c++){
    k_gemm_dual_mfma<<<dim3(1024/64, M2/128),256,0,stream>>>(R3+2*Q, wg2 + (size_t)c*1024, wu2 + (size_t)c*1024,
                                                  R3+3*Q, Ddim, FFNdim, 1024);
    k_gemm_mfma<<<dim3(Ddim/128, M2/128),256,0,stream>>>(R3+3*Q, wd2 + (size_t)c*1024*Ddim, R2,
                                             (c==0 ? R3+Q : R2), 1024, Ddim, Ddim);
  }
  // y = R2[0..Q)

  // ---- output ----
  k_out<<<(n+255)/256,256,0,stream>>>(R0, (float*)d_out, n);
  k_scatter<<<dim3(KSEL,Bdim),256,0,stream>>>(R1, R2, selsc, selidx, (float*)d_out);
}

// Round 3
// 1923.149 us; speedup vs baseline: 1.9777x; 1.1433x over previous
//
#include <hip/hip_runtime.h>
#include <math.h>

#define Bdim 4
#define Tdim 1024
#define Ddim 1024
#define Hdim 16
#define DHdim 64
#define FFNdim 4096
#define KSEL 256
#define EPSf 1e-6f

typedef __attribute__((ext_vector_type(8))) short bf16x8;   // 8 bf16 = 4 VGPR
typedef __attribute__((ext_vector_type(4))) float f32x4;
typedef __attribute__((ext_vector_type(4))) unsigned int u32x4;

#define MFMA_BF16(a,b,c) __builtin_amdgcn_mfma_f32_16x16x32_bf16(a,b,c,0,0,0)

__device__ __forceinline__ int clamp_row(int r){ return r < 0 ? 0 : (r > Tdim-1 ? Tdim-1 : r); }

// split 8 fp32 into bf16 hi (truncate) + bf16 lo (exact remainder, truncated).
__device__ __forceinline__ void split8(const float* xs, u32x4* hi, u32x4* lo){
  unsigned int hm[8], lm[8];
  #pragma unroll
  for (int i=0;i<8;i++){
    unsigned int b = __float_as_uint(xs[i]);
    hm[i] = b & 0xFFFF0000u;
    lm[i] = __float_as_uint(xs[i] - __uint_as_float(hm[i]));
  }
  u32x4 h, l;
  #pragma unroll
  for (int i=0;i<4;i++){
    h[i] = (hm[2*i] >> 16) | hm[2*i+1];
    l[i] = (lm[2*i] >> 16) | (lm[2*i+1] & 0xFFFF0000u);
  }
  *hi = h; *lo = l;
}

__device__ __forceinline__ void split1(float x, unsigned int* h16, unsigned int* l16){
  unsigned int b = __float_as_uint(x);
  unsigned int hm = b & 0xFFFF0000u;
  *h16 = hm >> 16;
  *l16 = __float_as_uint(x - __uint_as_float(hm)) >> 16;
}

// ---------------- fallback (diagnostic): out = hidden ----------------
__global__ void k_fallback(const float* __restrict__ in, float* __restrict__ out, int n){
  int i = blockIdx.x*blockDim.x + threadIdx.x;
  if (i < n) out[i] = in[i];
}

__global__ void k_init_sel(int* __restrict__ selidx, float* __restrict__ selsc, int n){
  int i = blockIdx.x*blockDim.x + threadIdx.x;
  if (i < n){ selidx[i] = i & (KSEL-1); selsc[i] = 0.f; }
}

// ---------------- rmsnorm ----------------
__global__ __launch_bounds__(256) void k_rmsnorm(const float* __restrict__ x, const float* __restrict__ w,
                          float* __restrict__ y){
  int tok = blockIdx.x;
  const float* xp = x + (size_t)tok*Ddim;
  float* yp = y + (size_t)tok*Ddim;
  int tid = threadIdx.x;
  float s = 0.f;
  float xv[4];
  #pragma unroll
  for (int u = 0; u < 4; u++){ xv[u] = xp[tid + 256*u]; s += xv[u]*xv[u]; }
  __shared__ float red[256];
  red[tid]=s; __syncthreads();
  for (int st=128; st>0; st>>=1){ if (tid<st) red[tid]+=red[tid+st]; __syncthreads(); }
  float r = 1.0f/sqrtf(red[0]/(float)Ddim + EPSf);
  #pragma unroll
  for (int u = 0; u < 4; u++) yp[tid + 256*u] = xv[u]*r*w[tid + 256*u];
}

// rope in-place on (b,S,H,64); posidx==nullptr -> pos=t else pos=posidx[b*S+t]
__global__ void k_rope(float* __restrict__ x, const int* __restrict__ posidx, int S, int n){
  int e = blockIdx.x*blockDim.x + threadIdx.x;
  if (e >= n) return;
  int j = e & 31;
  int q = e >> 9;
  int t = q % S;
  float pos = posidx ? (float)clamp_row(posidx[q]) : (float)t;
  float inv = exp2f(-0.4152410118609203f * (float)j);
  float ang = pos * inv;
  float c = cosf(ang), s = sinf(ang);
  size_t base = ((size_t)(e >> 5)) * 64;
  float x1 = x[base + j], x2 = x[base + 32 + j];
  x[base + j]      = x1*c - x2*s;
  x[base + 32 + j] = x2*c + x1*s;
}

// ---------------- MFMA flash attention ----------------
// block = (64 q-rows, head, batch), 256 threads = 4 waves; wave w owns q-rows w*16..w*16+15.
// K staged [key][d] bf16 hi/lo, slot-XOR swizzle; V staged transposed [d][key] hi/lo;
// P per-wave f32 LDS strip (stride 68). 3-term bf16 split on QK^T and PV.
__global__ __launch_bounds__(256) void k_attn_mfma(const float* __restrict__ q, const float* __restrict__ k,
                       const float* __restrict__ v, float* __restrict__ o, int S){
  __shared__ unsigned short Kh[64*64], Kl[64*64];
  __shared__ unsigned short Vh[64*64], Vl[64*64];   // V^T: [d][key]
  __shared__ float Pds[4*16*68];                    // per-wave P [16][68]

  const int qt = blockIdx.x, h = blockIdx.y, b = blockIdx.z;
  const int q0 = qt*64;
  const int tid = threadIdx.x;
  const int lane = tid & 63;
  const int ln15 = lane & 15, lk = lane >> 4;
  const int wv = tid >> 6;
  const int qbase = wv*16;

  // ---- Q A-fragments straight from global (rope'd q) ----
  bf16x8 qa_h[2], qa_l[2];
  {
    const float* qp = q + (((size_t)b*S + q0 + qbase + ln15)*Hdim + h)*64 + lk*8;
    #pragma unroll
    for (int ks=0; ks<2; ks++){
      float xs[8];
      #pragma unroll
      for (int i=0;i<8;i++) xs[i] = qp[ks*32 + i];
      u32x4 hi, lo; split8(xs, &hi, &lo);
      qa_h[ks] = *(bf16x8*)&hi;
      qa_l[ks] = *(bf16x8*)&lo;
    }
  }

  float m_i[4], l_i[4];
  f32x4 oacc[4];
  #pragma unroll
  for (int r=0;r<4;r++){ m_i[r] = -3.4e38f; l_i[r] = 0.f; }
  #pragma unroll
  for (int fd=0;fd<4;fd++){ f32x4 z = {0.f,0.f,0.f,0.f}; oacc[fd] = z; }

  float* Pw = Pds + wv*(16*68);

  for (int j0 = 0; j0 <= q0; j0 += 64){
    __syncthreads();   // previous tile's K/V readers done
    // ---- stage K [key][d] hi/lo, slot-XOR swizzled ----
    {
      int row = tid >> 2;
      int s0 = (tid & 3)*2;
      const float* kp = k + (((size_t)b*S + j0 + row)*Hdim + h)*64 + s0*8;
      #pragma unroll
      for (int g=0; g<2; g++){
        int slot = s0 + g;
        float xs[8];
        #pragma unroll
        for (int i=0;i<8;i++) xs[i] = kp[g*8 + i];
        u32x4 hi, lo; split8(xs, &hi, &lo);
        int base = row*64 + ((slot ^ (row&7))*8);
        *(u32x4*)&Kh[base] = hi;
        *(u32x4*)&Kl[base] = lo;
      }
    }
    // ---- stage V transposed [d][key] hi/lo (paired-key u32 writes) ----
    {
      int j = tid & 31;            // key pair
      int dbase = (tid >> 5)*8;
      const float* vp0 = v + (((size_t)b*S + j0 + 2*j)*Hdim + h)*64 + dbase;
      const float* vp1 = vp0 + (size_t)Hdim*64;
      float x0[8], x1[8];
      #pragma unroll
      for (int i=0;i<8;i++){ x0[i]=vp0[i]; x1[i]=vp1[i]; }
      unsigned int* VhW = (unsigned int*)Vh;
      unsigned int* VlW = (unsigned int*)Vl;
      #pragma unroll
      for (int i=0;i<8;i++){
        int d = dbase + i;
        unsigned int h0,l0,h1,l1;
        split1(x0[i], &h0, &l0); split1(x1[i], &h1, &l1);
        int off = d*32 + (((j>>2) ^ (d&7))*4) + (j&3);
        VhW[off] = h0 | (h1<<16);
        VlW[off] = l0 | (l1<<16);
      }
    }
    __syncthreads();

    // ---- QK^T: S-block [16 q x 64 keys], 3-term split ----
    f32x4 sacc[4];
    #pragma unroll
    for (int fj=0;fj<4;fj++){ f32x4 z = {0.f,0.f,0.f,0.f}; sacc[fj] = z; }
    #pragma unroll
    for (int ks=0; ks<2; ks++){
      #pragma unroll
      for (int fj=0;fj<4;fj++){
        int kr = fj*16 + ln15;
        int idx = kr*64 + (((ks*4+lk) ^ (kr&7))*8);
        bf16x8 kb_h = *(const bf16x8*)&Kh[idx];
        bf16x8 kb_l = *(const bf16x8*)&Kl[idx];
        sacc[fj] = MFMA_BF16(qa_h[ks], kb_h, sacc[fj]);
        sacc[fj] = MFMA_BF16(qa_h[ks], kb_l, sacc[fj]);
        sacc[fj] = MFMA_BF16(qa_l[ks], kb_h, sacc[fj]);
      }
    }
    // ---- scale + causal mask (C-layout: row=lk*4+r, col=fj*16+ln15) ----
    #pragma unroll
    for (int fj=0;fj<4;fj++){
      int key = j0 + fj*16 + ln15;
      #pragma unroll
      for (int r=0;r<4;r++){
        float sv = sacc[fj][r]*0.125f;
        int qrow = q0 + qbase + lk*4 + r;
        sacc[fj][r] = (key > qrow) ? -3.4e38f : sv;
      }
    }
    // ---- online softmax (wave-parallel: reduce over ln15 lanes) ----
    float p[4][4];
    #pragma unroll
    for (int r=0;r<4;r++){
      float mt = fmaxf(fmaxf(sacc[0][r],sacc[1][r]), fmaxf(sacc[2][r],sacc[3][r]));
      #pragma unroll
      for (int off=1; off<16; off<<=1) mt = fmaxf(mt, __shfl_xor(mt, off));
      float m_new = fmaxf(m_i[r], mt);
      float alpha = expf(m_i[r] - m_new);
      float rs = 0.f;
      #pragma unroll
      for (int fj=0;fj<4;fj++){
        p[fj][r] = expf(sacc[fj][r] - m_new);
        rs += p[fj][r];
      }
      #pragma unroll
      for (int off=1; off<16; off<<=1) rs += __shfl_xor(rs, off);
      l_i[r] = l_i[r]*alpha + rs;
      m_i[r] = m_new;
      #pragma unroll
      for (int fd=0;fd<4;fd++) oacc[fd][r] *= alpha;
    }
    // ---- P -> per-wave LDS (f32, stride 68) ----
    #pragma unroll
    for (int fj=0;fj<4;fj++)
      #pragma unroll
      for (int r=0;r<4;r++)
        Pw[(lk*4+r)*68 + fj*16 + ln15] = p[fj][r];
    // ---- PV: O += P @ V, 3-term split ----
    #pragma unroll
    for (int ks=0; ks<2; ks++){
      f32x4 pf0 = *(const f32x4*)&Pw[ln15*68 + ks*32 + lk*8];
      f32x4 pf1 = *(const f32x4*)&Pw[ln15*68 + ks*32 + lk*8 + 4];
      float xs[8] = {pf0[0],pf0[1],pf0[2],pf0[3],pf1[0],pf1[1],pf1[2],pf1[3]};
      u32x4 hi, lo; split8(xs, &hi, &lo);
      bf16x8 pa_h = *(bf16x8*)&hi;
      bf16x8 pa_l = *(bf16x8*)&lo;
      #pragma unroll
      for (int fd=0;fd<4;fd++){
        int d = fd*16 + ln15;
        int idx = d*64 + (((ks*4+lk) ^ (d&7))*8);
        bf16x8 vb_h = *(const bf16x8*)&Vh[idx];
        bf16x8 vb_l = *(const bf16x8*)&Vl[idx];
        oacc[fd] = MFMA_BF16(pa_h, vb_h, oacc[fd]);
        oacc[fd] = MFMA_BF16(pa_h, vb_l, oacc[fd]);
        oacc[fd] = MFMA_BF16(pa_l, vb_h, oacc[fd]);
      }
    }
  }
  // ---- epilogue ----
  #pragma unroll
  for (int r=0;r<4;r++){
    float inv_l = 1.0f/l_i[r];
    #pragma unroll
    for (int fd=0;fd<4;fd++){
      o[(((size_t)b*S + q0 + qbase + lk*4 + r)*Hdim + h)*64 + fd*16 + ln15] = oacc[fd][r]*inv_l;
    }
  }
}

// ---- MFMA GEMM: C[128x128 tile] = A(f32,lda=K) @ W(f32,ldw) (+addv), bf16x3 split ----
__global__ __launch_bounds__(256) void k_gemm_mfma(
    const float* __restrict__ A, const float* __restrict__ W,
    float* __restrict__ C, const float* __restrict__ addv,
    int K, int ldw, int ldc){
  __shared__ unsigned short Ah[128*32], Al[128*32], Bh[128*32], Bl[128*32];
  const int tid = threadIdx.x;
  const int row0 = blockIdx.y*128, col0 = blockIdx.x*128;
  const int lane = tid & 63;
  const int ln15 = lane & 15, lk = lane >> 4;
  const int wv = tid >> 6;
  const int wrow0 = (wv >> 1)*64, wcol0 = (wv & 1)*64;
  const int arow = tid >> 2;
  const int aks  = tid & 3;
  const int bcol = tid & 127;
  const int bks0 = tid >> 7;

  f32x4 acc[4][4];
  #pragma unroll
  for (int i=0;i<4;i++)
    #pragma unroll
    for (int j=0;j<4;j++){ f32x4 z = {0.f,0.f,0.f,0.f}; acc[i][j] = z; }

  for (int k0 = 0; k0 < K; k0 += 32){
    #pragma unroll
    for (int g=0; g<2; g++){
      int row = g*64 + arow;
      const float* ap = A + (size_t)(row0+row)*K + k0 + aks*8;
      float xs[8];
      #pragma unroll
      for (int i=0;i<8;i++) xs[i] = ap[i];
      u32x4 hi, lo; split8(xs, &hi, &lo);
      int base = row*32 + ((aks ^ ((row>>1)&3))*8);
      *(u32x4*)&Ah[base] = hi;
      *(u32x4*)&Al[base] = lo;
    }
    #pragma unroll
    for (int g=0; g<2; g++){
      int ks = bks0 + 2*g;
      const float* wp = W + (size_t)(k0 + ks*8)*ldw + col0 + bcol;
      float xs[8];
      #pragma unroll
      for (int i=0;i<8;i++) xs[i] = wp[(size_t)i*ldw];
      u32x4 hi, lo; split8(xs, &hi, &lo);
      int base = bcol*32 + ((ks ^ ((bcol>>1)&3))*8);
      *(u32x4*)&Bh[base] = hi;
      *(u32x4*)&Bl[base] = lo;
    }
    __syncthreads();
    bf16x8 ah[4], al[4];
    #pragma unroll
    for (int fi=0;fi<4;fi++){
      int r = wrow0 + fi*16 + ln15;
      int idx = r*32 + ((lk ^ ((r>>1)&3))*8);
      ah[fi] = *(const bf16x8*)&Ah[idx];
      al[fi] = *(const bf16x8*)&Al[idx];
    }
    #pragma unroll
    for (int fj=0;fj<4;fj++){
      int c = wcol0 + fj*16 + ln15;
      int idx = c*32 + ((lk ^ ((c>>1)&3))*8);
      bf16x8 bh = *(const bf16x8*)&Bh[idx];
      bf16x8 bl = *(const bf16x8*)&Bl[idx];
      #pragma unroll
      for (int fi=0;fi<4;fi++){
        acc[fi][fj] = MFMA_BF16(ah[fi], bh, acc[fi][fj]);
        acc[fi][fj] = MFMA_BF16(ah[fi], bl, acc[fi][fj]);
        acc[fi][fj] = MFMA_BF16(al[fi], bh, acc[fi][fj]);
      }
    }
    __syncthreads();
  }
  #pragma unroll
  for (int fi=0;fi<4;fi++){
    #pragma unroll
    for (int fj=0;fj<4;fj++){
      f32x4 v = acc[fi][fj];
      int cc = col0 + wcol0 + fj*16 + ln15;
      #pragma unroll
      for (int r=0;r<4;r++){
        size_t cix = (size_t)(row0 + wrow0 + fi*16 + lk*4 + r)*ldc + cc;
        float val = v[r];
        if (addv) val += addv[cix];
        C[cix] = val;
      }
    }
  }
}

// ---- fused SwiGLU MFMA: C = silu(A@Wg) * (A@Wu), 128x64 tile ----
__global__ __launch_bounds__(256) void k_gemm_dual_mfma(
    const float* __restrict__ A, const float* __restrict__ Wg,
    const float* __restrict__ Wu, float* __restrict__ C,
    int K, int ldw, int ldc){
  __shared__ unsigned short Ah[128*32], Al[128*32];
  __shared__ unsigned short Gh[64*32], Gl[64*32], Uh[64*32], Ul[64*32];
  const int tid = threadIdx.x;
  const int row0 = blockIdx.y*128, col0 = blockIdx.x*64;
  const int lane = tid & 63;
  const int ln15 = lane & 15, lk = lane >> 4;
  const int wv = tid >> 6;
  const int wrow0 = (wv >> 1)*64, wcol0 = (wv & 1)*32;
  const int arow = tid >> 2;
  const int aks  = tid & 3;
  const int bcol = tid & 63;
  const int bks  = tid >> 6;

  f32x4 ag[4][2], au[4][2];
  #pragma unroll
  for (int i=0;i<4;i++)
    #pragma unroll
    for (int j=0;j<2;j++){ f32x4 z = {0.f,0.f,0.f,0.f}; ag[i][j] = z; au[i][j] = z; }

  for (int k0 = 0; k0 < K; k0 += 32){
    #pragma unroll
    for (int g=0; g<2; g++){
      int row = g*64 + arow;
      const float* ap = A + (size_t)(row0+row)*K + k0 + aks*8;
      float xs[8];
      #pragma unroll
      for (int i=0;i<8;i++) xs[i] = ap[i];
      u32x4 hi, lo; split8(xs, &hi, &lo);
      int base = row*32 + ((aks ^ ((row>>1)&3))*8);
      *(u32x4*)&Ah[base] = hi;
      *(u32x4*)&Al[base] = lo;
    }
    {
      int wbase = bcol*32 + ((bks ^ ((bcol>>1)&3))*8);
      const float* gp = Wg + (size_t)(k0 + bks*8)*ldw + col0 + bcol;
      float xs[8];
      #pragma unroll
      for (int i=0;i<8;i++) xs[i] = gp[(size_t)i*ldw];
      u32x4 hi, lo; split8(xs, &hi, &lo);
      *(u32x4*)&Gh[wbase] = hi;
      *(u32x4*)&Gl[wbase] = lo;
      const float* up = Wu + (size_t)(k0 + bks*8)*ldw + col0 + bcol;
      #pragma unroll
      for (int i=0;i<8;i++) xs[i] = up[(size_t)i*ldw];
      split8(xs, &hi, &lo);
      *(u32x4*)&Uh[wbase] = hi;
      *(u32x4*)&Ul[wbase] = lo;
    }
    __syncthreads();
    bf16x8 ah[4], al[4];
    #pragma unroll
    for (int fi=0;fi<4;fi++){
      int r = wrow0 + fi*16 + ln15;
      int idx = r*32 + ((lk ^ ((r>>1)&3))*8);
      ah[fi] = *(const bf16x8*)&Ah[idx];
      al[fi] = *(const bf16x8*)&Al[idx];
    }
    #pragma unroll
    for (int fj=0;fj<2;fj++){
      int c = wcol0 + fj*16 + ln15;
      int idx = c*32 + ((lk ^ ((c>>1)&3))*8);
      bf16x8 gh = *(const bf16x8*)&Gh[idx];
      bf16x8 gl = *(const bf16x8*)&Gl[idx];
      bf16x8 uh = *(const bf16x8*)&Uh[idx];
      bf16x8 ul = *(const bf16x8*)&Ul[idx];
      #pragma unroll
      for (int fi=0;fi<4;fi++){
        ag[fi][fj] = MFMA_BF16(ah[fi], gh, ag[fi][fj]);
        ag[fi][fj] = MFMA_BF16(ah[fi], gl, ag[fi][fj]);
        ag[fi][fj] = MFMA_BF16(al[fi], gh, ag[fi][fj]);
        au[fi][fj] = MFMA_BF16(ah[fi], uh, au[fi][fj]);
        au[fi][fj] = MFMA_BF16(ah[fi], ul, au[fi][fj]);
        au[fi][fj] = MFMA_BF16(al[fi], uh, au[fi][fj]);
      }
    }
    __syncthreads();
  }
  #pragma unroll
  for (int fi=0;fi<4;fi++){
    #pragma unroll
    for (int fj=0;fj<2;fj++){
      f32x4 vg = ag[fi][fj];
      f32x4 vu = au[fi][fj];
      int cc = col0 + wcol0 + fj*16 + ln15;
      #pragma unroll
      for (int r=0;r<4;r++){
        size_t cix = (size_t)(row0 + wrow0 + fi*16 + lk*4 + r)*ldc + cc;
        float gg = vg[r];
        C[cix] = (gg/(1.0f+expf(-gg))) * vu[r];
      }
    }
  }
}

// ---------------- prior / gating ----------------
__global__ __launch_bounds__(256) void k_dstch(const float* __restrict__ proc, const float* __restrict__ x0,
                        const float* __restrict__ ml, float* __restrict__ dst, float* __restrict__ dch){
  int tok = blockIdx.x, tid = threadIdx.x;
  const float* pp = proc + (size_t)tok*Ddim;
  const float* xp = x0 + (size_t)tok*Ddim;
  const float* mu = ml + (size_t)tok*2*Ddim;
  const float* lv = mu + Ddim;
  float s1=0.f, s2=0.f;
  for (int i=tid;i<Ddim;i+=256){
    float r = pp[i]-xp[i];
    s1 += r*r;
    float t = r - mu[i];
    float l = lv[i];
    s2 += 0.5f*(l + (1.0f + t*t)*expf(-l) - 1.0f);
  }
  __shared__ float red[256], red2[256];
  red[tid]=s1; red2[tid]=s2; __syncthreads();
  for (int st=128; st>0; st>>=1){ if (tid<st){red[tid]+=red[tid+st]; red2[tid]+=red2[tid+st];} __syncthreads(); }
  if (tid==0){ dst[tok]=red[0]/(float)Ddim; dch[tok]=red2[0]/(float)Ddim; }
}

__global__ __launch_bounds__(1024) void k_gate(const float* __restrict__ dst, const float* __restrict__ dch,
                        float* __restrict__ g){
  int tid = threadIdx.x;
  float s1=0.f, s2=0.f;
  for (int i=tid; i<Bdim*Tdim; i+=1024){ s1+=dst[i]; s2+=dch[i]; }
  __shared__ float r1[1024], r2[1024];
  r1[tid]=s1; r2[tid]=s2; __syncthreads();
  for (int st=512; st>0; st>>=1){ if(tid<st){r1[tid]+=r1[tid+st]; r2[tid]+=r2[tid+st];} __syncthreads(); }
  float m1 = r1[0]/(float)(Bdim*Tdim), m2 = r2[0]/(float)(Bdim*Tdim);
  for (int i=tid; i<Bdim*Tdim; i+=1024){
    float z = (dst[i]-m1) + (dch[i]-m2);
    g[i] = 1.0f/(1.0f+expf(-z));
  }
}

__global__ __launch_bounds__(1024) void k_select(const float* __restrict__ g, int* __restrict__ selidx,
                         float* __restrict__ selsc){
  int b = blockIdx.x, t = threadIdx.x;
  __shared__ float gs[1024];
  __shared__ int flag[1024];
  float gv = g[b*Tdim + t];
  if (!(gv == gv)) gv = -3.4e38f;
  gs[t] = gv; __syncthreads();
  float gi = gs[t];
  int rank = 0;
  for (int j=0;j<Tdim;j++){
    float gj = gs[j];
    rank += (gj > gi) || (gj == gi && j < t);
  }
  int sel = (rank < KSEL) ? 1 : 0;
  flag[t] = sel; __syncthreads();
  if (sel){
    int pos = 0;
    for (int j=0;j<t;j++) pos += flag[j];
    if (pos < KSEL){
      selidx[b*KSEL+pos] = t;
      selsc[b*KSEL+pos] = gi;
    }
  }
}

__global__ __launch_bounds__(256) void k_gather(const float* __restrict__ proc, const int* __restrict__ selidx,
                         float* __restrict__ sel){
  int j = blockIdx.x, b = blockIdx.y, tid = threadIdx.x;
  int row = clamp_row(selidx[b*KSEL+j]);
  const float* src = proc + ((size_t)b*Tdim + row)*Ddim;
  float* dst = sel + ((size_t)b*KSEL + j)*Ddim;
  for (int d=tid; d<Ddim; d+=256) dst[d]=src[d];
}

__global__ void k_out(const float* __restrict__ proc, float* __restrict__ out, int n){
  int i = blockIdx.x*blockDim.x + threadIdx.x;
  if (i<n) out[i] = proc[i];
}

__global__ __launch_bounds__(256) void k_scatter(const float* __restrict__ sel, const float* __restrict__ y,
                          const float* __restrict__ selsc, const int* __restrict__ selidx,
                          float* __restrict__ out){
  int j = blockIdx.x, b = blockIdx.y, tid = threadIdx.x;
  int row = clamp_row(selidx[b*KSEL+j]);
  float s = selsc[b*KSEL+j];
  const float* sp = sel + ((size_t)b*KSEL + j)*Ddim;
  const float* yp = y + ((size_t)b*KSEL + j)*Ddim;
  float* op = out + ((size_t)b*Tdim + row)*Ddim;
  for (int d=tid; d<Ddim; d+=256){
    op[d] = sp[d] + s*(yp[d]-sp[d]);
  }
}

// ---------------- driver ----------------
extern "C" void kernel_launch(void* const* d_in, const int* in_sizes, int n_in,
                              void* d_out, int out_size, void* d_ws, size_t ws_size,
                              hipStream_t stream){
  (void)in_sizes; (void)n_in; (void)out_size;
  const float* hidden = (const float*)d_in[0];
  const float* wq1 = (const float*)d_in[1];
  const float* wk1 = (const float*)d_in[2];
  const float* wv1 = (const float*)d_in[3];
  const float* wo1 = (const float*)d_in[4];
  const float* wq2 = (const float*)d_in[5];
  const float* wk2 = (const float*)d_in[6];
  const float* wv2 = (const float*)d_in[7];
  const float* wo2 = (const float*)d_in[8];
  const float* wg1 = (const float*)d_in[9];
  const float* wu1 = (const float*)d_in[10];
  const float* wd1 = (const float*)d_in[11];
  const float* wg2 = (const float*)d_in[12];
  const float* wu2 = (const float*)d_in[13];
  const float* wd2 = (const float*)d_in[14];
  const float* ln1_1 = (const float*)d_in[15];
  const float* ln2_1 = (const float*)d_in[16];
  const float* ln1_2 = (const float*)d_in[17];
  const float* ln2_2 = (const float*)d_in[18];
  const float* prior_norm = (const float*)d_in[19];
  const float* prior_w = (const float*)d_in[20];

  const size_t A = (size_t)Bdim*Tdim*Ddim;      // 4M floats
  const size_t Q = (size_t)Bdim*KSEL*Ddim;      // 1M floats
  const int n = (int)A;
  const int MT = Bdim*Tdim;    // 4096
  const int M2 = Bdim*KSEL;    // 1024

  size_t need = (4*A + 16384) * sizeof(float);
  if (ws_size < need){
    k_fallback<<<(n+255)/256,256,0,stream>>>(hidden, (float*)d_out, n);
    return;
  }

  float* ws = (float*)d_ws;
  float* R0 = ws;
  float* R1 = ws + 1*A;
  float* R2 = ws + 2*A;
  float* R3 = ws + 3*A;
  float* dstb = ws + 4*A;
  float* dchb = dstb + 4096;
  float* gb   = dchb + 4096;
  float* selsc= gb + 4096;
  int*   selidx = (int*)(selsc + 1024);

  k_init_sel<<<4,256,0,stream>>>(selidx, selsc, Bdim*KSEL);

  // ---- layer 1 ----
  k_rmsnorm<<<MT,256,0,stream>>>(hidden, ln1_1, R0);                       // h = R0
  dim3 gD(Ddim/128, MT/128);
  k_gemm_mfma<<<gD,256,0,stream>>>(R0, wq1, R1, nullptr, Ddim, Ddim, Ddim); // q=R1
  k_gemm_mfma<<<gD,256,0,stream>>>(R0, wk1, R2, nullptr, Ddim, Ddim, Ddim); // k=R2
  k_gemm_mfma<<<gD,256,0,stream>>>(R0, wv1, R3, nullptr, Ddim, Ddim, Ddim); // v=R3
  int nr = MT*Hdim*32;
  k_rope<<<(nr+255)/256,256,0,stream>>>(R1, nullptr, Tdim, nr);
  k_rope<<<(nr+255)/256,256,0,stream>>>(R2, nullptr, Tdim, nr);
  k_attn_mfma<<<dim3(Tdim/64,Hdim,Bdim),256,0,stream>>>(R1, R2, R3, R0, Tdim); // ob=R0
  k_gemm_mfma<<<gD,256,0,stream>>>(R0, wo1, R1, hidden, Ddim, Ddim, Ddim);   // x1=R1 (+hidden)
  k_rmsnorm<<<MT,256,0,stream>>>(R1, ln2_1, R2);                             // h2=R2
  // FFN in 4 column-chunks of 1024
  for (int c = 0; c < 4; c++){
    k_gemm_dual_mfma<<<dim3(1024/64, MT/128),256,0,stream>>>(R2, wg1 + (size_t)c*1024, wu1 + (size_t)c*1024,
                                                  R3, Ddim, FFNdim, 1024);
    k_gemm_mfma<<<dim3(Ddim/128, MT/128),256,0,stream>>>(R3, wd1 + (size_t)c*1024*Ddim, R0,
                                             (c==0 ? R1 : R0), 1024, Ddim, Ddim);
  }
  // proc = R0

  // ---- prior / gate / select ----
  k_rmsnorm<<<MT,256,0,stream>>>(hidden, prior_norm, R1);                  // ph=R1
  k_gemm_mfma<<<dim3(2*Ddim/128, MT/128),256,0,stream>>>(R1, prior_w, R2, nullptr, Ddim, 2*Ddim, 2*Ddim); // ml
  k_dstch<<<MT,256,0,stream>>>(R0, hidden, R2, dstb, dchb);
  k_gate<<<1,1024,0,stream>>>(dstb, dchb, gb);
  k_select<<<Bdim,1024,0,stream>>>(gb, selidx, selsc);
  k_gather<<<dim3(KSEL,Bdim),256,0,stream>>>(R0, selidx, R1);              // selx = R1[0..Q)

  // ---- layer 2 (4x256 selected tokens) ----
  k_rmsnorm<<<M2,256,0,stream>>>(R1, ln1_2, R2);                            // h = R2[0..Q)
  dim3 gD2(Ddim/128, M2/128);
  k_gemm_mfma<<<gD2,256,0,stream>>>(R2, wq2, R2+Q,   nullptr, Ddim, Ddim, Ddim); // q2
  k_gemm_mfma<<<gD2,256,0,stream>>>(R2, wk2, R2+2*Q, nullptr, Ddim, Ddim, Ddim); // k2
  k_gemm_mfma<<<gD2,256,0,stream>>>(R2, wv2, R2+3*Q, nullptr, Ddim, Ddim, Ddim); // v2
  int nr2 = M2*Hdim*32;
  k_rope<<<(nr2+255)/256,256,0,stream>>>(R2+Q,   selidx, KSEL, nr2);
  k_rope<<<(nr2+255)/256,256,0,stream>>>(R2+2*Q, selidx, KSEL, nr2);
  k_attn_mfma<<<dim3(KSEL/64,Hdim,Bdim),256,0,stream>>>(R2+Q, R2+2*Q, R2+3*Q, R3, KSEL); // o2=R3
  k_gemm_mfma<<<gD2,256,0,stream>>>(R3, wo2, R3+Q, R1, Ddim, Ddim, Ddim);            // x12 (+selx)
  k_rmsnorm<<<M2,256,0,stream>>>(R3+Q, ln2_2, R3+2*Q);                               // h22
  for (int c = 0; c < 4; c++){
    k_gemm_dual_mfma<<<dim3(1024/64, M2/128),256,0,stream>>>(R3+2*Q, wg2 + (size_t)c*1024, wu2 + (size_t)c*1024,
                                                  R3+3*Q, Ddim, FFNdim, 1024);
    k_gemm_mfma<<<dim3(Ddim/128, M2/128),256,0,stream>>>(R3+3*Q, wd2 + (size_t)c*1024*Ddim, R2,
                                             (c==0 ? R3+Q : R2), 1024, Ddim, Ddim);
  }
  // y = R2[0..Q)

  // ---- output ----
  k_out<<<(n+255)/256,256,0,stream>>>(R0, (float*)d_out, n);
  k_scatter<<<dim3(KSEL,Bdim),256,0,stream>>>(R1, R2, selsc, selidx, (float*)d_out);
}

// Round 4
// 1902.195 us; speedup vs baseline: 1.9995x; 1.0110x over previous
//
#include <hip/hip_runtime.h>
#include <math.h>

#define Bdim 4
#define Tdim 1024
#define Ddim 1024
#define Hdim 16
#define DHdim 64
#define FFNdim 4096
#define KSEL 256
#define EPSf 1e-6f

typedef __attribute__((ext_vector_type(8))) short bf16x8;   // 8 bf16 = 4 VGPR
typedef __attribute__((ext_vector_type(4))) float f32x4;
typedef __attribute__((ext_vector_type(4))) unsigned int u32x4;
typedef unsigned short ushort_t;

#define MFMA_BF16(a,b,c) __builtin_amdgcn_mfma_f32_16x16x32_bf16(a,b,c,0,0,0)

__device__ __forceinline__ int clamp_row(int r){ return r < 0 ? 0 : (r > Tdim-1 ? Tdim-1 : r); }

// split 8 fp32 into bf16 hi (truncate) + bf16 lo (exact remainder, truncated).
__device__ __forceinline__ void split8(const float* xs, u32x4* hi, u32x4* lo){
  unsigned int hm[8], lm[8];
  #pragma unroll
  for (int i=0;i<8;i++){
    unsigned int b = __float_as_uint(xs[i]);
    hm[i] = b & 0xFFFF0000u;
    lm[i] = __float_as_uint(xs[i] - __uint_as_float(hm[i]));
  }
  u32x4 h, l;
  #pragma unroll
  for (int i=0;i<4;i++){
    h[i] = (hm[2*i] >> 16) | hm[2*i+1];
    l[i] = (lm[2*i] >> 16) | (lm[2*i+1] & 0xFFFF0000u);
  }
  *hi = h; *lo = l;
}

__device__ __forceinline__ void split1(float x, unsigned int* h16, unsigned int* l16){
  unsigned int b = __float_as_uint(x);
  unsigned int hm = b & 0xFFFF0000u;
  *h16 = hm >> 16;
  *l16 = __float_as_uint(x - __uint_as_float(hm)) >> 16;
}

// ---------------- fallback (diagnostic): out = hidden ----------------
__global__ void k_fallback(const float* __restrict__ in, float* __restrict__ out, int n){
  int i = blockIdx.x*blockDim.x + threadIdx.x;
  if (i < n) out[i] = in[i];
}

__global__ void k_init_sel(int* __restrict__ selidx, float* __restrict__ selsc, int n){
  int i = blockIdx.x*blockDim.x + threadIdx.x;
  if (i < n){ selidx[i] = i & (KSEL-1); selsc[i] = 0.f; }
}

// ---------------- rmsnorm (fp32 out, old path) ----------------
__global__ __launch_bounds__(256) void k_rmsnorm(const float* __restrict__ x, const float* __restrict__ w,
                          float* __restrict__ y){
  int tok = blockIdx.x;
  const float* xp = x + (size_t)tok*Ddim;
  float* yp = y + (size_t)tok*Ddim;
  int tid = threadIdx.x;
  float s = 0.f;
  float xv[4];
  #pragma unroll
  for (int u = 0; u < 4; u++){ xv[u] = xp[tid + 256*u]; s += xv[u]*xv[u]; }
  __shared__ float red[256];
  red[tid]=s; __syncthreads();
  for (int st=128; st>0; st>>=1){ if (tid<st) red[tid]+=red[tid+st]; __syncthreads(); }
  float r = 1.0f/sqrtf(red[0]/(float)Ddim + EPSf);
  #pragma unroll
  for (int u = 0; u < 4; u++) yp[tid + 256*u] = xv[u]*r*w[tid + 256*u];
}

// rmsnorm emitting bf16 hi/lo planes
__global__ __launch_bounds__(256) void k_rmsnorm_sp(const float* __restrict__ x, const float* __restrict__ w,
                          ushort_t* __restrict__ yh, ushort_t* __restrict__ yl){
  int tok = blockIdx.x;
  const float* xp = x + (size_t)tok*Ddim;
  size_t ybase = (size_t)tok*Ddim;
  int tid = threadIdx.x;
  float s = 0.f;
  float xv[4];
  #pragma unroll
  for (int u = 0; u < 4; u++){ xv[u] = xp[tid + 256*u]; s += xv[u]*xv[u]; }
  __shared__ float red[256];
  red[tid]=s; __syncthreads();
  for (int st=128; st>0; st>>=1){ if (tid<st) red[tid]+=red[tid+st]; __syncthreads(); }
  float r = 1.0f/sqrtf(red[0]/(float)Ddim + EPSf);
  #pragma unroll
  for (int u = 0; u < 4; u++){
    float yv = xv[u]*r*w[tid + 256*u];
    unsigned int h16,l16; split1(yv,&h16,&l16);
    yh[ybase + tid + 256*u] = (ushort_t)h16;
    yl[ybase + tid + 256*u] = (ushort_t)l16;
  }
}

// rope in-place fp32 (old path)
__global__ void k_rope(float* __restrict__ x, const int* __restrict__ posidx, int S, int n){
  int e = blockIdx.x*blockDim.x + threadIdx.x;
  if (e >= n) return;
  int j = e & 31;
  int q = e >> 9;
  int t = q % S;
  float pos = posidx ? (float)clamp_row(posidx[q]) : (float)t;
  float inv = exp2f(-0.4152410118609203f * (float)j);
  float ang = pos * inv;
  float c = cosf(ang), s = sinf(ang);
  size_t base = ((size_t)(e >> 5)) * 64;
  float x1 = x[base + j], x2 = x[base + 32 + j];
  x[base + j]      = x1*c - x2*s;
  x[base + 32 + j] = x2*c + x1*s;
}

// rope reading fp32, writing bf16 hi/lo planes
__global__ void k_rope_sp(const float* __restrict__ x, const int* __restrict__ posidx, int S, int n,
                          ushort_t* __restrict__ Xh, ushort_t* __restrict__ Xl){
  int e = blockIdx.x*blockDim.x + threadIdx.x;
  if (e >= n) return;
  int j = e & 31;
  int q = e >> 9;
  int t = q % S;
  float pos = posidx ? (float)clamp_row(posidx[q]) : (float)t;
  float inv = exp2f(-0.4152410118609203f * (float)j);
  float ang = pos * inv;
  float c = cosf(ang), s = sinf(ang);
  size_t base = ((size_t)(e >> 5)) * 64;
  float x1 = x[base + j], x2 = x[base + 32 + j];
  float y1 = x1*c - x2*s;
  float y2 = x2*c + x1*s;
  unsigned int h16,l16;
  split1(y1,&h16,&l16); Xh[base + j] = (ushort_t)h16; Xl[base + j] = (ushort_t)l16;
  split1(y2,&h16,&l16); Xh[base + 32 + j] = (ushort_t)h16; Xl[base + 32 + j] = (ushort_t)l16;
}

// weight pre-split: W[K][N] fp32 -> transposed planes Wh/Wl [N][K] (LDS transpose tile 64x64)
__global__ __launch_bounds__(256) void k_split_w(const float* __restrict__ W,
                          ushort_t* __restrict__ Wh, ushort_t* __restrict__ Wl, int K, int N){
  __shared__ float fs[64][65];
  int n0 = blockIdx.x*64, k0 = blockIdx.y*64;
  int tid = threadIdx.x;
  #pragma unroll
  for (int i=0;i<16;i++){
    int idx = tid + 256*i;
    int r = idx >> 6, c = idx & 63;
    fs[r][c] = W[(size_t)(k0 + r)*N + n0 + c];
  }
  __syncthreads();
  int n = tid >> 2, kq = tid & 3;
  unsigned int hw[8], lw[8];
  #pragma unroll
  for (int i=0;i<16;i+=2){
    float v0 = fs[kq*16+i][n], v1 = fs[kq*16+i+1][n];
    unsigned int h0,l0,h1,l1;
    split1(v0,&h0,&l0); split1(v1,&h1,&l1);
    hw[i>>1] = h0 | (h1<<16);
    lw[i>>1] = l0 | (l1<<16);
  }
  size_t base = (size_t)(n0+n)*K + k0 + kq*16;
  u32x4 a = {hw[0],hw[1],hw[2],hw[3]};
  u32x4 b = {hw[4],hw[5],hw[6],hw[7]};
  *(u32x4*)&Wh[base] = a;
  *(u32x4*)&Wh[base+8] = b;
  u32x4 c2 = {lw[0],lw[1],lw[2],lw[3]};
  u32x4 d2 = {lw[4],lw[5],lw[6],lw[7]};
  *(u32x4*)&Wl[base] = c2;
  *(u32x4*)&Wl[base+8] = d2;
}

// ---------------- MFMA flash attention (old path: fp32 in, split on stage) ----------------
__global__ __launch_bounds__(256) void k_attn_mfma(const float* __restrict__ q, const float* __restrict__ k,
                       const float* __restrict__ v, float* __restrict__ o, int S){
  __shared__ ushort_t Kh[64*64], Kl[64*64];
  __shared__ ushort_t Vh[64*64], Vl[64*64];
  __shared__ float Pds[4*16*68];
  const int qt = blockIdx.x, h = blockIdx.y, b = blockIdx.z;
  const int q0 = qt*64;
  const int tid = threadIdx.x;
  const int lane = tid & 63;
  const int ln15 = lane & 15, lk = lane >> 4;
  const int wv = tid >> 6;
  const int qbase = wv*16;
  bf16x8 qa_h[2], qa_l[2];
  {
    const float* qp = q + (((size_t)b*S + q0 + qbase + ln15)*Hdim + h)*64 + lk*8;
    #pragma unroll
    for (int ks=0; ks<2; ks++){
      float xs[8];
      #pragma unroll
      for (int i=0;i<8;i++) xs[i] = qp[ks*32 + i];
      u32x4 hi, lo; split8(xs, &hi, &lo);
      qa_h[ks] = *(bf16x8*)&hi;
      qa_l[ks] = *(bf16x8*)&lo;
    }
  }
  float m_i[4], l_i[4];
  f32x4 oacc[4];
  #pragma unroll
  for (int r=0;r<4;r++){ m_i[r] = -3.4e38f; l_i[r] = 0.f; }
  #pragma unroll
  for (int fd=0;fd<4;fd++){ f32x4 z = {0.f,0.f,0.f,0.f}; oacc[fd] = z; }
  float* Pw = Pds + wv*(16*68);
  for (int j0 = 0; j0 <= q0; j0 += 64){
    __syncthreads();
    {
      int row = tid >> 2;
      int s0 = (tid & 3)*2;
      const float* kp = k + (((size_t)b*S + j0 + row)*Hdim + h)*64 + s0*8;
      #pragma unroll
      for (int g=0; g<2; g++){
        int slot = s0 + g;
        float xs[8];
        #pragma unroll
        for (int i=0;i<8;i++) xs[i] = kp[g*8 + i];
        u32x4 hi, lo; split8(xs, &hi, &lo);
        int base = row*64 + ((slot ^ (row&7))*8);
        *(u32x4*)&Kh[base] = hi;
        *(u32x4*)&Kl[base] = lo;
      }
    }
    {
      int j = tid & 31;
      int dbase = (tid >> 5)*8;
      const float* vp0 = v + (((size_t)b*S + j0 + 2*j)*Hdim + h)*64 + dbase;
      const float* vp1 = vp0 + (size_t)Hdim*64;
      float x0[8], x1[8];
      #pragma unroll
      for (int i=0;i<8;i++){ x0[i]=vp0[i]; x1[i]=vp1[i]; }
      unsigned int* VhW = (unsigned int*)Vh;
      unsigned int* VlW = (unsigned int*)Vl;
      #pragma unroll
      for (int i=0;i<8;i++){
        int d = dbase + i;
        unsigned int h0,l0,h1,l1;
        split1(x0[i], &h0, &l0); split1(x1[i], &h1, &l1);
        int off = d*32 + (((j>>2) ^ (d&7))*4) + (j&3);
        VhW[off] = h0 | (h1<<16);
        VlW[off] = l0 | (l1<<16);
      }
    }
    __syncthreads();
    f32x4 sacc[4];
    #pragma unroll
    for (int fj=0;fj<4;fj++){ f32x4 z = {0.f,0.f,0.f,0.f}; sacc[fj] = z; }
    #pragma unroll
    for (int ks=0; ks<2; ks++){
      #pragma unroll
      for (int fj=0;fj<4;fj++){
        int kr = fj*16 + ln15;
        int idx = kr*64 + (((ks*4+lk) ^ (kr&7))*8);
        bf16x8 kb_h = *(const bf16x8*)&Kh[idx];
        bf16x8 kb_l = *(const bf16x8*)&Kl[idx];
        sacc[fj] = MFMA_BF16(qa_h[ks], kb_h, sacc[fj]);
        sacc[fj] = MFMA_BF16(qa_h[ks], kb_l, sacc[fj]);
        sacc[fj] = MFMA_BF16(qa_l[ks], kb_h, sacc[fj]);
      }
    }
    #pragma unroll
    for (int fj=0;fj<4;fj++){
      int key = j0 + fj*16 + ln15;
      #pragma unroll
      for (int r=0;r<4;r++){
        float sv = sacc[fj][r]*0.125f;
        int qrow = q0 + qbase + lk*4 + r;
        sacc[fj][r] = (key > qrow) ? -3.4e38f : sv;
      }
    }
    float p[4][4];
    #pragma unroll
    for (int r=0;r<4;r++){
      float mt = fmaxf(fmaxf(sacc[0][r],sacc[1][r]), fmaxf(sacc[2][r],sacc[3][r]));
      #pragma unroll
      for (int off=1; off<16; off<<=1) mt = fmaxf(mt, __shfl_xor(mt, off));
      float m_new = fmaxf(m_i[r], mt);
      float alpha = expf(m_i[r] - m_new);
      float rs = 0.f;
      #pragma unroll
      for (int fj=0;fj<4;fj++){
        p[fj][r] = expf(sacc[fj][r] - m_new);
        rs += p[fj][r];
      }
      #pragma unroll
      for (int off=1; off<16; off<<=1) rs += __shfl_xor(rs, off);
      l_i[r] = l_i[r]*alpha + rs;
      m_i[r] = m_new;
      #pragma unroll
      for (int fd=0;fd<4;fd++) oacc[fd][r] *= alpha;
    }
    #pragma unroll
    for (int fj=0;fj<4;fj++)
      #pragma unroll
      for (int r=0;r<4;r++)
        Pw[(lk*4+r)*68 + fj*16 + ln15] = p[fj][r];
    #pragma unroll
    for (int ks=0; ks<2; ks++){
      f32x4 pf0 = *(const f32x4*)&Pw[ln15*68 + ks*32 + lk*8];
      f32x4 pf1 = *(const f32x4*)&Pw[ln15*68 + ks*32 + lk*8 + 4];
      float xs[8] = {pf0[0],pf0[1],pf0[2],pf0[3],pf1[0],pf1[1],pf1[2],pf1[3]};
      u32x4 hi, lo; split8(xs, &hi, &lo);
      bf16x8 pa_h = *(bf16x8*)&hi;
      bf16x8 pa_l = *(bf16x8*)&lo;
      #pragma unroll
      for (int fd=0;fd<4;fd++){
        int d = fd*16 + ln15;
        int idx = d*64 + (((ks*4+lk) ^ (d&7))*8);
        bf16x8 vb_h = *(const bf16x8*)&Vh[idx];
        bf16x8 vb_l = *(const bf16x8*)&Vl[idx];
        oacc[fd] = MFMA_BF16(pa_h, vb_h, oacc[fd]);
        oacc[fd] = MFMA_BF16(pa_h, vb_l, oacc[fd]);
        oacc[fd] = MFMA_BF16(pa_l, vb_h, oacc[fd]);
      }
    }
  }
  #pragma unroll
  for (int r=0;r<4;r++){
    float inv_l = 1.0f/l_i[r];
    #pragma unroll
    for (int fd=0;fd<4;fd++){
      o[(((size_t)b*S + q0 + qbase + lk*4 + r)*Hdim + h)*64 + fd*16 + ln15] = oacc[fd][r]*inv_l;
    }
  }
}

// ---------------- MFMA flash attention (new path: all inputs/outputs pre-split planes) ----------------
__global__ __launch_bounds__(256) void k_attn_ps(
    const ushort_t* __restrict__ Qph, const ushort_t* __restrict__ Qpl,
    const ushort_t* __restrict__ Kph, const ushort_t* __restrict__ Kpl,
    const ushort_t* __restrict__ Vph, const ushort_t* __restrict__ Vpl,
    ushort_t* __restrict__ Oh, ushort_t* __restrict__ Ol, int S){
  __shared__ ushort_t Kh[64*64], Kl[64*64];
  __shared__ ushort_t Vh[64*64], Vl[64*64];
  __shared__ float Pds[4*16*68];
  const int qt = blockIdx.x, h = blockIdx.y, b = blockIdx.z;
  const int q0 = qt*64;
  const int tid = threadIdx.x;
  const int lane = tid & 63;
  const int ln15 = lane & 15, lk = lane >> 4;
  const int wv = tid >> 6;
  const int qbase = wv*16;
  bf16x8 qa_h[2], qa_l[2];
  {
    size_t qoff = (((size_t)b*S + q0 + qbase + ln15)*Hdim + h)*64;
    #pragma unroll
    for (int ks=0; ks<2; ks++){
      qa_h[ks] = *(const bf16x8*)&Qph[qoff + ks*32 + lk*8];
      qa_l[ks] = *(const bf16x8*)&Qpl[qoff + ks*32 + lk*8];
    }
  }
  float m_i[4], l_i[4];
  f32x4 oacc[4];
  #pragma unroll
  for (int r=0;r<4;r++){ m_i[r] = -3.4e38f; l_i[r] = 0.f; }
  #pragma unroll
  for (int fd=0;fd<4;fd++){ f32x4 z = {0.f,0.f,0.f,0.f}; oacc[fd] = z; }
  float* Pw = Pds + wv*(16*68);
  for (int j0 = 0; j0 <= q0; j0 += 64){
    __syncthreads();
    // K stage: plane copy with swizzle
    #pragma unroll
    for (int g=0; g<2; g++){
      int row = g*32 + (tid >> 3);
      int ks = tid & 7;
      size_t ga = (((size_t)b*S + j0 + row)*Hdim + h)*64 + ks*8;
      u32x4 hi = *(const u32x4*)&Kph[ga];
      u32x4 lo = *(const u32x4*)&Kpl[ga];
      int base = row*64 + ((ks ^ (row&7))*8);
      *(u32x4*)&Kh[base] = hi;
      *(u32x4*)&Kl[base] = lo;
    }
    // V stage: transpose repack from planes
    {
      int j = tid & 31;
      int dbase = (tid >> 5)*8;
      size_t g0 = (((size_t)b*S + j0 + 2*j)*Hdim + h)*64 + dbase;
      size_t g1 = g0 + (size_t)Hdim*64;
      u32x4 ah = *(const u32x4*)&Vph[g0];
      u32x4 bh = *(const u32x4*)&Vph[g1];
      u32x4 al = *(const u32x4*)&Vpl[g0];
      u32x4 bl = *(const u32x4*)&Vpl[g1];
      unsigned int* VhW = (unsigned int*)Vh;
      unsigned int* VlW = (unsigned int*)Vl;
      #pragma unroll
      for (int i=0;i<4;i++){
        int d0 = dbase + 2*i, d1 = d0 + 1;
        int off0 = d0*32 + (((j>>2) ^ (d0&7))*4) + (j&3);
        int off1 = d1*32 + (((j>>2) ^ (d1&7))*4) + (j&3);
        VhW[off0] = (ah[i] & 0xFFFFu) | (bh[i] << 16);
        VhW[off1] = (ah[i] >> 16)     | (bh[i] & 0xFFFF0000u);
        VlW[off0] = (al[i] & 0xFFFFu) | (bl[i] << 16);
        VlW[off1] = (al[i] >> 16)     | (bl[i] & 0xFFFF0000u);
      }
    }
    __syncthreads();
    f32x4 sacc[4];
    #pragma unroll
    for (int fj=0;fj<4;fj++){ f32x4 z = {0.f,0.f,0.f,0.f}; sacc[fj] = z; }
    #pragma unroll
    for (int ks=0; ks<2; ks++){
      #pragma unroll
      for (int fj=0;fj<4;fj++){
        int kr = fj*16 + ln15;
        int idx = kr*64 + (((ks*4+lk) ^ (kr&7))*8);
        bf16x8 kb_h = *(const bf16x8*)&Kh[idx];
        bf16x8 kb_l = *(const bf16x8*)&Kl[idx];
        sacc[fj] = MFMA_BF16(qa_h[ks], kb_h, sacc[fj]);
        sacc[fj] = MFMA_BF16(qa_h[ks], kb_l, sacc[fj]);
        sacc[fj] = MFMA_BF16(qa_l[ks], kb_h, sacc[fj]);
      }
    }
    #pragma unroll
    for (int fj=0;fj<4;fj++){
      int key = j0 + fj*16 + ln15;
      #pragma unroll
      for (int r=0;r<4;r++){
        float sv = sacc[fj][r]*0.125f;
        int qrow = q0 + qbase + lk*4 + r;
        sacc[fj][r] = (key > qrow) ? -3.4e38f : sv;
      }
    }
    float p[4][4];
    #pragma unroll
    for (int r=0;r<4;r++){
      float mt = fmaxf(fmaxf(sacc[0][r],sacc[1][r]), fmaxf(sacc[2][r],sacc[3][r]));
      #pragma unroll
      for (int off=1; off<16; off<<=1) mt = fmaxf(mt, __shfl_xor(mt, off));
      float m_new = fmaxf(m_i[r], mt);
      float alpha = expf(m_i[r] - m_new);
      float rs = 0.f;
      #pragma unroll
      for (int fj=0;fj<4;fj++){
        p[fj][r] = expf(sacc[fj][r] - m_new);
        rs += p[fj][r];
      }
      #pragma unroll
      for (int off=1; off<16; off<<=1) rs += __shfl_xor(rs, off);
      l_i[r] = l_i[r]*alpha + rs;
      m_i[r] = m_new;
      #pragma unroll
      for (int fd=0;fd<4;fd++) oacc[fd][r] *= alpha;
    }
    #pragma unroll
    for (int fj=0;fj<4;fj++)
      #pragma unroll
      for (int r=0;r<4;r++)
        Pw[(lk*4+r)*68 + fj*16 + ln15] = p[fj][r];
    #pragma unroll
    for (int ks=0; ks<2; ks++){
      f32x4 pf0 = *(const f32x4*)&Pw[ln15*68 + ks*32 + lk*8];
      f32x4 pf1 = *(const f32x4*)&Pw[ln15*68 + ks*32 + lk*8 + 4];
      float xs[8] = {pf0[0],pf0[1],pf0[2],pf0[3],pf1[0],pf1[1],pf1[2],pf1[3]};
      u32x4 hi, lo; split8(xs, &hi, &lo);
      bf16x8 pa_h = *(bf16x8*)&hi;
      bf16x8 pa_l = *(bf16x8*)&lo;
      #pragma unroll
      for (int fd=0;fd<4;fd++){
        int d = fd*16 + ln15;
        int idx = d*64 + (((ks*4+lk) ^ (d&7))*8);
        bf16x8 vb_h = *(const bf16x8*)&Vh[idx];
        bf16x8 vb_l = *(const bf16x8*)&Vl[idx];
        oacc[fd] = MFMA_BF16(pa_h, vb_h, oacc[fd]);
        oacc[fd] = MFMA_BF16(pa_h, vb_l, oacc[fd]);
        oacc[fd] = MFMA_BF16(pa_l, vb_h, oacc[fd]);
      }
    }
  }
  #pragma unroll
  for (int r=0;r<4;r++){
    float inv_l = 1.0f/l_i[r];
    #pragma unroll
    for (int fd=0;fd<4;fd++){
      float val = oacc[fd][r]*inv_l;
      unsigned int h16,l16; split1(val,&h16,&l16);
      size_t cix = (((size_t)b*S + q0 + qbase + lk*4 + r)*Hdim + h)*64 + fd*16 + ln15;
      Oh[cix] = (ushort_t)h16;
      Ol[cix] = (ushort_t)l16;
    }
  }
}

// ---- OLD MFMA GEMM (fp32 sources, split on stage) ----
__global__ __launch_bounds__(256) void k_gemm_mfma(
    const float* __restrict__ A, const float* __restrict__ W,
    float* __restrict__ C, const float* __restrict__ addv,
    int K, int ldw, int ldc){
  __shared__ ushort_t Ah[128*32], Al[128*32], Bh[128*32], Bl[128*32];
  const int tid = threadIdx.x;
  const int row0 = blockIdx.y*128, col0 = blockIdx.x*128;
  const int lane = tid & 63;
  const int ln15 = lane & 15, lk = lane >> 4;
  const int wv = tid >> 6;
  const int wrow0 = (wv >> 1)*64, wcol0 = (wv & 1)*64;
  const int arow = tid >> 2;
  const int aks  = tid & 3;
  const int bcol = tid & 127;
  const int bks0 = tid >> 7;
  f32x4 acc[4][4];
  #pragma unroll
  for (int i=0;i<4;i++)
    #pragma unroll
    for (int j=0;j<4;j++){ f32x4 z = {0.f,0.f,0.f,0.f}; acc[i][j] = z; }
  for (int k0 = 0; k0 < K; k0 += 32){
    #pragma unroll
    for (int g=0; g<2; g++){
      int row = g*64 + arow;
      const float* ap = A + (size_t)(row0+row)*K + k0 + aks*8;
      float xs[8];
      #pragma unroll
      for (int i=0;i<8;i++) xs[i] = ap[i];
      u32x4 hi, lo; split8(xs, &hi, &lo);
      int base = row*32 + ((aks ^ ((row>>1)&3))*8);
      *(u32x4*)&Ah[base] = hi;
      *(u32x4*)&Al[base] = lo;
    }
    #pragma unroll
    for (int g=0; g<2; g++){
      int ks = bks0 + 2*g;
      const float* wp = W + (size_t)(k0 + ks*8)*ldw + col0 + bcol;
      float xs[8];
      #pragma unroll
      for (int i=0;i<8;i++) xs[i] = wp[(size_t)i*ldw];
      u32x4 hi, lo; split8(xs, &hi, &lo);
      int base = bcol*32 + ((ks ^ ((bcol>>1)&3))*8);
      *(u32x4*)&Bh[base] = hi;
      *(u32x4*)&Bl[base] = lo;
    }
    __syncthreads();
    bf16x8 ah[4], al[4];
    #pragma unroll
    for (int fi=0;fi<4;fi++){
      int r = wrow0 + fi*16 + ln15;
      int idx = r*32 + ((lk ^ ((r>>1)&3))*8);
      ah[fi] = *(const bf16x8*)&Ah[idx];
      al[fi] = *(const bf16x8*)&Al[idx];
    }
    #pragma unroll
    for (int fj=0;fj<4;fj++){
      int c = wcol0 + fj*16 + ln15;
      int idx = c*32 + ((lk ^ ((c>>1)&3))*8);
      bf16x8 bh = *(const bf16x8*)&Bh[idx];
      bf16x8 bl = *(const bf16x8*)&Bl[idx];
      #pragma unroll
      for (int fi=0;fi<4;fi++){
        acc[fi][fj] = MFMA_BF16(ah[fi], bh, acc[fi][fj]);
        acc[fi][fj] = MFMA_BF16(ah[fi], bl, acc[fi][fj]);
        acc[fi][fj] = MFMA_BF16(al[fi], bh, acc[fi][fj]);
      }
    }
    __syncthreads();
  }
  #pragma unroll
  for (int fi=0;fi<4;fi++){
    #pragma unroll
    for (int fj=0;fj<4;fj++){
      f32x4 v = acc[fi][fj];
      int cc = col0 + wcol0 + fj*16 + ln15;
      #pragma unroll
      for (int r=0;r<4;r++){
        size_t cix = (size_t)(row0 + wrow0 + fi*16 + lk*4 + r)*ldc + cc;
        float val = v[r];
        if (addv) val += addv[cix];
        C[cix] = val;
      }
    }
  }
}

// ---- NEW MFMA GEMM: pre-split planes in, fp32 or planes out ----
__global__ __launch_bounds__(256) void k_gemm_ps(
    const ushort_t* __restrict__ Ahp, const ushort_t* __restrict__ Alp, int lda,
    const ushort_t* __restrict__ Bhp, const ushort_t* __restrict__ Blp, int ldb,
    float* __restrict__ C, ushort_t* __restrict__ Chp, ushort_t* __restrict__ Clp,
    const float* __restrict__ addv, int K, int ldc){
  __shared__ ushort_t Ah[128*32], Al[128*32], Bh[128*32], Bl[128*32];
  const int tid = threadIdx.x;
  const int row0 = blockIdx.y*128, col0 = blockIdx.x*128;
  const int lane = tid & 63;
  const int ln15 = lane & 15, lk = lane >> 4;
  const int wv = tid >> 6;
  const int wrow0 = (wv >> 1)*64, wcol0 = (wv & 1)*64;
  const int t4 = tid >> 2, ks4 = tid & 3;
  f32x4 acc[4][4];
  #pragma unroll
  for (int i=0;i<4;i++)
    #pragma unroll
    for (int j=0;j<4;j++){ f32x4 z = {0.f,0.f,0.f,0.f}; acc[i][j] = z; }
  for (int k0 = 0; k0 < K; k0 += 32){
    #pragma unroll
    for (int g=0; g<2; g++){
      int row = g*64 + t4;
      size_t ga = (size_t)(row0+row)*lda + k0 + ks4*8;
      u32x4 hi = *(const u32x4*)&Ahp[ga];
      u32x4 lo = *(const u32x4*)&Alp[ga];
      int base = row*32 + ((ks4 ^ ((row>>1)&3))*8);
      *(u32x4*)&Ah[base] = hi;
      *(u32x4*)&Al[base] = lo;
      int col = g*64 + t4;
      size_t gb = (size_t)(col0+col)*ldb + k0 + ks4*8;
      u32x4 bhi = *(const u32x4*)&Bhp[gb];
      u32x4 blo = *(const u32x4*)&Blp[gb];
      int bbase = col*32 + ((ks4 ^ ((col>>1)&3))*8);
      *(u32x4*)&Bh[bbase] = bhi;
      *(u32x4*)&Bl[bbase] = blo;
    }
    __syncthreads();
    bf16x8 ah[4], al[4];
    #pragma unroll
    for (int fi=0;fi<4;fi++){
      int r = wrow0 + fi*16 + ln15;
      int idx = r*32 + ((lk ^ ((r>>1)&3))*8);
      ah[fi] = *(const bf16x8*)&Ah[idx];
      al[fi] = *(const bf16x8*)&Al[idx];
    }
    #pragma unroll
    for (int fj=0;fj<4;fj++){
      int c = wcol0 + fj*16 + ln15;
      int idx = c*32 + ((lk ^ ((c>>1)&3))*8);
      bf16x8 bh = *(const bf16x8*)&Bh[idx];
      bf16x8 bl = *(const bf16x8*)&Bl[idx];
      #pragma unroll
      for (int fi=0;fi<4;fi++){
        acc[fi][fj] = MFMA_BF16(ah[fi], bh, acc[fi][fj]);
        acc[fi][fj] = MFMA_BF16(ah[fi], bl, acc[fi][fj]);
        acc[fi][fj] = MFMA_BF16(al[fi], bh, acc[fi][fj]);
      }
    }
    __syncthreads();
  }
  if (Chp){
    #pragma unroll
    for (int fi=0;fi<4;fi++){
      #pragma unroll
      for (int fj=0;fj<4;fj++){
        f32x4 v = acc[fi][fj];
        int cc = col0 + wcol0 + fj*16 + ln15;
        #pragma unroll
        for (int r=0;r<4;r++){
          size_t cix = (size_t)(row0 + wrow0 + fi*16 + lk*4 + r)*ldc + cc;
          unsigned int h16,l16; split1(v[r],&h16,&l16);
          Chp[cix] = (ushort_t)h16;
          Clp[cix] = (ushort_t)l16;
        }
      }
    }
  } else {
    #pragma unroll
    for (int fi=0;fi<4;fi++){
      #pragma unroll
      for (int fj=0;fj<4;fj++){
        f32x4 v = acc[fi][fj];
        int cc = col0 + wcol0 + fj*16 + ln15;
        #pragma unroll
        for (int r=0;r<4;r++){
          size_t cix = (size_t)(row0 + wrow0 + fi*16 + lk*4 + r)*ldc + cc;
          float val = v[r];
          if (addv) val += addv[cix];
          C[cix] = val;
        }
      }
    }
  }
}

// ---- OLD fused SwiGLU MFMA (fp32 sources) ----
__global__ __launch_bounds__(256) void k_gemm_dual_mfma(
    const float* __restrict__ A, const float* __restrict__ Wg,
    const float* __restrict__ Wu, float* __restrict__ C,
    int K, int ldw, int ldc){
  __shared__ ushort_t Ah[128*32], Al[128*32];
  __shared__ ushort_t Gh[64*32], Gl[64*32], Uh[64*32], Ul[64*32];
  const int tid = threadIdx.x;
  const int row0 = blockIdx.y*128, col0 = blockIdx.x*64;
  const int lane = tid & 63;
  const int ln15 = lane & 15, lk = lane >> 4;
  const int wv = tid >> 6;
  const int wrow0 = (wv >> 1)*64, wcol0 = (wv & 1)*32;
  const int arow = tid >> 2;
  const int aks  = tid & 3;
  const int bcol = tid & 63;
  const int bks  = tid >> 6;
  f32x4 ag[4][2], au[4][2];
  #pragma unroll
  for (int i=0;i<4;i++)
    #pragma unroll
    for (int j=0;j<2;j++){ f32x4 z = {0.f,0.f,0.f,0.f}; ag[i][j] = z; au[i][j] = z; }
  for (int k0 = 0; k0 < K; k0 += 32){
    #pragma unroll
    for (int g=0; g<2; g++){
      int row = g*64 + arow;
      const float* ap = A + (size_t)(row0+row)*K + k0 + aks*8;
      float xs[8];
      #pragma unroll
      for (int i=0;i<8;i++) xs[i] = ap[i];
      u32x4 hi, lo; split8(xs, &hi, &lo);
      int base = row*32 + ((aks ^ ((row>>1)&3))*8);
      *(u32x4*)&Ah[base] = hi;
      *(u32x4*)&Al[base] = lo;
    }
    {
      int wbase = bcol*32 + ((bks ^ ((bcol>>1)&3))*8);
      const float* gp = Wg + (size_t)(k0 + bks*8)*ldw + col0 + bcol;
      float xs[8];
      #pragma unroll
      for (int i=0;i<8;i++) xs[i] = gp[(size_t)i*ldw];
      u32x4 hi, lo; split8(xs, &hi, &lo);
      *(u32x4*)&Gh[wbase] = hi;
      *(u32x4*)&Gl[wbase] = lo;
      const float* up = Wu + (size_t)(k0 + bks*8)*ldw + col0 + bcol;
      #pragma unroll
      for (int i=0;i<8;i++) xs[i] = up[(size_t)i*ldw];
      split8(xs, &hi, &lo);
      *(u32x4*)&Uh[wbase] = hi;
      *(u32x4*)&Ul[wbase] = lo;
    }
    __syncthreads();
    bf16x8 ah[4], al[4];
    #pragma unroll
    for (int fi=0;fi<4;fi++){
      int r = wrow0 + fi*16 + ln15;
      int idx = r*32 + ((lk ^ ((r>>1)&3))*8);
      ah[fi] = *(const bf16x8*)&Ah[idx];
      al[fi] = *(const bf16x8*)&Al[idx];
    }
    #pragma unroll
    for (int fj=0;fj<2;fj++){
      int c = wcol0 + fj*16 + ln15;
      int idx = c*32 + ((lk ^ ((c>>1)&3))*8);
      bf16x8 gh = *(const bf16x8*)&Gh[idx];
      bf16x8 gl = *(const bf16x8*)&Gl[idx];
      bf16x8 uh = *(const bf16x8*)&Uh[idx];
      bf16x8 ul = *(const bf16x8*)&Ul[idx];
      #pragma unroll
      for (int fi=0;fi<4;fi++){
        ag[fi][fj] = MFMA_BF16(ah[fi], gh, ag[fi][fj]);
        ag[fi][fj] = MFMA_BF16(ah[fi], gl, ag[fi][fj]);
        ag[fi][fj] = MFMA_BF16(al[fi], gh, ag[fi][fj]);
        au[fi][fj] = MFMA_BF16(ah[fi], uh, au[fi][fj]);
        au[fi][fj] = MFMA_BF16(ah[fi], ul, au[fi][fj]);
        au[fi][fj] = MFMA_BF16(al[fi], uh, au[fi][fj]);
      }
    }
    __syncthreads();
  }
  #pragma unroll
  for (int fi=0;fi<4;fi++){
    #pragma unroll
    for (int fj=0;fj<2;fj++){
      f32x4 vg = ag[fi][fj];
      f32x4 vu = au[fi][fj];
      int cc = col0 + wcol0 + fj*16 + ln15;
      #pragma unroll
      for (int r=0;r<4;r++){
        size_t cix = (size_t)(row0 + wrow0 + fi*16 + lk*4 + r)*ldc + cc;
        float gg = vg[r];
        C[cix] = (gg/(1.0f+expf(-gg))) * vu[r];
      }
    }
  }
}

// ---- NEW fused SwiGLU MFMA (planes in, act planes out) ----
__global__ __launch_bounds__(256) void k_gemm_dual_ps(
    const ushort_t* __restrict__ Ahp, const ushort_t* __restrict__ Alp, int lda,
    const ushort_t* __restrict__ Ghp, const ushort_t* __restrict__ Glp,
    const ushort_t* __restrict__ Uhp, const ushort_t* __restrict__ Ulp, int ldb,
    ushort_t* __restrict__ Chp, ushort_t* __restrict__ Clp, int K, int ldc){
  __shared__ ushort_t Ah[128*32], Al[128*32];
  __shared__ ushort_t Gh[64*32], Gl[64*32], Uh[64*32], Ul[64*32];
  const int tid = threadIdx.x;
  const int row0 = blockIdx.y*128, col0 = blockIdx.x*64;
  const int lane = tid & 63;
  const int ln15 = lane & 15, lk = lane >> 4;
  const int wv = tid >> 6;
  const int wrow0 = (wv >> 1)*64, wcol0 = (wv & 1)*32;
  const int t4 = tid >> 2, ks4 = tid & 3;
  f32x4 ag[4][2], au[4][2];
  #pragma unroll
  for (int i=0;i<4;i++)
    #pragma unroll
    for (int j=0;j<2;j++){ f32x4 z = {0.f,0.f,0.f,0.f}; ag[i][j] = z; au[i][j] = z; }
  for (int k0 = 0; k0 < K; k0 += 32){
    #pragma unroll
    for (int g=0; g<2; g++){
      int row = g*64 + t4;
      size_t ga = (size_t)(row0+row)*lda + k0 + ks4*8;
      u32x4 hi = *(const u32x4*)&Ahp[ga];
      u32x4 lo = *(const u32x4*)&Alp[ga];
      int base = row*32 + ((ks4 ^ ((row>>1)&3))*8);
      *(u32x4*)&Ah[base] = hi;
      *(u32x4*)&Al[base] = lo;
    }
    {
      int col = t4;  // 0..63
      size_t gb = (size_t)(col0+col)*ldb + k0 + ks4*8;
      int wbase = col*32 + ((ks4 ^ ((col>>1)&3))*8);
      *(u32x4*)&Gh[wbase] = *(const u32x4*)&Ghp[gb];
      *(u32x4*)&Gl[wbase] = *(const u32x4*)&Glp[gb];
      *(u32x4*)&Uh[wbase] = *(const u32x4*)&Uhp[gb];
      *(u32x4*)&Ul[wbase] = *(const u32x4*)&Ulp[gb];
    }
    __syncthreads();
    bf16x8 ah[4], al[4];
    #pragma unroll
    for (int fi=0;fi<4;fi++){
      int r = wrow0 + fi*16 + ln15;
      int idx = r*32 + ((lk ^ ((r>>1)&3))*8);
      ah[fi] = *(const bf16x8*)&Ah[idx];
      al[fi] = *(const bf16x8*)&Al[idx];
    }
    #pragma unroll
    for (int fj=0;fj<2;fj++){
      int c = wcol0 + fj*16 + ln15;
      int idx = c*32 + ((lk ^ ((c>>1)&3))*8);
      bf16x8 gh = *(const bf16x8*)&Gh[idx];
      bf16x8 gl = *(const bf16x8*)&Gl[idx];
      bf16x8 uh = *(const bf16x8*)&Uh[idx];
      bf16x8 ul = *(const bf16x8*)&Ul[idx];
      #pragma unroll
      for (int fi=0;fi<4;fi++){
        ag[fi][fj] = MFMA_BF16(ah[fi], gh, ag[fi][fj]);
        ag[fi][fj] = MFMA_BF16(ah[fi], gl, ag[fi][fj]);
        ag[fi][fj] = MFMA_BF16(al[fi], gh, ag[fi][fj]);
        au[fi][fj] = MFMA_BF16(ah[fi], uh, au[fi][fj]);
        au[fi][fj] = MFMA_BF16(ah[fi], ul, au[fi][fj]);
        au[fi][fj] = MFMA_BF16(al[fi], uh, au[fi][fj]);
      }
    }
    __syncthreads();
  }
  #pragma unroll
  for (int fi=0;fi<4;fi++){
    #pragma unroll
    for (int fj=0;fj<2;fj++){
      f32x4 vg = ag[fi][fj];
      f32x4 vu = au[fi][fj];
      int cc = col0 + wcol0 + fj*16 + ln15;
      #pragma unroll
      for (int r=0;r<4;r++){
        size_t cix = (size_t)(row0 + wrow0 + fi*16 + lk*4 + r)*ldc + cc;
        float gg = vg[r];
        float val = (gg/(1.0f+expf(-gg))) * vu[r];
        unsigned int h16,l16; split1(val,&h16,&l16);
        Chp[cix] = (ushort_t)h16;
        Clp[cix] = (ushort_t)l16;
      }
    }
  }
}

// ---------------- prior / gating ----------------
__global__ __launch_bounds__(256) void k_dstch(const float* __restrict__ proc, const float* __restrict__ x0,
                        const float* __restrict__ ml, float* __restrict__ dst, float* __restrict__ dch){
  int tok = blockIdx.x, tid = threadIdx.x;
  const float* pp = proc + (size_t)tok*Ddim;
  const float* xp = x0 + (size_t)tok*Ddim;
  const float* mu = ml + (size_t)tok*2*Ddim;
  const float* lv = mu + Ddim;
  float s1=0.f, s2=0.f;
  for (int i=tid;i<Ddim;i+=256){
    float r = pp[i]-xp[i];
    s1 += r*r;
    float t = r - mu[i];
    float l = lv[i];
    s2 += 0.5f*(l + (1.0f + t*t)*expf(-l) - 1.0f);
  }
  __shared__ float red[256], red2[256];
  red[tid]=s1; red2[tid]=s2; __syncthreads();
  for (int st=128; st>0; st>>=1){ if (tid<st){red[tid]+=red[tid+st]; red2[tid]+=red2[tid+st];} __syncthreads(); }
  if (tid==0){ dst[tok]=red[0]/(float)Ddim; dch[tok]=red2[0]/(float)Ddim; }
}

// variant with separate mu / logvar buffers
__global__ __launch_bounds__(256) void k_dstch2(const float* __restrict__ proc, const float* __restrict__ x0,
                        const float* __restrict__ muB, const float* __restrict__ lvB,
                        float* __restrict__ dst, float* __restrict__ dch){
  int tok = blockIdx.x, tid = threadIdx.x;
  const float* pp = proc + (size_t)tok*Ddim;
  const float* xp = x0 + (size_t)tok*Ddim;
  const float* mu = muB + (size_t)tok*Ddim;
  const float* lv = lvB + (size_t)tok*Ddim;
  float s1=0.f, s2=0.f;
  for (int i=tid;i<Ddim;i+=256){
    float r = pp[i]-xp[i];
    s1 += r*r;
    float t = r - mu[i];
    float l = lv[i];
    s2 += 0.5f*(l + (1.0f + t*t)*expf(-l) - 1.0f);
  }
  __shared__ float red[256], red2[256];
  red[tid]=s1; red2[tid]=s2; __syncthreads();
  for (int st=128; st>0; st>>=1){ if (tid<st){red[tid]+=red[tid+st]; red2[tid]+=red2[tid+st];} __syncthreads(); }
  if (tid==0){ dst[tok]=red[0]/(float)Ddim; dch[tok]=red2[0]/(float)Ddim; }
}

__global__ __launch_bounds__(1024) void k_gate(const float* __restrict__ dst, const float* __restrict__ dch,
                        float* __restrict__ g){
  int tid = threadIdx.x;
  float s1=0.f, s2=0.f;
  for (int i=tid; i<Bdim*Tdim; i+=1024){ s1+=dst[i]; s2+=dch[i]; }
  __shared__ float r1[1024], r2[1024];
  r1[tid]=s1; r2[tid]=s2; __syncthreads();
  for (int st=512; st>0; st>>=1){ if(tid<st){r1[tid]+=r1[tid+st]; r2[tid]+=r2[tid+st];} __syncthreads(); }
  float m1 = r1[0]/(float)(Bdim*Tdim), m2 = r2[0]/(float)(Bdim*Tdim);
  for (int i=tid; i<Bdim*Tdim; i+=1024){
    float z = (dst[i]-m1) + (dch[i]-m2);
    g[i] = 1.0f/(1.0f+expf(-z));
  }
}

__global__ __launch_bounds__(1024) void k_select(const float* __restrict__ g, int* __restrict__ selidx,
                         float* __restrict__ selsc){
  int b = blockIdx.x, t = threadIdx.x;
  __shared__ float gs[1024];
  __shared__ int flag[1024];
  float gv = g[b*Tdim + t];
  if (!(gv == gv)) gv = -3.4e38f;
  gs[t] = gv; __syncthreads();
  float gi = gs[t];
  int rank = 0;
  for (int j=0;j<Tdim;j++){
    float gj = gs[j];
    rank += (gj > gi) || (gj == gi && j < t);
  }
  int sel = (rank < KSEL) ? 1 : 0;
  flag[t] = sel; __syncthreads();
  if (sel){
    int pos = 0;
    for (int j=0;j<t;j++) pos += flag[j];
    if (pos < KSEL){
      selidx[b*KSEL+pos] = t;
      selsc[b*KSEL+pos] = gi;
    }
  }
}

__global__ __launch_bounds__(256) void k_gather(const float* __restrict__ proc, const int* __restrict__ selidx,
                         float* __restrict__ sel){
  int j = blockIdx.x, b = blockIdx.y, tid = threadIdx.x;
  int row = clamp_row(selidx[b*KSEL+j]);
  const float* src = proc + ((size_t)b*Tdim + row)*Ddim;
  float* dst = sel + ((size_t)b*KSEL + j)*Ddim;
  for (int d=tid; d<Ddim; d+=256) dst[d]=src[d];
}

__global__ void k_out(const float* __restrict__ proc, float* __restrict__ out, int n){
  int i = blockIdx.x*blockDim.x + threadIdx.x;
  if (i<n) out[i] = proc[i];
}

__global__ __launch_bounds__(256) void k_scatter(const float* __restrict__ sel, const float* __restrict__ y,
                          const float* __restrict__ selsc, const int* __restrict__ selidx,
                          float* __restrict__ out){
  int j = blockIdx.x, b = blockIdx.y, tid = threadIdx.x;
  int row = clamp_row(selidx[b*KSEL+j]);
  float s = selsc[b*KSEL+j];
  const float* sp = sel + ((size_t)b*KSEL + j)*Ddim;
  const float* yp = y + ((size_t)b*KSEL + j)*Ddim;
  float* op = out + ((size_t)b*Tdim + row)*Ddim;
  for (int d=tid; d<Ddim; d+=256){
    op[d] = sp[d] + s*(yp[d]-sp[d]);
  }
}

// ---------------- driver ----------------
extern "C" void kernel_launch(void* const* d_in, const int* in_sizes, int n_in,
                              void* d_out, int out_size, void* d_ws, size_t ws_size,
                              hipStream_t stream){
  (void)in_sizes; (void)n_in; (void)out_size;
  const float* hidden = (const float*)d_in[0];
  const float* wq1 = (const float*)d_in[1];
  const float* wk1 = (const float*)d_in[2];
  const float* wv1 = (const float*)d_in[3];
  const float* wo1 = (const float*)d_in[4];
  const float* wq2 = (const float*)d_in[5];
  const float* wk2 = (const float*)d_in[6];
  const float* wv2 = (const float*)d_in[7];
  const float* wo2 = (const float*)d_in[8];
  const float* wg1 = (const float*)d_in[9];
  const float* wu1 = (const float*)d_in[10];
  const float* wd1 = (const float*)d_in[11];
  const float* wg2 = (const float*)d_in[12];
  const float* wu2 = (const float*)d_in[13];
  const float* wd2 = (const float*)d_in[14];
  const float* ln1_1 = (const float*)d_in[15];
  const float* ln2_1 = (const float*)d_in[16];
  const float* ln1_2 = (const float*)d_in[17];
  const float* ln2_2 = (const float*)d_in[18];
  const float* prior_norm = (const float*)d_in[19];
  const float* prior_w = (const float*)d_in[20];

  const size_t A = (size_t)Bdim*Tdim*Ddim;      // 4M floats
  const size_t Q = (size_t)Bdim*KSEL*Ddim;      // 1M floats
  const int n = (int)A;
  const int MT = Bdim*Tdim;    // 4096
  const int M2 = Bdim*KSEL;    // 1024

  const size_t WELEMS = 34u*1024*1024;          // 34M weight elems -> 68M ushorts
  size_t need_old = (4*A + 16384) * sizeof(float);
  size_t need_new = need_old + 2*WELEMS*sizeof(ushort_t);

  if (ws_size < need_old){
    k_fallback<<<(n+255)/256,256,0,stream>>>(hidden, (float*)d_out, n);
    return;
  }

  float* ws = (float*)d_ws;
  float* R0 = ws;
  float* R1 = ws + 1*A;
  float* R2 = ws + 2*A;
  float* R3 = ws + 3*A;
  float* dstb = ws + 4*A;
  float* dchb = dstb + 4096;
  float* gb   = dchb + 4096;
  float* selsc= gb + 4096;
  int*   selidx = (int*)(selsc + 1024);

  k_init_sel<<<4,256,0,stream>>>(selidx, selsc, Bdim*KSEL);

  if (ws_size >= need_new){
    // ================= NEW PATH: pre-split bf16 planes =================
    ushort_t* wpb = (ushort_t*)(ws + 4*A + 16384);
    size_t cur = 0;
    const size_t M1x1 = (size_t)1024*1024;
    const size_t M1x4 = (size_t)1024*4096;
    #define ALLOCW(nm, KN) ushort_t* nm##_h = wpb + cur; ushort_t* nm##_l = wpb + cur + (KN); cur += 2*(size_t)(KN);
    ALLOCW(pwq1, M1x1) ALLOCW(pwk1, M1x1) ALLOCW(pwv1, M1x1) ALLOCW(pwo1, M1x1)
    ALLOCW(pwq2, M1x1) ALLOCW(pwk2, M1x1) ALLOCW(pwv2, M1x1) ALLOCW(pwo2, M1x1)
    ALLOCW(pwg1, M1x4) ALLOCW(pwu1, M1x4) ALLOCW(pwd1, M1x4)
    ALLOCW(pwg2, M1x4) ALLOCW(pwu2, M1x4) ALLOCW(pwd2, M1x4)
    ALLOCW(ppw, (size_t)2048*1024)
    #undef ALLOCW

    // pre-split all weights (transposed planes [N][K])
    k_split_w<<<dim3(16,16),256,0,stream>>>(wq1, pwq1_h, pwq1_l, 1024, 1024);
    k_split_w<<<dim3(16,16),256,0,stream>>>(wk1, pwk1_h, pwk1_l, 1024, 1024);
    k_split_w<<<dim3(16,16),256,0,stream>>>(wv1, pwv1_h, pwv1_l, 1024, 1024);
    k_split_w<<<dim3(16,16),256,0,stream>>>(wo1, pwo1_h, pwo1_l, 1024, 1024);
    k_split_w<<<dim3(16,16),256,0,stream>>>(wq2, pwq2_h, pwq2_l, 1024, 1024);
    k_split_w<<<dim3(16,16),256,0,stream>>>(wk2, pwk2_h, pwk2_l, 1024, 1024);
    k_split_w<<<dim3(16,16),256,0,stream>>>(wv2, pwv2_h, pwv2_l, 1024, 1024);
    k_split_w<<<dim3(16,16),256,0,stream>>>(wo2, pwo2_h, pwo2_l, 1024, 1024);
    k_split_w<<<dim3(64,16),256,0,stream>>>(wg1, pwg1_h, pwg1_l, 1024, 4096);
    k_split_w<<<dim3(64,16),256,0,stream>>>(wu1, pwu1_h, pwu1_l, 1024, 4096);
    k_split_w<<<dim3(16,64),256,0,stream>>>(wd1, pwd1_h, pwd1_l, 4096, 1024);
    k_split_w<<<dim3(64,16),256,0,stream>>>(wg2, pwg2_h, pwg2_l, 1024, 4096);
    k_split_w<<<dim3(64,16),256,0,stream>>>(wu2, pwu2_h, pwu2_l, 1024, 4096);
    k_split_w<<<dim3(16,64),256,0,stream>>>(wd2, pwd2_h, pwd2_l, 4096, 1024);
    k_split_w<<<dim3(32,16),256,0,stream>>>(prior_w, ppw_h, ppw_l, 1024, 2048);

    // ---- layer 1 ----
    ushort_t* Hh = (ushort_t*)R0; ushort_t* Hl = Hh + A;
    k_rmsnorm_sp<<<MT,256,0,stream>>>(hidden, ln1_1, Hh, Hl);
    dim3 gD(Ddim/128, MT/128);
    k_gemm_ps<<<gD,256,0,stream>>>(Hh,Hl,1024, pwq1_h,pwq1_l,1024, R1, nullptr,nullptr, nullptr, 1024, 1024); // q f32
    k_gemm_ps<<<gD,256,0,stream>>>(Hh,Hl,1024, pwk1_h,pwk1_l,1024, R2, nullptr,nullptr, nullptr, 1024, 1024); // k f32
    ushort_t* Vp_h = (ushort_t*)R3; ushort_t* Vp_l = Vp_h + A;
    k_gemm_ps<<<gD,256,0,stream>>>(Hh,Hl,1024, pwv1_h,pwv1_l,1024, nullptr, Vp_h, Vp_l, nullptr, 1024, 1024); // v planes
    int nr = MT*Hdim*32;
    ushort_t* Qp_h = (ushort_t*)R0; ushort_t* Qp_l = Qp_h + A;     // over h-planes (dead)
    k_rope_sp<<<(nr+255)/256,256,0,stream>>>(R1, nullptr, Tdim, nr, Qp_h, Qp_l);
    ushort_t* Kp_h = (ushort_t*)R1; ushort_t* Kp_l = Kp_h + A;     // over q f32 (dead)
    k_rope_sp<<<(nr+255)/256,256,0,stream>>>(R2, nullptr, Tdim, nr, Kp_h, Kp_l);
    ushort_t* Op_h = (ushort_t*)R2; ushort_t* Op_l = Op_h + A;     // over k f32 (dead)
    k_attn_ps<<<dim3(Tdim/64,Hdim,Bdim),256,0,stream>>>(Qp_h,Qp_l, Kp_h,Kp_l, Vp_h,Vp_l, Op_h,Op_l, Tdim);
    k_gemm_ps<<<gD,256,0,stream>>>(Op_h,Op_l,1024, pwo1_h,pwo1_l,1024, R1, nullptr,nullptr, hidden, 1024, 1024); // x1=R1
    ushort_t* H2h = (ushort_t*)R0; ushort_t* H2l = H2h + A;
    k_rmsnorm_sp<<<MT,256,0,stream>>>(R1, ln2_1, H2h, H2l);
    ushort_t* ACTh = (ushort_t*)R3; ushort_t* ACTl = ACTh + A;     // over v-planes (dead)
    for (int c = 0; c < 4; c++){
      k_gemm_dual_ps<<<dim3(16, MT/128),256,0,stream>>>(H2h,H2l,1024,
          pwg1_h + (size_t)c*M1x1, pwg1_l + (size_t)c*M1x1,
          pwu1_h + (size_t)c*M1x1, pwu1_l + (size_t)c*M1x1, 1024,
          ACTh, ACTl, 1024, 1024);
      k_gemm_ps<<<dim3(8, MT/128),256,0,stream>>>(ACTh,ACTl,1024,
          pwd1_h + (size_t)c*1024, pwd1_l + (size_t)c*1024, 4096,
          R2, nullptr,nullptr, (c==0 ? R1 : R2), 1024, 1024);
    }
    // proc = R2

    // ---- prior / gate / select ----
    ushort_t* PHh = (ushort_t*)R0; ushort_t* PHl = PHh + A;        // over h2-planes (dead)
    k_rmsnorm_sp<<<MT,256,0,stream>>>(hidden, prior_norm, PHh, PHl);
    k_gemm_ps<<<gD,256,0,stream>>>(PHh,PHl,1024, ppw_h, ppw_l, 1024, R1, nullptr,nullptr, nullptr, 1024, 1024);              // mu (x1 dead)
    k_gemm_ps<<<gD,256,0,stream>>>(PHh,PHl,1024, ppw_h + M1x1, ppw_l + M1x1, 1024, R3, nullptr,nullptr, nullptr, 1024, 1024); // logvar (act dead)
    k_dstch2<<<MT,256,0,stream>>>(R2, hidden, R1, R3, dstb, dchb);
    k_gate<<<1,1024,0,stream>>>(dstb, dchb, gb);
    k_select<<<Bdim,1024,0,stream>>>(gb, selidx, selsc);
    float* SELX = R0;                                               // over ph-planes (dead)
    k_gather<<<dim3(KSEL,Bdim),256,0,stream>>>(R2, selidx, SELX);

    // ---- layer 2 ----
    ushort_t* h2h = (ushort_t*)R1;        ushort_t* h2l = h2h + Q;       // R1 slot0
    k_rmsnorm_sp<<<M2,256,0,stream>>>(SELX, ln1_2, h2h, h2l);
    float* q2f = R1 + Q;                                                  // R1 slot1
    float* k2f = R1 + 2*Q;                                                // R1 slot2
    ushort_t* v2h = (ushort_t*)(R1 + 3*Q); ushort_t* v2l = v2h + Q;       // R1 slot3
    dim3 gD2(Ddim/128, M2/128);
    k_gemm_ps<<<gD2,256,0,stream>>>(h2h,h2l,1024, pwq2_h,pwq2_l,1024, q2f, nullptr,nullptr, nullptr, 1024, 1024);
    k_gemm_ps<<<gD2,256,0,stream>>>(h2h,h2l,1024, pwk2_h,pwk2_l,1024, k2f, nullptr,nullptr, nullptr, 1024, 1024);
    k_gemm_ps<<<gD2,256,0,stream>>>(h2h,h2l,1024, pwv2_h,pwv2_l,1024, nullptr, v2h, v2l, nullptr, 1024, 1024);
    int nr2 = M2*Hdim*32;
    ushort_t* q2ph = (ushort_t*)(R0 + Q);   ushort_t* q2pl = q2ph + Q;    // R0 slot1
    ushort_t* k2ph = (ushort_t*)(R0 + 2*Q); ushort_t* k2pl = k2ph + Q;    // R0 slot2
    k_rope_sp<<<(nr2+255)/256,256,0,stream>>>(q2f, selidx, KSEL, nr2, q2ph, q2pl);
    k_rope_sp<<<(nr2+255)/256,256,0,stream>>>(k2f, selidx, KSEL, nr2, k2ph, k2pl);
    ushort_t* o2h = (ushort_t*)(R0 + 3*Q);  ushort_t* o2l = o2h + Q;      // R0 slot3
    k_attn_ps<<<dim3(KSEL/64,Hdim,Bdim),256,0,stream>>>(q2ph,q2pl, k2ph,k2pl, v2h,v2l, o2h,o2l, KSEL);
    float* X12 = R1 + Q;                                                  // over q2f (dead)
    k_gemm_ps<<<gD2,256,0,stream>>>(o2h,o2l,1024, pwo2_h,pwo2_l,1024, X12, nullptr,nullptr, SELX, 1024, 1024);
    ushort_t* h22h = (ushort_t*)(R1 + 2*Q); ushort_t* h22l = h22h + Q;    // over k2f (dead)
    k_rmsnorm_sp<<<M2,256,0,stream>>>(X12, ln2_2, h22h, h22l);
    ushort_t* act2h = (ushort_t*)(R1 + 3*Q); ushort_t* act2l = act2h + Q; // over v2-planes (dead)
    float* Y = R3;                                                        // logvar dead
    for (int c = 0; c < 4; c++){
      k_gemm_dual_ps<<<dim3(16, M2/128),256,0,stream>>>(h22h,h22l,1024,
          pwg2_h + (size_t)c*M1x1, pwg2_l + (size_t)c*M1x1,
          pwu2_h + (size_t)c*M1x1, pwu2_l + (size_t)c*M1x1, 1024,
          act2h, act2l, 1024, 1024);
      k_gemm_ps<<<dim3(8, M2/128),256,0,stream>>>(act2h,act2l,1024,
          pwd2_h + (size_t)c*1024, pwd2_l + (size_t)c*1024, 4096,
          Y, nullptr,nullptr, (c==0 ? X12 : Y), 1024, 1024);
    }
    // ---- output ----
    k_out<<<(n+255)/256,256,0,stream>>>(R2, (float*)d_out, n);
    k_scatter<<<dim3(KSEL,Bdim),256,0,stream>>>(SELX, Y, selsc, selidx, (float*)d_out);
    return;
  }

  // ================= OLD PATH (round-3, verified) =================
  k_rmsnorm<<<MT,256,0,stream>>>(hidden, ln1_1, R0);
  dim3 gD(Ddim/128, MT/128);
  k_gemm_mfma<<<gD,256,0,stream>>>(R0, wq1, R1, nullptr, Ddim, Ddim, Ddim);
  k_gemm_mfma<<<gD,256,0,stream>>>(R0, wk1, R2, nullptr, Ddim, Ddim, Ddim);
  k_gemm_mfma<<<gD,256,0,stream>>>(R0, wv1, R3, nullptr, Ddim, Ddim, Ddim);
  int nr = MT*Hdim*32;
  k_rope<<<(nr+255)/256,256,0,stream>>>(R1, nullptr, Tdim, nr);
  k_rope<<<(nr+255)/256,256,0,stream>>>(R2, nullptr, Tdim, nr);
  k_attn_mfma<<<dim3(Tdim/64,Hdim,Bdim),256,0,stream>>>(R1, R2, R3, R0, Tdim);
  k_gemm_mfma<<<gD,256,0,stream>>>(R0, wo1, R1, hidden, Ddim, Ddim, Ddim);
  k_rmsnorm<<<MT,256,0,stream>>>(R1, ln2_1, R2);
  for (int c = 0; c < 4; c++){
    k_gemm_dual_mfma<<<dim3(1024/64, MT/128),256,0,stream>>>(R2, wg1 + (size_t)c*1024, wu1 + (size_t)c*1024,
                                                  R3, Ddim, FFNdim, 1024);
    k_gemm_mfma<<<dim3(Ddim/128, MT/128),256,0,stream>>>(R3, wd1 + (size_t)c*1024*Ddim, R0,
                                             (c==0 ? R1 : R0), 1024, Ddim, Ddim);
  }
  k_rmsnorm<<<MT,256,0,stream>>>(hidden, prior_norm, R1);
  k_gemm_mfma<<<dim3(2*Ddim/128, MT/128),256,0,stream>>>(R1, prior_w, R2, nullptr, Ddim, 2*Ddim, 2*Ddim);
  k_dstch<<<MT,256,0,stream>>>(R0, hidden, R2, dstb, dchb);
  k_gate<<<1,1024,0,stream>>>(dstb, dchb, gb);
  k_select<<<Bdim,1024,0,stream>>>(gb, selidx, selsc);
  k_gather<<<dim3(KSEL,Bdim),256,0,stream>>>(R0, selidx, R1);
  k_rmsnorm<<<M2,256,0,stream>>>(R1, ln1_2, R2);
  dim3 gD2(Ddim/128, M2/128);
  k_gemm_mfma<<<gD2,256,0,stream>>>(R2, wq2, R2+Q,   nullptr, Ddim, Ddim, Ddim);
  k_gemm_mfma<<<gD2,256,0,stream>>>(R2, wk2, R2+2*Q, nullptr, Ddim, Ddim, Ddim);
  k_gemm_mfma<<<gD2,256,0,stream>>>(R2, wv2, R2+3*Q, nullptr, Ddim, Ddim, Ddim);
  int nr2 = M2*Hdim*32;
  k_rope<<<(nr2+255)/256,256,0,stream>>>(R2+Q,   selidx, KSEL, nr2);
  k_rope<<<(nr2+255)/256,256,0,stream>>>(R2+2*Q, selidx, KSEL, nr2);
  k_attn_mfma<<<dim3(KSEL/64,Hdim,Bdim),256,0,stream>>>(R2+Q, R2+2*Q, R2+3*Q, R3, KSEL);
  k_gemm_mfma<<<gD2,256,0,stream>>>(R3, wo2, R3+Q, R1, Ddim, Ddim, Ddim);
  k_rmsnorm<<<M2,256,0,stream>>>(R3+Q, ln2_2, R3+2*Q);
  for (int c = 0; c < 4; c++){
    k_gemm_dual_mfma<<<dim3(1024/64, M2/128),256,0,stream>>>(R3+2*Q, wg2 + (size_t)c*1024, wu2 + (size_t)c*1024,
                                                  R3+3*Q, Ddim, FFNdim, 1024);
    k_gemm_mfma<<<dim3(Ddim/128, M2/128),256,0,stream>>>(R3+3*Q, wd2 + (size_t)c*1024*Ddim, R2,
                                             (c==0 ? R3+Q : R2), 1024, Ddim, Ddim);
  }
  k_out<<<(n+255)/256,256,0,stream>>>(R0, (float*)d_out, n);
  k_scatter<<<dim3(KSEL,Bdim),256,0,stream>>>(R1, R2, selsc, selidx, (float*)d_out);
}

// Round 5
// 1526.802 us; speedup vs baseline: 2.4911x; 1.2459x over previous
//
#include <hip/hip_runtime.h>
#include <math.h>

#define Bdim 4
#define Tdim 1024
#define Ddim 1024
#define Hdim 16
#define DHdim 64
#define FFNdim 4096
#define KSEL 256
#define EPSf 1e-6f

typedef __attribute__((ext_vector_type(8))) short bf16x8;   // 8 bf16 = 4 VGPR
typedef __attribute__((ext_vector_type(4))) float f32x4;
typedef __attribute__((ext_vector_type(4))) unsigned int u32x4;
typedef unsigned short ushort_t;

#define MFMA_BF16(a,b,c) __builtin_amdgcn_mfma_f32_16x16x32_bf16(a,b,c,0,0,0)

__device__ __forceinline__ int clamp_row(int r){ return r < 0 ? 0 : (r > Tdim-1 ? Tdim-1 : r); }

// split 8 fp32 into bf16 hi (truncate) + bf16 lo (exact remainder, truncated).
__device__ __forceinline__ void split8(const float* xs, u32x4* hi, u32x4* lo){
  unsigned int hm[8], lm[8];
  #pragma unroll
  for (int i=0;i<8;i++){
    unsigned int b = __float_as_uint(xs[i]);
    hm[i] = b & 0xFFFF0000u;
    lm[i] = __float_as_uint(xs[i] - __uint_as_float(hm[i]));
  }
  u32x4 h, l;
  #pragma unroll
  for (int i=0;i<4;i++){
    h[i] = (hm[2*i] >> 16) | hm[2*i+1];
    l[i] = (lm[2*i] >> 16) | (lm[2*i+1] & 0xFFFF0000u);
  }
  *hi = h; *lo = l;
}

__device__ __forceinline__ void split1(float x, unsigned int* h16, unsigned int* l16){
  unsigned int b = __float_as_uint(x);
  unsigned int hm = b & 0xFFFF0000u;
  *h16 = hm >> 16;
  *l16 = __float_as_uint(x - __uint_as_float(hm)) >> 16;
}

// ---------------- fallback (diagnostic): out = hidden ----------------
__global__ void k_fallback(const float* __restrict__ in, float* __restrict__ out, int n){
  int i = blockIdx.x*blockDim.x + threadIdx.x;
  if (i < n) out[i] = in[i];
}

__global__ void k_init_sel(int* __restrict__ selidx, float* __restrict__ selsc, int n){
  int i = blockIdx.x*blockDim.x + threadIdx.x;
  if (i < n){ selidx[i] = i & (KSEL-1); selsc[i] = 0.f; }
}

// ---------------- rmsnorm (fp32 out, old path) ----------------
__global__ __launch_bounds__(256) void k_rmsnorm(const float* __restrict__ x, const float* __restrict__ w,
                          float* __restrict__ y){
  int tok = blockIdx.x;
  const float* xp = x + (size_t)tok*Ddim;
  float* yp = y + (size_t)tok*Ddim;
  int tid = threadIdx.x;
  float s = 0.f;
  float xv[4];
  #pragma unroll
  for (int u = 0; u < 4; u++){ xv[u] = xp[tid + 256*u]; s += xv[u]*xv[u]; }
  __shared__ float red[256];
  red[tid]=s; __syncthreads();
  for (int st=128; st>0; st>>=1){ if (tid<st) red[tid]+=red[tid+st]; __syncthreads(); }
  float r = 1.0f/sqrtf(red[0]/(float)Ddim + EPSf);
  #pragma unroll
  for (int u = 0; u < 4; u++) yp[tid + 256*u] = xv[u]*r*w[tid + 256*u];
}

// rmsnorm emitting bf16 hi/lo planes
__global__ __launch_bounds__(256) void k_rmsnorm_sp(const float* __restrict__ x, const float* __restrict__ w,
                          ushort_t* __restrict__ yh, ushort_t* __restrict__ yl){
  int tok = blockIdx.x;
  const float* xp = x + (size_t)tok*Ddim;
  size_t ybase = (size_t)tok*Ddim;
  int tid = threadIdx.x;
  float s = 0.f;
  float xv[4];
  #pragma unroll
  for (int u = 0; u < 4; u++){ xv[u] = xp[tid + 256*u]; s += xv[u]*xv[u]; }
  __shared__ float red[256];
  red[tid]=s; __syncthreads();
  for (int st=128; st>0; st>>=1){ if (tid<st) red[tid]+=red[tid+st]; __syncthreads(); }
  float r = 1.0f/sqrtf(red[0]/(float)Ddim + EPSf);
  #pragma unroll
  for (int u = 0; u < 4; u++){
    float yv = xv[u]*r*w[tid + 256*u];
    unsigned int h16,l16; split1(yv,&h16,&l16);
    yh[ybase + tid + 256*u] = (ushort_t)h16;
    yl[ybase + tid + 256*u] = (ushort_t)l16;
  }
}

// rope in-place fp32 (old path)
__global__ void k_rope(float* __restrict__ x, const int* __restrict__ posidx, int S, int n){
  int e = blockIdx.x*blockDim.x + threadIdx.x;
  if (e >= n) return;
  int j = e & 31;
  int q = e >> 9;
  int t = q % S;
  float pos = posidx ? (float)clamp_row(posidx[q]) : (float)t;
  float inv = exp2f(-0.4152410118609203f * (float)j);
  float ang = pos * inv;
  float c = cosf(ang), s = sinf(ang);
  size_t base = ((size_t)(e >> 5)) * 64;
  float x1 = x[base + j], x2 = x[base + 32 + j];
  x[base + j]      = x1*c - x2*s;
  x[base + 32 + j] = x2*c + x1*s;
}

// rope reading fp32, writing bf16 hi/lo planes
__global__ void k_rope_sp(const float* __restrict__ x, const int* __restrict__ posidx, int S, int n,
                          ushort_t* __restrict__ Xh, ushort_t* __restrict__ Xl){
  int e = blockIdx.x*blockDim.x + threadIdx.x;
  if (e >= n) return;
  int j = e & 31;
  int q = e >> 9;
  int t = q % S;
  float pos = posidx ? (float)clamp_row(posidx[q]) : (float)t;
  float inv = exp2f(-0.4152410118609203f * (float)j);
  float ang = pos * inv;
  float c = cosf(ang), s = sinf(ang);
  size_t base = ((size_t)(e >> 5)) * 64;
  float x1 = x[base + j], x2 = x[base + 32 + j];
  float y1 = x1*c - x2*s;
  float y2 = x2*c + x1*s;
  unsigned int h16,l16;
  split1(y1,&h16,&l16); Xh[base + j] = (ushort_t)h16; Xl[base + j] = (ushort_t)l16;
  split1(y2,&h16,&l16); Xh[base + 32 + j] = (ushort_t)h16; Xl[base + 32 + j] = (ushort_t)l16;
}

// weight pre-split: W[K][N] fp32 -> transposed planes Wh/Wl [N][K]
__global__ __launch_bounds__(256) void k_split_w(const float* __restrict__ W,
                          ushort_t* __restrict__ Wh, ushort_t* __restrict__ Wl, int K, int N){
  __shared__ float fs[64][65];
  int n0 = blockIdx.x*64, k0 = blockIdx.y*64;
  int tid = threadIdx.x;
  #pragma unroll
  for (int i=0;i<16;i++){
    int idx = tid + 256*i;
    int r = idx >> 6, c = idx & 63;
    fs[r][c] = W[(size_t)(k0 + r)*N + n0 + c];
  }
  __syncthreads();
  int n = tid >> 2, kq = tid & 3;
  unsigned int hw[8], lw[8];
  #pragma unroll
  for (int i=0;i<16;i+=2){
    float v0 = fs[kq*16+i][n], v1 = fs[kq*16+i+1][n];
    unsigned int h0,l0,h1,l1;
    split1(v0,&h0,&l0); split1(v1,&h1,&l1);
    hw[i>>1] = h0 | (h1<<16);
    lw[i>>1] = l0 | (l1<<16);
  }
  size_t base = (size_t)(n0+n)*K + k0 + kq*16;
  u32x4 a = {hw[0],hw[1],hw[2],hw[3]};
  u32x4 b = {hw[4],hw[5],hw[6],hw[7]};
  *(u32x4*)&Wh[base] = a;
  *(u32x4*)&Wh[base+8] = b;
  u32x4 c2 = {lw[0],lw[1],lw[2],lw[3]};
  u32x4 d2 = {lw[4],lw[5],lw[6],lw[7]};
  *(u32x4*)&Wl[base] = c2;
  *(u32x4*)&Wl[base+8] = d2;
}

// ---------------- MFMA flash attention (old path: fp32 in, split on stage) ----------------
__global__ __launch_bounds__(256) void k_attn_mfma(const float* __restrict__ q, const float* __restrict__ k,
                       const float* __restrict__ v, float* __restrict__ o, int S){
  __shared__ ushort_t Kh[64*64], Kl[64*64];
  __shared__ ushort_t Vh[64*64], Vl[64*64];
  __shared__ float Pds[4*16*68];
  const int qt = blockIdx.x, h = blockIdx.y, b = blockIdx.z;
  const int q0 = qt*64;
  const int tid = threadIdx.x;
  const int lane = tid & 63;
  const int ln15 = lane & 15, lk = lane >> 4;
  const int wv = tid >> 6;
  const int qbase = wv*16;
  bf16x8 qa_h[2], qa_l[2];
  {
    const float* qp = q + (((size_t)b*S + q0 + qbase + ln15)*Hdim + h)*64 + lk*8;
    #pragma unroll
    for (int ks=0; ks<2; ks++){
      float xs[8];
      #pragma unroll
      for (int i=0;i<8;i++) xs[i] = qp[ks*32 + i];
      u32x4 hi, lo; split8(xs, &hi, &lo);
      qa_h[ks] = *(bf16x8*)&hi;
      qa_l[ks] = *(bf16x8*)&lo;
    }
  }
  float m_i[4], l_i[4];
  f32x4 oacc[4];
  #pragma unroll
  for (int r=0;r<4;r++){ m_i[r] = -3.4e38f; l_i[r] = 0.f; }
  #pragma unroll
  for (int fd=0;fd<4;fd++){ f32x4 z = {0.f,0.f,0.f,0.f}; oacc[fd] = z; }
  float* Pw = Pds + wv*(16*68);
  for (int j0 = 0; j0 <= q0; j0 += 64){
    __syncthreads();
    {
      int row = tid >> 2;
      int s0 = (tid & 3)*2;
      const float* kp = k + (((size_t)b*S + j0 + row)*Hdim + h)*64 + s0*8;
      #pragma unroll
      for (int g=0; g<2; g++){
        int slot = s0 + g;
        float xs[8];
        #pragma unroll
        for (int i=0;i<8;i++) xs[i] = kp[g*8 + i];
        u32x4 hi, lo; split8(xs, &hi, &lo);
        int base = row*64 + ((slot ^ (row&7))*8);
        *(u32x4*)&Kh[base] = hi;
        *(u32x4*)&Kl[base] = lo;
      }
    }
    {
      int j = tid & 31;
      int dbase = (tid >> 5)*8;
      const float* vp0 = v + (((size_t)b*S + j0 + 2*j)*Hdim + h)*64 + dbase;
      const float* vp1 = vp0 + (size_t)Hdim*64;
      float x0[8], x1[8];
      #pragma unroll
      for (int i=0;i<8;i++){ x0[i]=vp0[i]; x1[i]=vp1[i]; }
      unsigned int* VhW = (unsigned int*)Vh;
      unsigned int* VlW = (unsigned int*)Vl;
      #pragma unroll
      for (int i=0;i<8;i++){
        int d = dbase + i;
        unsigned int h0,l0,h1,l1;
        split1(x0[i], &h0, &l0); split1(x1[i], &h1, &l1);
        int off = d*32 + (((j>>2) ^ (d&7))*4) + (j&3);
        VhW[off] = h0 | (h1<<16);
        VlW[off] = l0 | (l1<<16);
      }
    }
    __syncthreads();
    f32x4 sacc[4];
    #pragma unroll
    for (int fj=0;fj<4;fj++){ f32x4 z = {0.f,0.f,0.f,0.f}; sacc[fj] = z; }
    #pragma unroll
    for (int ks=0; ks<2; ks++){
      #pragma unroll
      for (int fj=0;fj<4;fj++){
        int kr = fj*16 + ln15;
        int idx = kr*64 + (((ks*4+lk) ^ (kr&7))*8);
        bf16x8 kb_h = *(const bf16x8*)&Kh[idx];
        bf16x8 kb_l = *(const bf16x8*)&Kl[idx];
        sacc[fj] = MFMA_BF16(qa_h[ks], kb_h, sacc[fj]);
        sacc[fj] = MFMA_BF16(qa_h[ks], kb_l, sacc[fj]);
        sacc[fj] = MFMA_BF16(qa_l[ks], kb_h, sacc[fj]);
      }
    }
    #pragma unroll
    for (int fj=0;fj<4;fj++){
      int key = j0 + fj*16 + ln15;
      #pragma unroll
      for (int r=0;r<4;r++){
        float sv = sacc[fj][r]*0.125f;
        int qrow = q0 + qbase + lk*4 + r;
        sacc[fj][r] = (key > qrow) ? -3.4e38f : sv;
      }
    }
    float p[4][4];
    #pragma unroll
    for (int r=0;r<4;r++){
      float mt = fmaxf(fmaxf(sacc[0][r],sacc[1][r]), fmaxf(sacc[2][r],sacc[3][r]));
      #pragma unroll
      for (int off=1; off<16; off<<=1) mt = fmaxf(mt, __shfl_xor(mt, off));
      float m_new = fmaxf(m_i[r], mt);
      float alpha = expf(m_i[r] - m_new);
      float rs = 0.f;
      #pragma unroll
      for (int fj=0;fj<4;fj++){
        p[fj][r] = expf(sacc[fj][r] - m_new);
        rs += p[fj][r];
      }
      #pragma unroll
      for (int off=1; off<16; off<<=1) rs += __shfl_xor(rs, off);
      l_i[r] = l_i[r]*alpha + rs;
      m_i[r] = m_new;
      #pragma unroll
      for (int fd=0;fd<4;fd++) oacc[fd][r] *= alpha;
    }
    #pragma unroll
    for (int fj=0;fj<4;fj++)
      #pragma unroll
      for (int r=0;r<4;r++)
        Pw[(lk*4+r)*68 + fj*16 + ln15] = p[fj][r];
    #pragma unroll
    for (int ks=0; ks<2; ks++){
      f32x4 pf0 = *(const f32x4*)&Pw[ln15*68 + ks*32 + lk*8];
      f32x4 pf1 = *(const f32x4*)&Pw[ln15*68 + ks*32 + lk*8 + 4];
      float xs[8] = {pf0[0],pf0[1],pf0[2],pf0[3],pf1[0],pf1[1],pf1[2],pf1[3]};
      u32x4 hi, lo; split8(xs, &hi, &lo);
      bf16x8 pa_h = *(bf16x8*)&hi;
      bf16x8 pa_l = *(bf16x8*)&lo;
      #pragma unroll
      for (int fd=0;fd<4;fd++){
        int d = fd*16 + ln15;
        int idx = d*64 + (((ks*4+lk) ^ (d&7))*8);
        bf16x8 vb_h = *(const bf16x8*)&Vh[idx];
        bf16x8 vb_l = *(const bf16x8*)&Vl[idx];
        oacc[fd] = MFMA_BF16(pa_h, vb_h, oacc[fd]);
        oacc[fd] = MFMA_BF16(pa_h, vb_l, oacc[fd]);
        oacc[fd] = MFMA_BF16(pa_l, vb_h, oacc[fd]);
      }
    }
  }
  #pragma unroll
  for (int r=0;r<4;r++){
    float inv_l = 1.0f/l_i[r];
    #pragma unroll
    for (int fd=0;fd<4;fd++){
      o[(((size_t)b*S + q0 + qbase + lk*4 + r)*Hdim + h)*64 + fd*16 + ln15] = oacc[fd][r]*inv_l;
    }
  }
}

// ---------------- MFMA flash attention (new path: pre-split planes) ----------------
__global__ __launch_bounds__(256) void k_attn_ps(
    const ushort_t* __restrict__ Qph, const ushort_t* __restrict__ Qpl,
    const ushort_t* __restrict__ Kph, const ushort_t* __restrict__ Kpl,
    const ushort_t* __restrict__ Vph, const ushort_t* __restrict__ Vpl,
    ushort_t* __restrict__ Oh, ushort_t* __restrict__ Ol, int S){
  __shared__ ushort_t Kh[64*64], Kl[64*64];
  __shared__ ushort_t Vh[64*64], Vl[64*64];
  __shared__ float Pds[4*16*68];
  const int qt = blockIdx.x, h = blockIdx.y, b = blockIdx.z;
  const int q0 = qt*64;
  const int tid = threadIdx.x;
  const int lane = tid & 63;
  const int ln15 = lane & 15, lk = lane >> 4;
  const int wv = tid >> 6;
  const int qbase = wv*16;
  bf16x8 qa_h[2], qa_l[2];
  {
    size_t qoff = (((size_t)b*S + q0 + qbase + ln15)*Hdim + h)*64;
    #pragma unroll
    for (int ks=0; ks<2; ks++){
      qa_h[ks] = *(const bf16x8*)&Qph[qoff + ks*32 + lk*8];
      qa_l[ks] = *(const bf16x8*)&Qpl[qoff + ks*32 + lk*8];
    }
  }
  float m_i[4], l_i[4];
  f32x4 oacc[4];
  #pragma unroll
  for (int r=0;r<4;r++){ m_i[r] = -3.4e38f; l_i[r] = 0.f; }
  #pragma unroll
  for (int fd=0;fd<4;fd++){ f32x4 z = {0.f,0.f,0.f,0.f}; oacc[fd] = z; }
  float* Pw = Pds + wv*(16*68);
  for (int j0 = 0; j0 <= q0; j0 += 64){
    __syncthreads();
    #pragma unroll
    for (int g=0; g<2; g++){
      int row = g*32 + (tid >> 3);
      int ks = tid & 7;
      size_t ga = (((size_t)b*S + j0 + row)*Hdim + h)*64 + ks*8;
      u32x4 hi = *(const u32x4*)&Kph[ga];
      u32x4 lo = *(const u32x4*)&Kpl[ga];
      int base = row*64 + ((ks ^ (row&7))*8);
      *(u32x4*)&Kh[base] = hi;
      *(u32x4*)&Kl[base] = lo;
    }
    {
      int j = tid & 31;
      int dbase = (tid >> 5)*8;
      size_t g0 = (((size_t)b*S + j0 + 2*j)*Hdim + h)*64 + dbase;
      size_t g1 = g0 + (size_t)Hdim*64;
      u32x4 ah = *(const u32x4*)&Vph[g0];
      u32x4 bh = *(const u32x4*)&Vph[g1];
      u32x4 al = *(const u32x4*)&Vpl[g0];
      u32x4 bl = *(const u32x4*)&Vpl[g1];
      unsigned int* VhW = (unsigned int*)Vh;
      unsigned int* VlW = (unsigned int*)Vl;
      #pragma unroll
      for (int i=0;i<4;i++){
        int d0 = dbase + 2*i, d1 = d0 + 1;
        int off0 = d0*32 + (((j>>2) ^ (d0&7))*4) + (j&3);
        int off1 = d1*32 + (((j>>2) ^ (d1&7))*4) + (j&3);
        VhW[off0] = (ah[i] & 0xFFFFu) | (bh[i] << 16);
        VhW[off1] = (ah[i] >> 16)     | (bh[i] & 0xFFFF0000u);
        VlW[off0] = (al[i] & 0xFFFFu) | (bl[i] << 16);
        VlW[off1] = (al[i] >> 16)     | (bl[i] & 0xFFFF0000u);
      }
    }
    __syncthreads();
    f32x4 sacc[4];
    #pragma unroll
    for (int fj=0;fj<4;fj++){ f32x4 z = {0.f,0.f,0.f,0.f}; sacc[fj] = z; }
    #pragma unroll
    for (int ks=0; ks<2; ks++){
      #pragma unroll
      for (int fj=0;fj<4;fj++){
        int kr = fj*16 + ln15;
        int idx = kr*64 + (((ks*4+lk) ^ (kr&7))*8);
        bf16x8 kb_h = *(const bf16x8*)&Kh[idx];
        bf16x8 kb_l = *(const bf16x8*)&Kl[idx];
        sacc[fj] = MFMA_BF16(qa_h[ks], kb_h, sacc[fj]);
        sacc[fj] = MFMA_BF16(qa_h[ks], kb_l, sacc[fj]);
        sacc[fj] = MFMA_BF16(qa_l[ks], kb_h, sacc[fj]);
      }
    }
    #pragma unroll
    for (int fj=0;fj<4;fj++){
      int key = j0 + fj*16 + ln15;
      #pragma unroll
      for (int r=0;r<4;r++){
        float sv = sacc[fj][r]*0.125f;
        int qrow = q0 + qbase + lk*4 + r;
        sacc[fj][r] = (key > qrow) ? -3.4e38f : sv;
      }
    }
    float p[4][4];
    #pragma unroll
    for (int r=0;r<4;r++){
      float mt = fmaxf(fmaxf(sacc[0][r],sacc[1][r]), fmaxf(sacc[2][r],sacc[3][r]));
      #pragma unroll
      for (int off=1; off<16; off<<=1) mt = fmaxf(mt, __shfl_xor(mt, off));
      float m_new = fmaxf(m_i[r], mt);
      float alpha = expf(m_i[r] - m_new);
      float rs = 0.f;
      #pragma unroll
      for (int fj=0;fj<4;fj++){
        p[fj][r] = expf(sacc[fj][r] - m_new);
        rs += p[fj][r];
      }
      #pragma unroll
      for (int off=1; off<16; off<<=1) rs += __shfl_xor(rs, off);
      l_i[r] = l_i[r]*alpha + rs;
      m_i[r] = m_new;
      #pragma unroll
      for (int fd=0;fd<4;fd++) oacc[fd][r] *= alpha;
    }
    #pragma unroll
    for (int fj=0;fj<4;fj++)
      #pragma unroll
      for (int r=0;r<4;r++)
        Pw[(lk*4+r)*68 + fj*16 + ln15] = p[fj][r];
    #pragma unroll
    for (int ks=0; ks<2; ks++){
      f32x4 pf0 = *(const f32x4*)&Pw[ln15*68 + ks*32 + lk*8];
      f32x4 pf1 = *(const f32x4*)&Pw[ln15*68 + ks*32 + lk*8 + 4];
      float xs[8] = {pf0[0],pf0[1],pf0[2],pf0[3],pf1[0],pf1[1],pf1[2],pf1[3]};
      u32x4 hi, lo; split8(xs, &hi, &lo);
      bf16x8 pa_h = *(bf16x8*)&hi;
      bf16x8 pa_l = *(bf16x8*)&lo;
      #pragma unroll
      for (int fd=0;fd<4;fd++){
        int d = fd*16 + ln15;
        int idx = d*64 + (((ks*4+lk) ^ (d&7))*8);
        bf16x8 vb_h = *(const bf16x8*)&Vh[idx];
        bf16x8 vb_l = *(const bf16x8*)&Vl[idx];
        oacc[fd] = MFMA_BF16(pa_h, vb_h, oacc[fd]);
        oacc[fd] = MFMA_BF16(pa_h, vb_l, oacc[fd]);
        oacc[fd] = MFMA_BF16(pa_l, vb_h, oacc[fd]);
      }
    }
  }
  #pragma unroll
  for (int r=0;r<4;r++){
    float inv_l = 1.0f/l_i[r];
    #pragma unroll
    for (int fd=0;fd<4;fd++){
      float val = oacc[fd][r]*inv_l;
      unsigned int h16,l16; split1(val,&h16,&l16);
      size_t cix = (((size_t)b*S + q0 + qbase + lk*4 + r)*Hdim + h)*64 + fd*16 + ln15;
      Oh[cix] = (ushort_t)h16;
      Ol[cix] = (ushort_t)l16;
    }
  }
}

// ---- OLD MFMA GEMM (fp32 sources, 256 threads) ----
__global__ __launch_bounds__(256) void k_gemm_mfma(
    const float* __restrict__ A, const float* __restrict__ W,
    float* __restrict__ C, const float* __restrict__ addv,
    int K, int ldw, int ldc){
  __shared__ ushort_t Ah[128*32], Al[128*32], Bh[128*32], Bl[128*32];
  const int tid = threadIdx.x;
  const int row0 = blockIdx.y*128, col0 = blockIdx.x*128;
  const int lane = tid & 63;
  const int ln15 = lane & 15, lk = lane >> 4;
  const int wv = tid >> 6;
  const int wrow0 = (wv >> 1)*64, wcol0 = (wv & 1)*64;
  const int arow = tid >> 2;
  const int aks  = tid & 3;
  const int bcol = tid & 127;
  const int bks0 = tid >> 7;
  f32x4 acc[4][4];
  #pragma unroll
  for (int i=0;i<4;i++)
    #pragma unroll
    for (int j=0;j<4;j++){ f32x4 z = {0.f,0.f,0.f,0.f}; acc[i][j] = z; }
  for (int k0 = 0; k0 < K; k0 += 32){
    #pragma unroll
    for (int g=0; g<2; g++){
      int row = g*64 + arow;
      const float* ap = A + (size_t)(row0+row)*K + k0 + aks*8;
      float xs[8];
      #pragma unroll
      for (int i=0;i<8;i++) xs[i] = ap[i];
      u32x4 hi, lo; split8(xs, &hi, &lo);
      int base = row*32 + ((aks ^ ((row>>1)&3))*8);
      *(u32x4*)&Ah[base] = hi;
      *(u32x4*)&Al[base] = lo;
    }
    #pragma unroll
    for (int g=0; g<2; g++){
      int ks = bks0 + 2*g;
      const float* wp = W + (size_t)(k0 + ks*8)*ldw + col0 + bcol;
      float xs[8];
      #pragma unroll
      for (int i=0;i<8;i++) xs[i] = wp[(size_t)i*ldw];
      u32x4 hi, lo; split8(xs, &hi, &lo);
      int base = bcol*32 + ((ks ^ ((bcol>>1)&3))*8);
      *(u32x4*)&Bh[base] = hi;
      *(u32x4*)&Bl[base] = lo;
    }
    __syncthreads();
    bf16x8 ah[4], al[4];
    #pragma unroll
    for (int fi=0;fi<4;fi++){
      int r = wrow0 + fi*16 + ln15;
      int idx = r*32 + ((lk ^ ((r>>1)&3))*8);
      ah[fi] = *(const bf16x8*)&Ah[idx];
      al[fi] = *(const bf16x8*)&Al[idx];
    }
    #pragma unroll
    for (int fj=0;fj<4;fj++){
      int c = wcol0 + fj*16 + ln15;
      int idx = c*32 + ((lk ^ ((c>>1)&3))*8);
      bf16x8 bh = *(const bf16x8*)&Bh[idx];
      bf16x8 bl = *(const bf16x8*)&Bl[idx];
      #pragma unroll
      for (int fi=0;fi<4;fi++){
        acc[fi][fj] = MFMA_BF16(ah[fi], bh, acc[fi][fj]);
        acc[fi][fj] = MFMA_BF16(ah[fi], bl, acc[fi][fj]);
        acc[fi][fj] = MFMA_BF16(al[fi], bh, acc[fi][fj]);
      }
    }
    __syncthreads();
  }
  #pragma unroll
  for (int fi=0;fi<4;fi++){
    #pragma unroll
    for (int fj=0;fj<4;fj++){
      f32x4 v = acc[fi][fj];
      int cc = col0 + wcol0 + fj*16 + ln15;
      #pragma unroll
      for (int r=0;r<4;r++){
        size_t cix = (size_t)(row0 + wrow0 + fi*16 + lk*4 + r)*ldc + cc;
        float val = v[r];
        if (addv) val += addv[cix];
        C[cix] = val;
      }
    }
  }
}

// ---- NEW MFMA GEMM: planes in, 512 threads / 8 waves, register prefetch ----
__global__ __launch_bounds__(512) void k_gemm_ps(
    const ushort_t* __restrict__ Ahp, const ushort_t* __restrict__ Alp, int lda,
    const ushort_t* __restrict__ Bhp, const ushort_t* __restrict__ Blp, int ldb,
    float* __restrict__ C, ushort_t* __restrict__ Chp, ushort_t* __restrict__ Clp,
    const float* __restrict__ addv, int K, int ldc){
  __shared__ ushort_t Ah[128*32], Al[128*32], Bh[128*32], Bl[128*32];
  const int tid = threadIdx.x;
  const int row0 = blockIdx.y*128, col0 = blockIdx.x*128;
  const int lane = tid & 63;
  const int ln15 = lane & 15, lk = lane >> 4;
  const int wv = tid >> 6;                     // 0..7
  const int wrow0 = (wv >> 2)*64, wcol0 = (wv & 3)*32;
  const int t8 = tid >> 2, ks4 = tid & 3;      // 128 rows x 4 kslots
  const int sbase = t8*32 + ((ks4 ^ ((t8>>1)&3))*8);
  const size_t gaBase = (size_t)(row0 + t8)*lda + ks4*8;
  const size_t gbBase = (size_t)(col0 + t8)*ldb + ks4*8;

  f32x4 acc[4][2];
  #pragma unroll
  for (int i=0;i<4;i++)
    #pragma unroll
    for (int j=0;j<2;j++){ f32x4 z = {0.f,0.f,0.f,0.f}; acc[i][j] = z; }

  // prologue prefetch (k0 = 0)
  u32x4 rAh = *(const u32x4*)&Ahp[gaBase];
  u32x4 rAl = *(const u32x4*)&Alp[gaBase];
  u32x4 rBh = *(const u32x4*)&Bhp[gbBase];
  u32x4 rBl = *(const u32x4*)&Blp[gbBase];

  for (int k0 = 0; k0 < K; k0 += 32){
    __syncthreads();                 // previous iteration's LDS readers done
    *(u32x4*)&Ah[sbase] = rAh;
    *(u32x4*)&Al[sbase] = rAl;
    *(u32x4*)&Bh[sbase] = rBh;
    *(u32x4*)&Bl[sbase] = rBl;
    __syncthreads();
    if (k0 + 32 < K){                // issue next-tile loads; hide under MFMA
      rAh = *(const u32x4*)&Ahp[gaBase + k0 + 32];
      rAl = *(const u32x4*)&Alp[gaBase + k0 + 32];
      rBh = *(const u32x4*)&Bhp[gbBase + k0 + 32];
      rBl = *(const u32x4*)&Blp[gbBase + k0 + 32];
    }
    bf16x8 ah[4], al[4];
    #pragma unroll
    for (int fi=0;fi<4;fi++){
      int r = wrow0 + fi*16 + ln15;
      int idx = r*32 + ((lk ^ ((r>>1)&3))*8);
      ah[fi] = *(const bf16x8*)&Ah[idx];
      al[fi] = *(const bf16x8*)&Al[idx];
    }
    #pragma unroll
    for (int fj=0;fj<2;fj++){
      int c = wcol0 + fj*16 + ln15;
      int idx = c*32 + ((lk ^ ((c>>1)&3))*8);
      bf16x8 bh = *(const bf16x8*)&Bh[idx];
      bf16x8 bl = *(const bf16x8*)&Bl[idx];
      #pragma unroll
      for (int fi=0;fi<4;fi++){
        acc[fi][fj] = MFMA_BF16(ah[fi], bh, acc[fi][fj]);
        acc[fi][fj] = MFMA_BF16(ah[fi], bl, acc[fi][fj]);
        acc[fi][fj] = MFMA_BF16(al[fi], bh, acc[fi][fj]);
      }
    }
  }
  if (Chp){
    #pragma unroll
    for (int fi=0;fi<4;fi++){
      #pragma unroll
      for (int fj=0;fj<2;fj++){
        f32x4 v = acc[fi][fj];
        int cc = col0 + wcol0 + fj*16 + ln15;
        #pragma unroll
        for (int r=0;r<4;r++){
          size_t cix = (size_t)(row0 + wrow0 + fi*16 + lk*4 + r)*ldc + cc;
          unsigned int h16,l16; split1(v[r],&h16,&l16);
          Chp[cix] = (ushort_t)h16;
          Clp[cix] = (ushort_t)l16;
        }
      }
    }
  } else {
    #pragma unroll
    for (int fi=0;fi<4;fi++){
      #pragma unroll
      for (int fj=0;fj<2;fj++){
        f32x4 v = acc[fi][fj];
        int cc = col0 + wcol0 + fj*16 + ln15;
        #pragma unroll
        for (int r=0;r<4;r++){
          size_t cix = (size_t)(row0 + wrow0 + fi*16 + lk*4 + r)*ldc + cc;
          float val = v[r];
          if (addv) val += addv[cix];
          C[cix] = val;
        }
      }
    }
  }
}

// ---- OLD fused SwiGLU MFMA (fp32 sources, 256 threads) ----
__global__ __launch_bounds__(256) void k_gemm_dual_mfma(
    const float* __restrict__ A, const float* __restrict__ Wg,
    const float* __restrict__ Wu, float* __restrict__ C,
    int K, int ldw, int ldc){
  __shared__ ushort_t Ah[128*32], Al[128*32];
  __shared__ ushort_t Gh[64*32], Gl[64*32], Uh[64*32], Ul[64*32];
  const int tid = threadIdx.x;
  const int row0 = blockIdx.y*128, col0 = blockIdx.x*64;
  const int lane = tid & 63;
  const int ln15 = lane & 15, lk = lane >> 4;
  const int wv = tid >> 6;
  const int wrow0 = (wv >> 1)*64, wcol0 = (wv & 1)*32;
  const int arow = tid >> 2;
  const int aks  = tid & 3;
  const int bcol = tid & 63;
  const int bks  = tid >> 6;
  f32x4 ag[4][2], au[4][2];
  #pragma unroll
  for (int i=0;i<4;i++)
    #pragma unroll
    for (int j=0;j<2;j++){ f32x4 z = {0.f,0.f,0.f,0.f}; ag[i][j] = z; au[i][j] = z; }
  for (int k0 = 0; k0 < K; k0 += 32){
    #pragma unroll
    for (int g=0; g<2; g++){
      int row = g*64 + arow;
      const float* ap = A + (size_t)(row0+row)*K + k0 + aks*8;
      float xs[8];
      #pragma unroll
      for (int i=0;i<8;i++) xs[i] = ap[i];
      u32x4 hi, lo; split8(xs, &hi, &lo);
      int base = row*32 + ((aks ^ ((row>>1)&3))*8);
      *(u32x4*)&Ah[base] = hi;
      *(u32x4*)&Al[base] = lo;
    }
    {
      int wbase = bcol*32 + ((bks ^ ((bcol>>1)&3))*8);
      const float* gp = Wg + (size_t)(k0 + bks*8)*ldw + col0 + bcol;
      float xs[8];
      #pragma unroll
      for (int i=0;i<8;i++) xs[i] = gp[(size_t)i*ldw];
      u32x4 hi, lo; split8(xs, &hi, &lo);
      *(u32x4*)&Gh[wbase] = hi;
      *(u32x4*)&Gl[wbase] = lo;
      const float* up = Wu + (size_t)(k0 + bks*8)*ldw + col0 + bcol;
      #pragma unroll
      for (int i=0;i<8;i++) xs[i] = up[(size_t)i*ldw];
      split8(xs, &hi, &lo);
      *(u32x4*)&Uh[wbase] = hi;
      *(u32x4*)&Ul[wbase] = lo;
    }
    __syncthreads();
    bf16x8 ah[4], al[4];
    #pragma unroll
    for (int fi=0;fi<4;fi++){
      int r = wrow0 + fi*16 + ln15;
      int idx = r*32 + ((lk ^ ((r>>1)&3))*8);
      ah[fi] = *(const bf16x8*)&Ah[idx];
      al[fi] = *(const bf16x8*)&Al[idx];
    }
    #pragma unroll
    for (int fj=0;fj<2;fj++){
      int c = wcol0 + fj*16 + ln15;
      int idx = c*32 + ((lk ^ ((c>>1)&3))*8);
      bf16x8 gh = *(const bf16x8*)&Gh[idx];
      bf16x8 gl = *(const bf16x8*)&Gl[idx];
      bf16x8 uh = *(const bf16x8*)&Uh[idx];
      bf16x8 ul = *(const bf16x8*)&Ul[idx];
      #pragma unroll
      for (int fi=0;fi<4;fi++){
        ag[fi][fj] = MFMA_BF16(ah[fi], gh, ag[fi][fj]);
        ag[fi][fj] = MFMA_BF16(ah[fi], gl, ag[fi][fj]);
        ag[fi][fj] = MFMA_BF16(al[fi], gh, ag[fi][fj]);
        au[fi][fj] = MFMA_BF16(ah[fi], uh, au[fi][fj]);
        au[fi][fj] = MFMA_BF16(ah[fi], ul, au[fi][fj]);
        au[fi][fj] = MFMA_BF16(al[fi], uh, au[fi][fj]);
      }
    }
    __syncthreads();
  }
  #pragma unroll
  for (int fi=0;fi<4;fi++){
    #pragma unroll
    for (int fj=0;fj<2;fj++){
      f32x4 vg = ag[fi][fj];
      f32x4 vu = au[fi][fj];
      int cc = col0 + wcol0 + fj*16 + ln15;
      #pragma unroll
      for (int r=0;r<4;r++){
        size_t cix = (size_t)(row0 + wrow0 + fi*16 + lk*4 + r)*ldc + cc;
        float gg = vg[r];
        C[cix] = (gg/(1.0f+expf(-gg))) * vu[r];
      }
    }
  }
}

// ---- NEW fused SwiGLU MFMA: planes in, 512 threads / 8 waves, register prefetch ----
__global__ __launch_bounds__(512) void k_gemm_dual_ps(
    const ushort_t* __restrict__ Ahp, const ushort_t* __restrict__ Alp, int lda,
    const ushort_t* __restrict__ Ghp, const ushort_t* __restrict__ Glp,
    const ushort_t* __restrict__ Uhp, const ushort_t* __restrict__ Ulp, int ldb,
    ushort_t* __restrict__ Chp, ushort_t* __restrict__ Clp, int K, int ldc){
  __shared__ ushort_t Ah[128*32], Al[128*32];
  __shared__ ushort_t Gh[64*32], Gl[64*32], Uh[64*32], Ul[64*32];
  const int tid = threadIdx.x;
  const int row0 = blockIdx.y*128, col0 = blockIdx.x*64;
  const int lane = tid & 63;
  const int ln15 = lane & 15, lk = lane >> 4;
  const int wv = tid >> 6;                       // 0..7
  const int wrow0 = (wv >> 1)*32, wcol0 = (wv & 1)*32;
  const int t8 = tid >> 2, ks4 = tid & 3;        // A: 128 rows x 4 kslots
  const int abase = t8*32 + ((ks4 ^ ((t8>>1)&3))*8);
  const size_t gaBase = (size_t)(row0 + t8)*lda + ks4*8;
  // G/U staging: first 4 waves -> G, last 4 waves -> U (wave-uniform)
  const int isU = (tid >= 256);
  const int t2 = tid & 255;
  const int wcolS = t2 >> 2, wksS = t2 & 3;
  const int wsbase = wcolS*32 + ((wksS ^ ((wcolS>>1)&3))*8);
  const ushort_t* Wph = isU ? Uhp : Ghp;
  const ushort_t* Wpl = isU ? Ulp : Glp;
  ushort_t* WsH = isU ? Uh : Gh;
  ushort_t* WsL = isU ? Ul : Gl;
  const size_t gwBase = (size_t)(col0 + wcolS)*ldb + wksS*8;

  f32x4 ag[2][2], au[2][2];
  #pragma unroll
  for (int i=0;i<2;i++)
    #pragma unroll
    for (int j=0;j<2;j++){ f32x4 z = {0.f,0.f,0.f,0.f}; ag[i][j] = z; au[i][j] = z; }

  u32x4 rAh = *(const u32x4*)&Ahp[gaBase];
  u32x4 rAl = *(const u32x4*)&Alp[gaBase];
  u32x4 rWh = *(const u32x4*)&Wph[gwBase];
  u32x4 rWl = *(const u32x4*)&Wpl[gwBase];

  for (int k0 = 0; k0 < K; k0 += 32){
    __syncthreads();
    *(u32x4*)&Ah[abase] = rAh;
    *(u32x4*)&Al[abase] = rAl;
    *(u32x4*)&WsH[wsbase] = rWh;
    *(u32x4*)&WsL[wsbase] = rWl;
    __syncthreads();
    if (k0 + 32 < K){
      rAh = *(const u32x4*)&Ahp[gaBase + k0 + 32];
      rAl = *(const u32x4*)&Alp[gaBase + k0 + 32];
      rWh = *(const u32x4*)&Wph[gwBase + k0 + 32];
      rWl = *(const u32x4*)&Wpl[gwBase + k0 + 32];
    }
    bf16x8 ah[2], al[2];
    #pragma unroll
    for (int fi=0;fi<2;fi++){
      int r = wrow0 + fi*16 + ln15;
      int idx = r*32 + ((lk ^ ((r>>1)&3))*8);
      ah[fi] = *(const bf16x8*)&Ah[idx];
      al[fi] = *(const bf16x8*)&Al[idx];
    }
    #pragma unroll
    for (int fj=0;fj<2;fj++){
      int c = wcol0 + fj*16 + ln15;
      int idx = c*32 + ((lk ^ ((c>>1)&3))*8);
      bf16x8 gh = *(const bf16x8*)&Gh[idx];
      bf16x8 gl = *(const bf16x8*)&Gl[idx];
      bf16x8 uh = *(const bf16x8*)&Uh[idx];
      bf16x8 ul = *(const bf16x8*)&Ul[idx];
      #pragma unroll
      for (int fi=0;fi<2;fi++){
        ag[fi][fj] = MFMA_BF16(ah[fi], gh, ag[fi][fj]);
        ag[fi][fj] = MFMA_BF16(ah[fi], gl, ag[fi][fj]);
        ag[fi][fj] = MFMA_BF16(al[fi], gh, ag[fi][fj]);
        au[fi][fj] = MFMA_BF16(ah[fi], uh, au[fi][fj]);
        au[fi][fj] = MFMA_BF16(ah[fi], ul, au[fi][fj]);
        au[fi][fj] = MFMA_BF16(al[fi], uh, au[fi][fj]);
      }
    }
  }
  #pragma unroll
  for (int fi=0;fi<2;fi++){
    #pragma unroll
    for (int fj=0;fj<2;fj++){
      f32x4 vg = ag[fi][fj];
      f32x4 vu = au[fi][fj];
      int cc = col0 + wcol0 + fj*16 + ln15;
      #pragma unroll
      for (int r=0;r<4;r++){
        size_t cix = (size_t)(row0 + wrow0 + fi*16 + lk*4 + r)*ldc + cc;
        float gg = vg[r];
        float val = (gg/(1.0f+expf(-gg))) * vu[r];
        unsigned int h16,l16; split1(val,&h16,&l16);
        Chp[cix] = (ushort_t)h16;
        Clp[cix] = (ushort_t)l16;
      }
    }
  }
}

// ---------------- prior / gating ----------------
__global__ __launch_bounds__(256) void k_dstch(const float* __restrict__ proc, const float* __restrict__ x0,
                        const float* __restrict__ ml, float* __restrict__ dst, float* __restrict__ dch){
  int tok = blockIdx.x, tid = threadIdx.x;
  const float* pp = proc + (size_t)tok*Ddim;
  const float* xp = x0 + (size_t)tok*Ddim;
  const float* mu = ml + (size_t)tok*2*Ddim;
  const float* lv = mu + Ddim;
  float s1=0.f, s2=0.f;
  for (int i=tid;i<Ddim;i+=256){
    float r = pp[i]-xp[i];
    s1 += r*r;
    float t = r - mu[i];
    float l = lv[i];
    s2 += 0.5f*(l + (1.0f + t*t)*expf(-l) - 1.0f);
  }
  __shared__ float red[256], red2[256];
  red[tid]=s1; red2[tid]=s2; __syncthreads();
  for (int st=128; st>0; st>>=1){ if (tid<st){red[tid]+=red[tid+st]; red2[tid]+=red2[tid+st];} __syncthreads(); }
  if (tid==0){ dst[tok]=red[0]/(float)Ddim; dch[tok]=red2[0]/(float)Ddim; }
}

__global__ __launch_bounds__(256) void k_dstch2(const float* __restrict__ proc, const float* __restrict__ x0,
                        const float* __restrict__ muB, const float* __restrict__ lvB,
                        float* __restrict__ dst, float* __restrict__ dch){
  int tok = blockIdx.x, tid = threadIdx.x;
  const float* pp = proc + (size_t)tok*Ddim;
  const float* xp = x0 + (size_t)tok*Ddim;
  const float* mu = muB + (size_t)tok*Ddim;
  const float* lv = lvB + (size_t)tok*Ddim;
  float s1=0.f, s2=0.f;
  for (int i=tid;i<Ddim;i+=256){
    float r = pp[i]-xp[i];
    s1 += r*r;
    float t = r - mu[i];
    float l = lv[i];
    s2 += 0.5f*(l + (1.0f + t*t)*expf(-l) - 1.0f);
  }
  __shared__ float red[256], red2[256];
  red[tid]=s1; red2[tid]=s2; __syncthreads();
  for (int st=128; st>0; st>>=1){ if (tid<st){red[tid]+=red[tid+st]; red2[tid]+=red2[tid+st];} __syncthreads(); }
  if (tid==0){ dst[tok]=red[0]/(float)Ddim; dch[tok]=red2[0]/(float)Ddim; }
}

__global__ __launch_bounds__(1024) void k_gate(const float* __restrict__ dst, const float* __restrict__ dch,
                        float* __restrict__ g){
  int tid = threadIdx.x;
  float s1=0.f, s2=0.f;
  for (int i=tid; i<Bdim*Tdim; i+=1024){ s1+=dst[i]; s2+=dch[i]; }
  __shared__ float r1[1024], r2[1024];
  r1[tid]=s1; r2[tid]=s2; __syncthreads();
  for (int st=512; st>0; st>>=1){ if(tid<st){r1[tid]+=r1[tid+st]; r2[tid]+=r2[tid+st];} __syncthreads(); }
  float m1 = r1[0]/(float)(Bdim*Tdim), m2 = r2[0]/(float)(Bdim*Tdim);
  for (int i=tid; i<Bdim*Tdim; i+=1024){
    float z = (dst[i]-m1) + (dch[i]-m2);
    g[i] = 1.0f/(1.0f+expf(-z));
  }
}

__global__ __launch_bounds__(1024) void k_select(const float* __restrict__ g, int* __restrict__ selidx,
                         float* __restrict__ selsc){
  int b = blockIdx.x, t = threadIdx.x;
  __shared__ float gs[1024];
  __shared__ int flag[1024];
  float gv = g[b*Tdim + t];
  if (!(gv == gv)) gv = -3.4e38f;
  gs[t] = gv; __syncthreads();
  float gi = gs[t];
  int rank = 0;
  for (int j=0;j<Tdim;j++){
    float gj = gs[j];
    rank += (gj > gi) || (gj == gi && j < t);
  }
  int sel = (rank < KSEL) ? 1 : 0;
  flag[t] = sel; __syncthreads();
  if (sel){
    int pos = 0;
    for (int j=0;j<t;j++) pos += flag[j];
    if (pos < KSEL){
      selidx[b*KSEL+pos] = t;
      selsc[b*KSEL+pos] = gi;
    }
  }
}

__global__ __launch_bounds__(256) void k_gather(const float* __restrict__ proc, const int* __restrict__ selidx,
                         float* __restrict__ sel){
  int j = blockIdx.x, b = blockIdx.y, tid = threadIdx.x;
  int row = clamp_row(selidx[b*KSEL+j]);
  const float* src = proc + ((size_t)b*Tdim + row)*Ddim;
  float* dst = sel + ((size_t)b*KSEL + j)*Ddim;
  for (int d=tid; d<Ddim; d+=256) dst[d]=src[d];
}

__global__ void k_out(const float* __restrict__ proc, float* __restrict__ out, int n){
  int i = blockIdx.x*blockDim.x + threadIdx.x;
  if (i<n) out[i] = proc[i];
}

__global__ __launch_bounds__(256) void k_scatter(const float* __restrict__ sel, const float* __restrict__ y,
                          const float* __restrict__ selsc, const int* __restrict__ selidx,
                          float* __restrict__ out){
  int j = blockIdx.x, b = blockIdx.y, tid = threadIdx.x;
  int row = clamp_row(selidx[b*KSEL+j]);
  float s = selsc[b*KSEL+j];
  const float* sp = sel + ((size_t)b*KSEL + j)*Ddim;
  const float* yp = y + ((size_t)b*KSEL + j)*Ddim;
  float* op = out + ((size_t)b*Tdim + row)*Ddim;
  for (int d=tid; d<Ddim; d+=256){
    op[d] = sp[d] + s*(yp[d]-sp[d]);
  }
}

// ---------------- driver ----------------
extern "C" void kernel_launch(void* const* d_in, const int* in_sizes, int n_in,
                              void* d_out, int out_size, void* d_ws, size_t ws_size,
                              hipStream_t stream){
  (void)in_sizes; (void)n_in; (void)out_size;
  const float* hidden = (const float*)d_in[0];
  const float* wq1 = (const float*)d_in[1];
  const float* wk1 = (const float*)d_in[2];
  const float* wv1 = (const float*)d_in[3];
  const float* wo1 = (const float*)d_in[4];
  const float* wq2 = (const float*)d_in[5];
  const float* wk2 = (const float*)d_in[6];
  const float* wv2 = (const float*)d_in[7];
  const float* wo2 = (const float*)d_in[8];
  const float* wg1 = (const float*)d_in[9];
  const float* wu1 = (const float*)d_in[10];
  const float* wd1 = (const float*)d_in[11];
  const float* wg2 = (const float*)d_in[12];
  const float* wu2 = (const float*)d_in[13];
  const float* wd2 = (const float*)d_in[14];
  const float* ln1_1 = (const float*)d_in[15];
  const float* ln2_1 = (const float*)d_in[16];
  const float* ln1_2 = (const float*)d_in[17];
  const float* ln2_2 = (const float*)d_in[18];
  const float* prior_norm = (const float*)d_in[19];
  const float* prior_w = (const float*)d_in[20];

  const size_t A = (size_t)Bdim*Tdim*Ddim;      // 4M floats
  const size_t Q = (size_t)Bdim*KSEL*Ddim;      // 1M floats
  const int n = (int)A;
  const int MT = Bdim*Tdim;    // 4096
  const int M2 = Bdim*KSEL;    // 1024

  const size_t WELEMS = 34u*1024*1024;          // 34M weight elems -> 68M ushorts
  size_t need_old = (4*A + 16384) * sizeof(float);
  size_t need_new = need_old + 2*WELEMS*sizeof(ushort_t);

  if (ws_size < need_old){
    k_fallback<<<(n+255)/256,256,0,stream>>>(hidden, (float*)d_out, n);
    return;
  }

  float* ws = (float*)d_ws;
  float* R0 = ws;
  float* R1 = ws + 1*A;
  float* R2 = ws + 2*A;
  float* R3 = ws + 3*A;
  float* dstb = ws + 4*A;
  float* dchb = dstb + 4096;
  float* gb   = dchb + 4096;
  float* selsc= gb + 4096;
  int*   selidx = (int*)(selsc + 1024);

  k_init_sel<<<4,256,0,stream>>>(selidx, selsc, Bdim*KSEL);

  if (ws_size >= need_new){
    // ================= NEW PATH: pre-split bf16 planes, 512-thread GEMMs =================
    ushort_t* wpb = (ushort_t*)(ws + 4*A + 16384);
    size_t cur = 0;
    const size_t M1x1 = (size_t)1024*1024;
    const size_t M1x4 = (size_t)1024*4096;
    #define ALLOCW(nm, KN) ushort_t* nm##_h = wpb + cur; ushort_t* nm##_l = wpb + cur + (KN); cur += 2*(size_t)(KN);
    ALLOCW(pwq1, M1x1) ALLOCW(pwk1, M1x1) ALLOCW(pwv1, M1x1) ALLOCW(pwo1, M1x1)
    ALLOCW(pwq2, M1x1) ALLOCW(pwk2, M1x1) ALLOCW(pwv2, M1x1) ALLOCW(pwo2, M1x1)
    ALLOCW(pwg1, M1x4) ALLOCW(pwu1, M1x4) ALLOCW(pwd1, M1x4)
    ALLOCW(pwg2, M1x4) ALLOCW(pwu2, M1x4) ALLOCW(pwd2, M1x4)
    ALLOCW(ppw, (size_t)2048*1024)
    #undef ALLOCW

    k_split_w<<<dim3(16,16),256,0,stream>>>(wq1, pwq1_h, pwq1_l, 1024, 1024);
    k_split_w<<<dim3(16,16),256,0,stream>>>(wk1, pwk1_h, pwk1_l, 1024, 1024);
    k_split_w<<<dim3(16,16),256,0,stream>>>(wv1, pwv1_h, pwv1_l, 1024, 1024);
    k_split_w<<<dim3(16,16),256,0,stream>>>(wo1, pwo1_h, pwo1_l, 1024, 1024);
    k_split_w<<<dim3(16,16),256,0,stream>>>(wq2, pwq2_h, pwq2_l, 1024, 1024);
    k_split_w<<<dim3(16,16),256,0,stream>>>(wk2, pwk2_h, pwk2_l, 1024, 1024);
    k_split_w<<<dim3(16,16),256,0,stream>>>(wv2, pwv2_h, pwv2_l, 1024, 1024);
    k_split_w<<<dim3(16,16),256,0,stream>>>(wo2, pwo2_h, pwo2_l, 1024, 1024);
    k_split_w<<<dim3(64,16),256,0,stream>>>(wg1, pwg1_h, pwg1_l, 1024, 4096);
    k_split_w<<<dim3(64,16),256,0,stream>>>(wu1, pwu1_h, pwu1_l, 1024, 4096);
    k_split_w<<<dim3(16,64),256,0,stream>>>(wd1, pwd1_h, pwd1_l, 4096, 1024);
    k_split_w<<<dim3(64,16),256,0,stream>>>(wg2, pwg2_h, pwg2_l, 1024, 4096);
    k_split_w<<<dim3(64,16),256,0,stream>>>(wu2, pwu2_h, pwu2_l, 1024, 4096);
    k_split_w<<<dim3(16,64),256,0,stream>>>(wd2, pwd2_h, pwd2_l, 4096, 1024);
    k_split_w<<<dim3(32,16),256,0,stream>>>(prior_w, ppw_h, ppw_l, 1024, 2048);

    // ---- layer 1 ----
    ushort_t* Hh = (ushort_t*)R0; ushort_t* Hl = Hh + A;
    k_rmsnorm_sp<<<MT,256,0,stream>>>(hidden, ln1_1, Hh, Hl);
    dim3 gD(Ddim/128, MT/128);
    k_gemm_ps<<<gD,512,0,stream>>>(Hh,Hl,1024, pwq1_h,pwq1_l,1024, R1, nullptr,nullptr, nullptr, 1024, 1024);
    k_gemm_ps<<<gD,512,0,stream>>>(Hh,Hl,1024, pwk1_h,pwk1_l,1024, R2, nullptr,nullptr, nullptr, 1024, 1024);
    ushort_t* Vp_h = (ushort_t*)R3; ushort_t* Vp_l = Vp_h + A;
    k_gemm_ps<<<gD,512,0,stream>>>(Hh,Hl,1024, pwv1_h,pwv1_l,1024, nullptr, Vp_h, Vp_l, nullptr, 1024, 1024);
    int nr = MT*Hdim*32;
    ushort_t* Qp_h = (ushort_t*)R0; ushort_t* Qp_l = Qp_h + A;
    k_rope_sp<<<(nr+255)/256,256,0,stream>>>(R1, nullptr, Tdim, nr, Qp_h, Qp_l);
    ushort_t* Kp_h = (ushort_t*)R1; ushort_t* Kp_l = Kp_h + A;
    k_rope_sp<<<(nr+255)/256,256,0,stream>>>(R2, nullptr, Tdim, nr, Kp_h, Kp_l);
    ushort_t* Op_h = (ushort_t*)R2; ushort_t* Op_l = Op_h + A;
    k_attn_ps<<<dim3(Tdim/64,Hdim,Bdim),256,0,stream>>>(Qp_h,Qp_l, Kp_h,Kp_l, Vp_h,Vp_l, Op_h,Op_l, Tdim);
    k_gemm_ps<<<gD,512,0,stream>>>(Op_h,Op_l,1024, pwo1_h,pwo1_l,1024, R1, nullptr,nullptr, hidden, 1024, 1024);
    ushort_t* H2h = (ushort_t*)R0; ushort_t* H2l = H2h + A;
    k_rmsnorm_sp<<<MT,256,0,stream>>>(R1, ln2_1, H2h, H2l);
    ushort_t* ACTh = (ushort_t*)R3; ushort_t* ACTl = ACTh + A;
    for (int c = 0; c < 4; c++){
      k_gemm_dual_ps<<<dim3(16, MT/128),512,0,stream>>>(H2h,H2l,1024,
          pwg1_h + (size_t)c*M1x1, pwg1_l + (size_t)c*M1x1,
          pwu1_h + (size_t)c*M1x1, pwu1_l + (size_t)c*M1x1, 1024,
          ACTh, ACTl, 1024, 1024);
      k_gemm_ps<<<dim3(8, MT/128),512,0,stream>>>(ACTh,ACTl,1024,
          pwd1_h + (size_t)c*1024, pwd1_l + (size_t)c*1024, 4096,
          R2, nullptr,nullptr, (c==0 ? R1 : R2), 1024, 1024);
    }
    // proc = R2

    // ---- prior / gate / select ----
    ushort_t* PHh = (ushort_t*)R0; ushort_t* PHl = PHh + A;
    k_rmsnorm_sp<<<MT,256,0,stream>>>(hidden, prior_norm, PHh, PHl);
    k_gemm_ps<<<gD,512,0,stream>>>(PHh,PHl,1024, ppw_h, ppw_l, 1024, R1, nullptr,nullptr, nullptr, 1024, 1024);
    k_gemm_ps<<<gD,512,0,stream>>>(PHh,PHl,1024, ppw_h + M1x1, ppw_l + M1x1, 1024, R3, nullptr,nullptr, nullptr, 1024, 1024);
    k_dstch2<<<MT,256,0,stream>>>(R2, hidden, R1, R3, dstb, dchb);
    k_gate<<<1,1024,0,stream>>>(dstb, dchb, gb);
    k_select<<<Bdim,1024,0,stream>>>(gb, selidx, selsc);
    float* SELX = R0;
    k_gather<<<dim3(KSEL,Bdim),256,0,stream>>>(R2, selidx, SELX);

    // ---- layer 2 ----
    ushort_t* h2h = (ushort_t*)R1;        ushort_t* h2l = h2h + Q;
    k_rmsnorm_sp<<<M2,256,0,stream>>>(SELX, ln1_2, h2h, h2l);
    float* q2f = R1 + Q;
    float* k2f = R1 + 2*Q;
    ushort_t* v2h = (ushort_t*)(R1 + 3*Q); ushort_t* v2l = v2h + Q;
    dim3 gD2(Ddim/128, M2/128);
    k_gemm_ps<<<gD2,512,0,stream>>>(h2h,h2l,1024, pwq2_h,pwq2_l,1024, q2f, nullptr,nullptr, nullptr, 1024, 1024);
    k_gemm_ps<<<gD2,512,0,stream>>>(h2h,h2l,1024, pwk2_h,pwk2_l,1024, k2f, nullptr,nullptr, nullptr, 1024, 1024);
    k_gemm_ps<<<gD2,512,0,stream>>>(h2h,h2l,1024, pwv2_h,pwv2_l,1024, nullptr, v2h, v2l, nullptr, 1024, 1024);
    int nr2 = M2*Hdim*32;
    ushort_t* q2ph = (ushort_t*)(R0 + Q);   ushort_t* q2pl = q2ph + Q;
    ushort_t* k2ph = (ushort_t*)(R0 + 2*Q); ushort_t* k2pl = k2ph + Q;
    k_rope_sp<<<(nr2+255)/256,256,0,stream>>>(q2f, selidx, KSEL, nr2, q2ph, q2pl);
    k_rope_sp<<<(nr2+255)/256,256,0,stream>>>(k2f, selidx, KSEL, nr2, k2ph, k2pl);
    ushort_t* o2h = (ushort_t*)(R0 + 3*Q);  ushort_t* o2l = o2h + Q;
    k_attn_ps<<<dim3(KSEL/64,Hdim,Bdim),256,0,stream>>>(q2ph,q2pl, k2ph,k2pl, v2h,v2l, o2h,o2l, KSEL);
    float* X12 = R1 + Q;
    k_gemm_ps<<<gD2,512,0,stream>>>(o2h,o2l,1024, pwo2_h,pwo2_l,1024, X12, nullptr,nullptr, SELX, 1024, 1024);
    ushort_t* h22h = (ushort_t*)(R1 + 2*Q); ushort_t* h22l = h22h + Q;
    k_rmsnorm_sp<<<M2,256,0,stream>>>(X12, ln2_2, h22h, h22l);
    ushort_t* act2h = (ushort_t*)(R1 + 3*Q); ushort_t* act2l = act2h + Q;
    float* Y = R3;
    for (int c = 0; c < 4; c++){
      k_gemm_dual_ps<<<dim3(16, M2/128),512,0,stream>>>(h22h,h22l,1024,
          pwg2_h + (size_t)c*M1x1, pwg2_l + (size_t)c*M1x1,
          pwu2_h + (size_t)c*M1x1, pwu2_l + (size_t)c*M1x1, 1024,
          act2h, act2l, 1024, 1024);
      k_gemm_ps<<<dim3(8, M2/128),512,0,stream>>>(act2h,act2l,1024,
          pwd2_h + (size_t)c*1024, pwd2_l + (size_t)c*1024, 4096,
          Y, nullptr,nullptr, (c==0 ? X12 : Y), 1024, 1024);
    }
    // ---- output ----
    k_out<<<(n+255)/256,256,0,stream>>>(R2, (float*)d_out, n);
    k_scatter<<<dim3(KSEL,Bdim),256,0,stream>>>(SELX, Y, selsc, selidx, (float*)d_out);
    return;
  }

  // ================= OLD PATH (round-3, verified) =================
  k_rmsnorm<<<MT,256,0,stream>>>(hidden, ln1_1, R0);
  dim3 gD(Ddim/128, MT/128);
  k_gemm_mfma<<<gD,256,0,stream>>>(R0, wq1, R1, nullptr, Ddim, Ddim, Ddim);
  k_gemm_mfma<<<gD,256,0,stream>>>(R0, wk1, R2, nullptr, Ddim, Ddim, Ddim);
  k_gemm_mfma<<<gD,256,0,stream>>>(R0, wv1, R3, nullptr, Ddim, Ddim, Ddim);
  int nr = MT*Hdim*32;
  k_rope<<<(nr+255)/256,256,0,stream>>>(R1, nullptr, Tdim, nr);
  k_rope<<<(nr+255)/256,256,0,stream>>>(R2, nullptr, Tdim, nr);
  k_attn_mfma<<<dim3(Tdim/64,Hdim,Bdim),256,0,stream>>>(R1, R2, R3, R0, Tdim);
  k_gemm_mfma<<<gD,256,0,stream>>>(R0, wo1, R1, hidden, Ddim, Ddim, Ddim);
  k_rmsnorm<<<MT,256,0,stream>>>(R1, ln2_1, R2);
  for (int c = 0; c < 4; c++){
    k_gemm_dual_mfma<<<dim3(1024/64, MT/128),256,0,stream>>>(R2, wg1 + (size_t)c*1024, wu1 + (size_t)c*1024,
                                                  R3, Ddim, FFNdim, 1024);
    k_gemm_mfma<<<dim3(Ddim/128, MT/128),256,0,stream>>>(R3, wd1 + (size_t)c*1024*Ddim, R0,
                                             (c==0 ? R1 : R0), 1024, Ddim, Ddim);
  }
  k_rmsnorm<<<MT,256,0,stream>>>(hidden, prior_norm, R1);
  k_gemm_mfma<<<dim3(2*Ddim/128, MT/128),256,0,stream>>>(R1, prior_w, R2, nullptr, Ddim, 2*Ddim, 2*Ddim);
  k_dstch<<<MT,256,0,stream>>>(R0, hidden, R2, dstb, dchb);
  k_gate<<<1,1024,0,stream>>>(dstb, dchb, gb);
  k_select<<<Bdim,1024,0,stream>>>(gb, selidx, selsc);
  k_gather<<<dim3(KSEL,Bdim),256,0,stream>>>(R0, selidx, R1);
  k_rmsnorm<<<M2,256,0,stream>>>(R1, ln1_2, R2);
  dim3 gD2(Ddim/128, M2/128);
  k_gemm_mfma<<<gD2,256,0,stream>>>(R2, wq2, R2+Q,   nullptr, Ddim, Ddim, Ddim);
  k_gemm_mfma<<<gD2,256,0,stream>>>(R2, wk2, R2+2*Q, nullptr, Ddim, Ddim, Ddim);
  k_gemm_mfma<<<gD2,256,0,stream>>>(R2, wv2, R2+3*Q, nullptr, Ddim, Ddim, Ddim);
  int nr2 = M2*Hdim*32;
  k_rope<<<(nr2+255)/256,256,0,stream>>>(R2+Q,   selidx, KSEL, nr2);
  k_rope<<<(nr2+255)/256,256,0,stream>>>(R2+2*Q, selidx, KSEL, nr2);
  k_attn_mfma<<<dim3(KSEL/64,Hdim,Bdim),256,0,stream>>>(R2+Q, R2+2*Q, R2+3*Q, R3, KSEL);
  k_gemm_mfma<<<gD2,256,0,stream>>>(R3, wo2, R3+Q, R1, Ddim, Ddim, Ddim);
  k_rmsnorm<<<M2,256,0,stream>>>(R3+Q, ln2_2, R3+2*Q);
  for (int c = 0; c < 4; c++){
    k_gemm_dual_mfma<<<dim3(1024/64, M2/128),256,0,stream>>>(R3+2*Q, wg2 + (size_t)c*1024, wu2 + (size_t)c*1024,
                                                  R3+3*Q, Ddim, FFNdim, 1024);
    k_gemm_mfma<<<dim3(Ddim/128, M2/128),256,0,stream>>>(R3+3*Q, wd2 + (size_t)c*1024*Ddim, R2,
                                             (c==0 ? R3+Q : R2), 1024, Ddim, Ddim);
  }
  k_out<<<(n+255)/256,256,0,stream>>>(R0, (float*)d_out, n);
  k_scatter<<<dim3(KSEL,Bdim),256,0,stream>>>(R1, R2, selsc, selidx, (float*)d_out);
}

// Round 6
// 1378.675 us; speedup vs baseline: 2.7587x; 1.1074x over previous
//
#include <hip/hip_runtime.h>
#include <math.h>

#define Bdim 4
#define Tdim 1024
#define Ddim 1024
#define Hdim 16
#define DHdim 64
#define FFNdim 4096
#define KSEL 256
#define EPSf 1e-6f

typedef __attribute__((ext_vector_type(8))) short bf16x8;   // 8 bf16 = 4 VGPR
typedef __attribute__((ext_vector_type(4))) float f32x4;
typedef __attribute__((ext_vector_type(4))) unsigned int u32x4;
typedef unsigned short ushort_t;

#define MFMA_BF16(a,b,c) __builtin_amdgcn_mfma_f32_16x16x32_bf16(a,b,c,0,0,0)

__device__ __forceinline__ int clamp_row(int r){ return r < 0 ? 0 : (r > Tdim-1 ? Tdim-1 : r); }

// split 8 fp32 into bf16 hi (truncate) + bf16 lo (exact remainder, truncated).
__device__ __forceinline__ void split8(const float* xs, u32x4* hi, u32x4* lo){
  unsigned int hm[8], lm[8];
  #pragma unroll
  for (int i=0;i<8;i++){
    unsigned int b = __float_as_uint(xs[i]);
    hm[i] = b & 0xFFFF0000u;
    lm[i] = __float_as_uint(xs[i] - __uint_as_float(hm[i]));
  }
  u32x4 h, l;
  #pragma unroll
  for (int i=0;i<4;i++){
    h[i] = (hm[2*i] >> 16) | hm[2*i+1];
    l[i] = (lm[2*i] >> 16) | (lm[2*i+1] & 0xFFFF0000u);
  }
  *hi = h; *lo = l;
}

__device__ __forceinline__ void split1(float x, unsigned int* h16, unsigned int* l16){
  unsigned int b = __float_as_uint(x);
  unsigned int hm = b & 0xFFFF0000u;
  *h16 = hm >> 16;
  *l16 = __float_as_uint(x - __uint_as_float(hm)) >> 16;
}

// ---------------- fallback (diagnostic): out = hidden ----------------
__global__ void k_fallback(const float* __restrict__ in, float* __restrict__ out, int n){
  int i = blockIdx.x*blockDim.x + threadIdx.x;
  if (i < n) out[i] = in[i];
}

__global__ void k_init_sel(int* __restrict__ selidx, float* __restrict__ selsc, int n){
  int i = blockIdx.x*blockDim.x + threadIdx.x;
  if (i < n){ selidx[i] = i & (KSEL-1); selsc[i] = 0.f; }
}

// ---------------- rmsnorm (fp32 out, old path) ----------------
__global__ __launch_bounds__(256) void k_rmsnorm(const float* __restrict__ x, const float* __restrict__ w,
                          float* __restrict__ y){
  int tok = blockIdx.x;
  const float* xp = x + (size_t)tok*Ddim;
  float* yp = y + (size_t)tok*Ddim;
  int tid = threadIdx.x;
  float s = 0.f;
  float xv[4];
  #pragma unroll
  for (int u = 0; u < 4; u++){ xv[u] = xp[tid + 256*u]; s += xv[u]*xv[u]; }
  __shared__ float red[256];
  red[tid]=s; __syncthreads();
  for (int st=128; st>0; st>>=1){ if (tid<st) red[tid]+=red[tid+st]; __syncthreads(); }
  float r = 1.0f/sqrtf(red[0]/(float)Ddim + EPSf);
  #pragma unroll
  for (int u = 0; u < 4; u++) yp[tid + 256*u] = xv[u]*r*w[tid + 256*u];
}

// rmsnorm emitting bf16 hi/lo planes
__global__ __launch_bounds__(256) void k_rmsnorm_sp(const float* __restrict__ x, const float* __restrict__ w,
                          ushort_t* __restrict__ yh, ushort_t* __restrict__ yl){
  int tok = blockIdx.x;
  const float* xp = x + (size_t)tok*Ddim;
  size_t ybase = (size_t)tok*Ddim;
  int tid = threadIdx.x;
  float s = 0.f;
  float xv[4];
  #pragma unroll
  for (int u = 0; u < 4; u++){ xv[u] = xp[tid + 256*u]; s += xv[u]*xv[u]; }
  __shared__ float red[256];
  red[tid]=s; __syncthreads();
  for (int st=128; st>0; st>>=1){ if (tid<st) red[tid]+=red[tid+st]; __syncthreads(); }
  float r = 1.0f/sqrtf(red[0]/(float)Ddim + EPSf);
  #pragma unroll
  for (int u = 0; u < 4; u++){
    float yv = xv[u]*r*w[tid + 256*u];
    unsigned int h16,l16; split1(yv,&h16,&l16);
    yh[ybase + tid + 256*u] = (ushort_t)h16;
    yl[ybase + tid + 256*u] = (ushort_t)l16;
  }
}

// rope in-place fp32 (old path)
__global__ void k_rope(float* __restrict__ x, const int* __restrict__ posidx, int S, int n){
  int e = blockIdx.x*blockDim.x + threadIdx.x;
  if (e >= n) return;
  int j = e & 31;
  int q = e >> 9;
  int t = q % S;
  float pos = posidx ? (float)clamp_row(posidx[q]) : (float)t;
  float inv = exp2f(-0.4152410118609203f * (float)j);
  float ang = pos * inv;
  float c = cosf(ang), s = sinf(ang);
  size_t base = ((size_t)(e >> 5)) * 64;
  float x1 = x[base + j], x2 = x[base + 32 + j];
  x[base + j]      = x1*c - x2*s;
  x[base + 32 + j] = x2*c + x1*s;
}

// rope reading fp32, writing bf16 hi/lo planes
__global__ void k_rope_sp(const float* __restrict__ x, const int* __restrict__ posidx, int S, int n,
                          ushort_t* __restrict__ Xh, ushort_t* __restrict__ Xl){
  int e = blockIdx.x*blockDim.x + threadIdx.x;
  if (e >= n) return;
  int j = e & 31;
  int q = e >> 9;
  int t = q % S;
  float pos = posidx ? (float)clamp_row(posidx[q]) : (float)t;
  float inv = exp2f(-0.4152410118609203f * (float)j);
  float ang = pos * inv;
  float c = cosf(ang), s = sinf(ang);
  size_t base = ((size_t)(e >> 5)) * 64;
  float x1 = x[base + j], x2 = x[base + 32 + j];
  float y1 = x1*c - x2*s;
  float y2 = x2*c + x1*s;
  unsigned int h16,l16;
  split1(y1,&h16,&l16); Xh[base + j] = (ushort_t)h16; Xl[base + j] = (ushort_t)l16;
  split1(y2,&h16,&l16); Xh[base + 32 + j] = (ushort_t)h16; Xl[base + 32 + j] = (ushort_t)l16;
}

// weight pre-split: W[K][N] fp32 -> transposed planes Wh/Wl [N][K]
__global__ __launch_bounds__(256) void k_split_w(const float* __restrict__ W,
                          ushort_t* __restrict__ Wh, ushort_t* __restrict__ Wl, int K, int N){
  __shared__ float fs[64][65];
  int n0 = blockIdx.x*64, k0 = blockIdx.y*64;
  int tid = threadIdx.x;
  #pragma unroll
  for (int i=0;i<16;i++){
    int idx = tid + 256*i;
    int r = idx >> 6, c = idx & 63;
    fs[r][c] = W[(size_t)(k0 + r)*N + n0 + c];
  }
  __syncthreads();
  int n = tid >> 2, kq = tid & 3;
  unsigned int hw[8], lw[8];
  #pragma unroll
  for (int i=0;i<16;i+=2){
    float v0 = fs[kq*16+i][n], v1 = fs[kq*16+i+1][n];
    unsigned int h0,l0,h1,l1;
    split1(v0,&h0,&l0); split1(v1,&h1,&l1);
    hw[i>>1] = h0 | (h1<<16);
    lw[i>>1] = l0 | (l1<<16);
  }
  size_t base = (size_t)(n0+n)*K + k0 + kq*16;
  u32x4 a = {hw[0],hw[1],hw[2],hw[3]};
  u32x4 b = {hw[4],hw[5],hw[6],hw[7]};
  *(u32x4*)&Wh[base] = a;
  *(u32x4*)&Wh[base+8] = b;
  u32x4 c2 = {lw[0],lw[1],lw[2],lw[3]};
  u32x4 d2 = {lw[4],lw[5],lw[6],lw[7]};
  *(u32x4*)&Wl[base] = c2;
  *(u32x4*)&Wl[base+8] = d2;
}

// ---------------- MFMA flash attention (old path: fp32 in, split on stage) ----------------
__global__ __launch_bounds__(256) void k_attn_mfma(const float* __restrict__ q, const float* __restrict__ k,
                       const float* __restrict__ v, float* __restrict__ o, int S){
  __shared__ ushort_t Kh[64*64], Kl[64*64];
  __shared__ ushort_t Vh[64*64], Vl[64*64];
  __shared__ float Pds[4*16*68];
  const int qt = blockIdx.x, h = blockIdx.y, b = blockIdx.z;
  const int q0 = qt*64;
  const int tid = threadIdx.x;
  const int lane = tid & 63;
  const int ln15 = lane & 15, lk = lane >> 4;
  const int wv = tid >> 6;
  const int qbase = wv*16;
  bf16x8 qa_h[2], qa_l[2];
  {
    const float* qp = q + (((size_t)b*S + q0 + qbase + ln15)*Hdim + h)*64 + lk*8;
    #pragma unroll
    for (int ks=0; ks<2; ks++){
      float xs[8];
      #pragma unroll
      for (int i=0;i<8;i++) xs[i] = qp[ks*32 + i];
      u32x4 hi, lo; split8(xs, &hi, &lo);
      qa_h[ks] = *(bf16x8*)&hi;
      qa_l[ks] = *(bf16x8*)&lo;
    }
  }
  float m_i[4], l_i[4];
  f32x4 oacc[4];
  #pragma unroll
  for (int r=0;r<4;r++){ m_i[r] = -3.4e38f; l_i[r] = 0.f; }
  #pragma unroll
  for (int fd=0;fd<4;fd++){ f32x4 z = {0.f,0.f,0.f,0.f}; oacc[fd] = z; }
  float* Pw = Pds + wv*(16*68);
  for (int j0 = 0; j0 <= q0; j0 += 64){
    __syncthreads();
    {
      int row = tid >> 2;
      int s0 = (tid & 3)*2;
      const float* kp = k + (((size_t)b*S + j0 + row)*Hdim + h)*64 + s0*8;
      #pragma unroll
      for (int g=0; g<2; g++){
        int slot = s0 + g;
        float xs[8];
        #pragma unroll
        for (int i=0;i<8;i++) xs[i] = kp[g*8 + i];
        u32x4 hi, lo; split8(xs, &hi, &lo);
        int base = row*64 + ((slot ^ (row&7))*8);
        *(u32x4*)&Kh[base] = hi;
        *(u32x4*)&Kl[base] = lo;
      }
    }
    {
      int j = tid & 31;
      int dbase = (tid >> 5)*8;
      const float* vp0 = v + (((size_t)b*S + j0 + 2*j)*Hdim + h)*64 + dbase;
      const float* vp1 = vp0 + (size_t)Hdim*64;
      float x0[8], x1[8];
      #pragma unroll
      for (int i=0;i<8;i++){ x0[i]=vp0[i]; x1[i]=vp1[i]; }
      unsigned int* VhW = (unsigned int*)Vh;
      unsigned int* VlW = (unsigned int*)Vl;
      #pragma unroll
      for (int i=0;i<8;i++){
        int d = dbase + i;
        unsigned int h0,l0,h1,l1;
        split1(x0[i], &h0, &l0); split1(x1[i], &h1, &l1);
        int off = d*32 + (((j>>2) ^ (d&7))*4) + (j&3);
        VhW[off] = h0 | (h1<<16);
        VlW[off] = l0 | (l1<<16);
      }
    }
    __syncthreads();
    f32x4 sacc[4];
    #pragma unroll
    for (int fj=0;fj<4;fj++){ f32x4 z = {0.f,0.f,0.f,0.f}; sacc[fj] = z; }
    #pragma unroll
    for (int ks=0; ks<2; ks++){
      #pragma unroll
      for (int fj=0;fj<4;fj++){
        int kr = fj*16 + ln15;
        int idx = kr*64 + (((ks*4+lk) ^ (kr&7))*8);
        bf16x8 kb_h = *(const bf16x8*)&Kh[idx];
        bf16x8 kb_l = *(const bf16x8*)&Kl[idx];
        sacc[fj] = MFMA_BF16(qa_h[ks], kb_h, sacc[fj]);
        sacc[fj] = MFMA_BF16(qa_h[ks], kb_l, sacc[fj]);
        sacc[fj] = MFMA_BF16(qa_l[ks], kb_h, sacc[fj]);
      }
    }
    #pragma unroll
    for (int fj=0;fj<4;fj++){
      int key = j0 + fj*16 + ln15;
      #pragma unroll
      for (int r=0;r<4;r++){
        float sv = sacc[fj][r]*0.125f;
        int qrow = q0 + qbase + lk*4 + r;
        sacc[fj][r] = (key > qrow) ? -3.4e38f : sv;
      }
    }
    float p[4][4];
    #pragma unroll
    for (int r=0;r<4;r++){
      float mt = fmaxf(fmaxf(sacc[0][r],sacc[1][r]), fmaxf(sacc[2][r],sacc[3][r]));
      #pragma unroll
      for (int off=1; off<16; off<<=1) mt = fmaxf(mt, __shfl_xor(mt, off));
      float m_new = fmaxf(m_i[r], mt);
      float alpha = expf(m_i[r] - m_new);
      float rs = 0.f;
      #pragma unroll
      for (int fj=0;fj<4;fj++){
        p[fj][r] = expf(sacc[fj][r] - m_new);
        rs += p[fj][r];
      }
      #pragma unroll
      for (int off=1; off<16; off<<=1) rs += __shfl_xor(rs, off);
      l_i[r] = l_i[r]*alpha + rs;
      m_i[r] = m_new;
      #pragma unroll
      for (int fd=0;fd<4;fd++) oacc[fd][r] *= alpha;
    }
    #pragma unroll
    for (int fj=0;fj<4;fj++)
      #pragma unroll
      for (int r=0;r<4;r++)
        Pw[(lk*4+r)*68 + fj*16 + ln15] = p[fj][r];
    #pragma unroll
    for (int ks=0; ks<2; ks++){
      f32x4 pf0 = *(const f32x4*)&Pw[ln15*68 + ks*32 + lk*8];
      f32x4 pf1 = *(const f32x4*)&Pw[ln15*68 + ks*32 + lk*8 + 4];
      float xs[8] = {pf0[0],pf0[1],pf0[2],pf0[3],pf1[0],pf1[1],pf1[2],pf1[3]};
      u32x4 hi, lo; split8(xs, &hi, &lo);
      bf16x8 pa_h = *(bf16x8*)&hi;
      bf16x8 pa_l = *(bf16x8*)&lo;
      #pragma unroll
      for (int fd=0;fd<4;fd++){
        int d = fd*16 + ln15;
        int idx = d*64 + (((ks*4+lk) ^ (d&7))*8);
        bf16x8 vb_h = *(const bf16x8*)&Vh[idx];
        bf16x8 vb_l = *(const bf16x8*)&Vl[idx];
        oacc[fd] = MFMA_BF16(pa_h, vb_h, oacc[fd]);
        oacc[fd] = MFMA_BF16(pa_h, vb_l, oacc[fd]);
        oacc[fd] = MFMA_BF16(pa_l, vb_h, oacc[fd]);
      }
    }
  }
  #pragma unroll
  for (int r=0;r<4;r++){
    float inv_l = 1.0f/l_i[r];
    #pragma unroll
    for (int fd=0;fd<4;fd++){
      o[(((size_t)b*S + q0 + qbase + lk*4 + r)*Hdim + h)*64 + fd*16 + ln15] = oacc[fd][r]*inv_l;
    }
  }
}

// ---------------- MFMA flash attention (new path: pre-split planes, defer-max softmax) ----------------
// T13: softmax is shift-invariant; keep stale row-max while tile max <= m+8 (P <= e^8, safe in f32/bf16).
// Denominator kept as PER-LANE partial (alpha rescale is lane-local); single 4-step reduce at the end.
__global__ __launch_bounds__(256) void k_attn_ps(
    const ushort_t* __restrict__ Qph, const ushort_t* __restrict__ Qpl,
    const ushort_t* __restrict__ Kph, const ushort_t* __restrict__ Kpl,
    const ushort_t* __restrict__ Vph, const ushort_t* __restrict__ Vpl,
    ushort_t* __restrict__ Oh, ushort_t* __restrict__ Ol, int S){
  __shared__ ushort_t Kh[64*64], Kl[64*64];
  __shared__ ushort_t Vh[64*64], Vl[64*64];
  __shared__ float Pds[4*16*68];
  const int qt = blockIdx.x, h = blockIdx.y, b = blockIdx.z;
  const int q0 = qt*64;
  const int tid = threadIdx.x;
  const int lane = tid & 63;
  const int ln15 = lane & 15, lk = lane >> 4;
  const int wv = tid >> 6;
  const int qbase = wv*16;
  bf16x8 qa_h[2], qa_l[2];
  {
    size_t qoff = (((size_t)b*S + q0 + qbase + ln15)*Hdim + h)*64;
    #pragma unroll
    for (int ks=0; ks<2; ks++){
      qa_h[ks] = *(const bf16x8*)&Qph[qoff + ks*32 + lk*8];
      qa_l[ks] = *(const bf16x8*)&Qpl[qoff + ks*32 + lk*8];
    }
  }
  float m_i[4], lp[4];
  f32x4 oacc[4];
  #pragma unroll
  for (int r=0;r<4;r++){ m_i[r] = -3.4e38f; lp[r] = 0.f; }
  #pragma unroll
  for (int fd=0;fd<4;fd++){ f32x4 z = {0.f,0.f,0.f,0.f}; oacc[fd] = z; }
  float* Pw = Pds + wv*(16*68);
  for (int j0 = 0; j0 <= q0; j0 += 64){
    __syncthreads();
    #pragma unroll
    for (int g=0; g<2; g++){
      int row = g*32 + (tid >> 3);
      int ks = tid & 7;
      size_t ga = (((size_t)b*S + j0 + row)*Hdim + h)*64 + ks*8;
      u32x4 hi = *(const u32x4*)&Kph[ga];
      u32x4 lo = *(const u32x4*)&Kpl[ga];
      int base = row*64 + ((ks ^ (row&7))*8);
      *(u32x4*)&Kh[base] = hi;
      *(u32x4*)&Kl[base] = lo;
    }
    {
      int j = tid & 31;
      int dbase = (tid >> 5)*8;
      size_t g0 = (((size_t)b*S + j0 + 2*j)*Hdim + h)*64 + dbase;
      size_t g1 = g0 + (size_t)Hdim*64;
      u32x4 ah = *(const u32x4*)&Vph[g0];
      u32x4 bh = *(const u32x4*)&Vph[g1];
      u32x4 al = *(const u32x4*)&Vpl[g0];
      u32x4 bl = *(const u32x4*)&Vpl[g1];
      unsigned int* VhW = (unsigned int*)Vh;
      unsigned int* VlW = (unsigned int*)Vl;
      #pragma unroll
      for (int i=0;i<4;i++){
        int d0 = dbase + 2*i, d1 = d0 + 1;
        int off0 = d0*32 + (((j>>2) ^ (d0&7))*4) + (j&3);
        int off1 = d1*32 + (((j>>2) ^ (d1&7))*4) + (j&3);
        VhW[off0] = (ah[i] & 0xFFFFu) | (bh[i] << 16);
        VhW[off1] = (ah[i] >> 16)     | (bh[i] & 0xFFFF0000u);
        VlW[off0] = (al[i] & 0xFFFFu) | (bl[i] << 16);
        VlW[off1] = (al[i] >> 16)     | (bl[i] & 0xFFFF0000u);
      }
    }
    __syncthreads();
    f32x4 sacc[4];
    #pragma unroll
    for (int fj=0;fj<4;fj++){ f32x4 z = {0.f,0.f,0.f,0.f}; sacc[fj] = z; }
    #pragma unroll
    for (int ks=0; ks<2; ks++){
      #pragma unroll
      for (int fj=0;fj<4;fj++){
        int kr = fj*16 + ln15;
        int idx = kr*64 + (((ks*4+lk) ^ (kr&7))*8);
        bf16x8 kb_h = *(const bf16x8*)&Kh[idx];
        bf16x8 kb_l = *(const bf16x8*)&Kl[idx];
        sacc[fj] = MFMA_BF16(qa_h[ks], kb_h, sacc[fj]);
        sacc[fj] = MFMA_BF16(qa_h[ks], kb_l, sacc[fj]);
        sacc[fj] = MFMA_BF16(qa_l[ks], kb_h, sacc[fj]);
      }
    }
    #pragma unroll
    for (int fj=0;fj<4;fj++){
      int key = j0 + fj*16 + ln15;
      #pragma unroll
      for (int r=0;r<4;r++){
        float sv = sacc[fj][r]*0.125f;
        int qrow = q0 + qbase + lk*4 + r;
        sacc[fj][r] = (key > qrow) ? -3.4e38f : sv;
      }
    }
    // ---- defer-max online softmax ----
    float tm[4];
    #pragma unroll
    for (int r=0;r<4;r++)
      tm[r] = fmaxf(fmaxf(sacc[0][r],sacc[1][r]), fmaxf(sacc[2][r],sacc[3][r]));
    bool okl = (tm[0] <= m_i[0]+8.f) & (tm[1] <= m_i[1]+8.f)
             & (tm[2] <= m_i[2]+8.f) & (tm[3] <= m_i[3]+8.f);
    float p[4][4];
    if (__all(okl)){
      // fast path: no cross-lane ops, no rescale
      #pragma unroll
      for (int r=0;r<4;r++){
        #pragma unroll
        for (int fj=0;fj<4;fj++){
          float pv = expf(sacc[fj][r] - m_i[r]);
          p[fj][r] = pv;
          lp[r] += pv;
        }
      }
    } else {
      #pragma unroll
      for (int r=0;r<4;r++){
        float mt = tm[r];
        #pragma unroll
        for (int off=1; off<16; off<<=1) mt = fmaxf(mt, __shfl_xor(mt, off));
        float m_new = fmaxf(m_i[r], mt);
        float alpha = expf(m_i[r] - m_new);
        lp[r] *= alpha;
        #pragma unroll
        for (int fd=0;fd<4;fd++) oacc[fd][r] *= alpha;
        m_i[r] = m_new;
        #pragma unroll
        for (int fj=0;fj<4;fj++){
          float pv = expf(sacc[fj][r] - m_new);
          p[fj][r] = pv;
          lp[r] += pv;
        }
      }
    }
    #pragma unroll
    for (int fj=0;fj<4;fj++)
      #pragma unroll
      for (int r=0;r<4;r++)
        Pw[(lk*4+r)*68 + fj*16 + ln15] = p[fj][r];
    #pragma unroll
    for (int ks=0; ks<2; ks++){
      f32x4 pf0 = *(const f32x4*)&Pw[ln15*68 + ks*32 + lk*8];
      f32x4 pf1 = *(const f32x4*)&Pw[ln15*68 + ks*32 + lk*8 + 4];
      float xs[8] = {pf0[0],pf0[1],pf0[2],pf0[3],pf1[0],pf1[1],pf1[2],pf1[3]};
      u32x4 hi, lo; split8(xs, &hi, &lo);
      bf16x8 pa_h = *(bf16x8*)&hi;
      bf16x8 pa_l = *(bf16x8*)&lo;
      #pragma unroll
      for (int fd=0;fd<4;fd++){
        int d = fd*16 + ln15;
        int idx = d*64 + (((ks*4+lk) ^ (d&7))*8);
        bf16x8 vb_h = *(const bf16x8*)&Vh[idx];
        bf16x8 vb_l = *(const bf16x8*)&Vl[idx];
        oacc[fd] = MFMA_BF16(pa_h, vb_h, oacc[fd]);
        oacc[fd] = MFMA_BF16(pa_h, vb_l, oacc[fd]);
        oacc[fd] = MFMA_BF16(pa_l, vb_h, oacc[fd]);
      }
    }
  }
  // final denominator: reduce per-lane partials across the 16-lane group (once)
  #pragma unroll
  for (int r=0;r<4;r++){
    float l = lp[r];
    #pragma unroll
    for (int off=1; off<16; off<<=1) l += __shfl_xor(l, off);
    float inv_l = 1.0f/l;
    #pragma unroll
    for (int fd=0;fd<4;fd++){
      float val = oacc[fd][r]*inv_l;
      unsigned int h16,l16; split1(val,&h16,&l16);
      size_t cix = (((size_t)b*S + q0 + qbase + lk*4 + r)*Hdim + h)*64 + fd*16 + ln15;
      Oh[cix] = (ushort_t)h16;
      Ol[cix] = (ushort_t)l16;
    }
  }
}

// ---- OLD MFMA GEMM (fp32 sources, 256 threads) ----
__global__ __launch_bounds__(256) void k_gemm_mfma(
    const float* __restrict__ A, const float* __restrict__ W,
    float* __restrict__ C, const float* __restrict__ addv,
    int K, int ldw, int ldc){
  __shared__ ushort_t Ah[128*32], Al[128*32], Bh[128*32], Bl[128*32];
  const int tid = threadIdx.x;
  const int row0 = blockIdx.y*128, col0 = blockIdx.x*128;
  const int lane = tid & 63;
  const int ln15 = lane & 15, lk = lane >> 4;
  const int wv = tid >> 6;
  const int wrow0 = (wv >> 1)*64, wcol0 = (wv & 1)*64;
  const int arow = tid >> 2;
  const int aks  = tid & 3;
  const int bcol = tid & 127;
  const int bks0 = tid >> 7;
  f32x4 acc[4][4];
  #pragma unroll
  for (int i=0;i<4;i++)
    #pragma unroll
    for (int j=0;j<4;j++){ f32x4 z = {0.f,0.f,0.f,0.f}; acc[i][j] = z; }
  for (int k0 = 0; k0 < K; k0 += 32){
    #pragma unroll
    for (int g=0; g<2; g++){
      int row = g*64 + arow;
      const float* ap = A + (size_t)(row0+row)*K + k0 + aks*8;
      float xs[8];
      #pragma unroll
      for (int i=0;i<8;i++) xs[i] = ap[i];
      u32x4 hi, lo; split8(xs, &hi, &lo);
      int base = row*32 + ((aks ^ ((row>>1)&3))*8);
      *(u32x4*)&Ah[base] = hi;
      *(u32x4*)&Al[base] = lo;
    }
    #pragma unroll
    for (int g=0; g<2; g++){
      int ks = bks0 + 2*g;
      const float* wp = W + (size_t)(k0 + ks*8)*ldw + col0 + bcol;
      float xs[8];
      #pragma unroll
      for (int i=0;i<8;i++) xs[i] = wp[(size_t)i*ldw];
      u32x4 hi, lo; split8(xs, &hi, &lo);
      int base = bcol*32 + ((ks ^ ((bcol>>1)&3))*8);
      *(u32x4*)&Bh[base] = hi;
      *(u32x4*)&Bl[base] = lo;
    }
    __syncthreads();
    bf16x8 ah[4], al[4];
    #pragma unroll
    for (int fi=0;fi<4;fi++){
      int r = wrow0 + fi*16 + ln15;
      int idx = r*32 + ((lk ^ ((r>>1)&3))*8);
      ah[fi] = *(const bf16x8*)&Ah[idx];
      al[fi] = *(const bf16x8*)&Al[idx];
    }
    #pragma unroll
    for (int fj=0;fj<4;fj++){
      int c = wcol0 + fj*16 + ln15;
      int idx = c*32 + ((lk ^ ((c>>1)&3))*8);
      bf16x8 bh = *(const bf16x8*)&Bh[idx];
      bf16x8 bl = *(const bf16x8*)&Bl[idx];
      #pragma unroll
      for (int fi=0;fi<4;fi++){
        acc[fi][fj] = MFMA_BF16(ah[fi], bh, acc[fi][fj]);
        acc[fi][fj] = MFMA_BF16(ah[fi], bl, acc[fi][fj]);
        acc[fi][fj] = MFMA_BF16(al[fi], bh, acc[fi][fj]);
      }
    }
    __syncthreads();
  }
  #pragma unroll
  for (int fi=0;fi<4;fi++){
    #pragma unroll
    for (int fj=0;fj<4;fj++){
      f32x4 v = acc[fi][fj];
      int cc = col0 + wcol0 + fj*16 + ln15;
      #pragma unroll
      for (int r=0;r<4;r++){
        size_t cix = (size_t)(row0 + wrow0 + fi*16 + lk*4 + r)*ldc + cc;
        float val = v[r];
        if (addv) val += addv[cix];
        C[cix] = val;
      }
    }
  }
}

// ---- NEW MFMA GEMM: planes in, 512 threads / 8 waves, register prefetch ----
__global__ __launch_bounds__(512) void k_gemm_ps(
    const ushort_t* __restrict__ Ahp, const ushort_t* __restrict__ Alp, int lda,
    const ushort_t* __restrict__ Bhp, const ushort_t* __restrict__ Blp, int ldb,
    float* __restrict__ C, ushort_t* __restrict__ Chp, ushort_t* __restrict__ Clp,
    const float* __restrict__ addv, int K, int ldc){
  __shared__ ushort_t Ah[128*32], Al[128*32], Bh[128*32], Bl[128*32];
  const int tid = threadIdx.x;
  const int row0 = blockIdx.y*128, col0 = blockIdx.x*128;
  const int lane = tid & 63;
  const int ln15 = lane & 15, lk = lane >> 4;
  const int wv = tid >> 6;                     // 0..7
  const int wrow0 = (wv >> 2)*64, wcol0 = (wv & 3)*32;
  const int t8 = tid >> 2, ks4 = tid & 3;      // 128 rows x 4 kslots
  const int sbase = t8*32 + ((ks4 ^ ((t8>>1)&3))*8);
  const size_t gaBase = (size_t)(row0 + t8)*lda + ks4*8;
  const size_t gbBase = (size_t)(col0 + t8)*ldb + ks4*8;

  f32x4 acc[4][2];
  #pragma unroll
  for (int i=0;i<4;i++)
    #pragma unroll
    for (int j=0;j<2;j++){ f32x4 z = {0.f,0.f,0.f,0.f}; acc[i][j] = z; }

  u32x4 rAh = *(const u32x4*)&Ahp[gaBase];
  u32x4 rAl = *(const u32x4*)&Alp[gaBase];
  u32x4 rBh = *(const u32x4*)&Bhp[gbBase];
  u32x4 rBl = *(const u32x4*)&Blp[gbBase];

  for (int k0 = 0; k0 < K; k0 += 32){
    __syncthreads();
    *(u32x4*)&Ah[sbase] = rAh;
    *(u32x4*)&Al[sbase] = rAl;
    *(u32x4*)&Bh[sbase] = rBh;
    *(u32x4*)&Bl[sbase] = rBl;
    __syncthreads();
    if (k0 + 32 < K){
      rAh = *(const u32x4*)&Ahp[gaBase + k0 + 32];
      rAl = *(const u32x4*)&Alp[gaBase + k0 + 32];
      rBh = *(const u32x4*)&Bhp[gbBase + k0 + 32];
      rBl = *(const u32x4*)&Blp[gbBase + k0 + 32];
    }
    bf16x8 ah[4], al[4];
    #pragma unroll
    for (int fi=0;fi<4;fi++){
      int r = wrow0 + fi*16 + ln15;
      int idx = r*32 + ((lk ^ ((r>>1)&3))*8);
      ah[fi] = *(const bf16x8*)&Ah[idx];
      al[fi] = *(const bf16x8*)&Al[idx];
    }
    #pragma unroll
    for (int fj=0;fj<2;fj++){
      int c = wcol0 + fj*16 + ln15;
      int idx = c*32 + ((lk ^ ((c>>1)&3))*8);
      bf16x8 bh = *(const bf16x8*)&Bh[idx];
      bf16x8 bl = *(const bf16x8*)&Bl[idx];
      #pragma unroll
      for (int fi=0;fi<4;fi++){
        acc[fi][fj] = MFMA_BF16(ah[fi], bh, acc[fi][fj]);
        acc[fi][fj] = MFMA_BF16(ah[fi], bl, acc[fi][fj]);
        acc[fi][fj] = MFMA_BF16(al[fi], bh, acc[fi][fj]);
      }
    }
  }
  if (Chp){
    #pragma unroll
    for (int fi=0;fi<4;fi++){
      #pragma unroll
      for (int fj=0;fj<2;fj++){
        f32x4 v = acc[fi][fj];
        int cc = col0 + wcol0 + fj*16 + ln15;
        #pragma unroll
        for (int r=0;r<4;r++){
          size_t cix = (size_t)(row0 + wrow0 + fi*16 + lk*4 + r)*ldc + cc;
          unsigned int h16,l16; split1(v[r],&h16,&l16);
          Chp[cix] = (ushort_t)h16;
          Clp[cix] = (ushort_t)l16;
        }
      }
    }
  } else {
    #pragma unroll
    for (int fi=0;fi<4;fi++){
      #pragma unroll
      for (int fj=0;fj<2;fj++){
        f32x4 v = acc[fi][fj];
        int cc = col0 + wcol0 + fj*16 + ln15;
        #pragma unroll
        for (int r=0;r<4;r++){
          size_t cix = (size_t)(row0 + wrow0 + fi*16 + lk*4 + r)*ldc + cc;
          float val = v[r];
          if (addv) val += addv[cix];
          C[cix] = val;
        }
      }
    }
  }
}

// ---- FUSED multi-weight GEMM: blockIdx.z selects weight/output (qkv: z=3, prior: z=2) ----
// z==2 writes planes (C2h/C2l); z<2 writes f32 (C0/C1). No addv.
__global__ __launch_bounds__(512) void k_gemm_qkv(
    const ushort_t* __restrict__ Ahp, const ushort_t* __restrict__ Alp, int lda,
    const ushort_t* __restrict__ B0h, const ushort_t* __restrict__ B0l,
    const ushort_t* __restrict__ B1h, const ushort_t* __restrict__ B1l,
    const ushort_t* __restrict__ B2h, const ushort_t* __restrict__ B2l, int ldb,
    float* __restrict__ C0, float* __restrict__ C1,
    ushort_t* __restrict__ C2h, ushort_t* __restrict__ C2l,
    int K, int ldc){
  __shared__ ushort_t Ah[128*32], Al[128*32], Bh[128*32], Bl[128*32];
  const int z = blockIdx.z;
  const ushort_t* Bhp = (z==0) ? B0h : (z==1) ? B1h : B2h;
  const ushort_t* Blp = (z==0) ? B0l : (z==1) ? B1l : B2l;
  const int tid = threadIdx.x;
  const int row0 = blockIdx.y*128, col0 = blockIdx.x*128;
  const int lane = tid & 63;
  const int ln15 = lane & 15, lk = lane >> 4;
  const int wv = tid >> 6;
  const int wrow0 = (wv >> 2)*64, wcol0 = (wv & 3)*32;
  const int t8 = tid >> 2, ks4 = tid & 3;
  const int sbase = t8*32 + ((ks4 ^ ((t8>>1)&3))*8);
  const size_t gaBase = (size_t)(row0 + t8)*lda + ks4*8;
  const size_t gbBase = (size_t)(col0 + t8)*ldb + ks4*8;

  f32x4 acc[4][2];
  #pragma unroll
  for (int i=0;i<4;i++)
    #pragma unroll
    for (int j=0;j<2;j++){ f32x4 zz = {0.f,0.f,0.f,0.f}; acc[i][j] = zz; }

  u32x4 rAh = *(const u32x4*)&Ahp[gaBase];
  u32x4 rAl = *(const u32x4*)&Alp[gaBase];
  u32x4 rBh = *(const u32x4*)&Bhp[gbBase];
  u32x4 rBl = *(const u32x4*)&Blp[gbBase];

  for (int k0 = 0; k0 < K; k0 += 32){
    __syncthreads();
    *(u32x4*)&Ah[sbase] = rAh;
    *(u32x4*)&Al[sbase] = rAl;
    *(u32x4*)&Bh[sbase] = rBh;
    *(u32x4*)&Bl[sbase] = rBl;
    __syncthreads();
    if (k0 + 32 < K){
      rAh = *(const u32x4*)&Ahp[gaBase + k0 + 32];
      rAl = *(const u32x4*)&Alp[gaBase + k0 + 32];
      rBh = *(const u32x4*)&Bhp[gbBase + k0 + 32];
      rBl = *(const u32x4*)&Blp[gbBase + k0 + 32];
    }
    bf16x8 ah[4], al[4];
    #pragma unroll
    for (int fi=0;fi<4;fi++){
      int r = wrow0 + fi*16 + ln15;
      int idx = r*32 + ((lk ^ ((r>>1)&3))*8);
      ah[fi] = *(const bf16x8*)&Ah[idx];
      al[fi] = *(const bf16x8*)&Al[idx];
    }
    #pragma unroll
    for (int fj=0;fj<2;fj++){
      int c = wcol0 + fj*16 + ln15;
      int idx = c*32 + ((lk ^ ((c>>1)&3))*8);
      bf16x8 bh = *(const bf16x8*)&Bh[idx];
      bf16x8 bl = *(const bf16x8*)&Bl[idx];
      #pragma unroll
      for (int fi=0;fi<4;fi++){
        acc[fi][fj] = MFMA_BF16(ah[fi], bh, acc[fi][fj]);
        acc[fi][fj] = MFMA_BF16(ah[fi], bl, acc[fi][fj]);
        acc[fi][fj] = MFMA_BF16(al[fi], bh, acc[fi][fj]);
      }
    }
  }
  if (z == 2){
    #pragma unroll
    for (int fi=0;fi<4;fi++){
      #pragma unroll
      for (int fj=0;fj<2;fj++){
        f32x4 v = acc[fi][fj];
        int cc = col0 + wcol0 + fj*16 + ln15;
        #pragma unroll
        for (int r=0;r<4;r++){
          size_t cix = (size_t)(row0 + wrow0 + fi*16 + lk*4 + r)*ldc + cc;
          unsigned int h16,l16; split1(v[r],&h16,&l16);
          C2h[cix] = (ushort_t)h16;
          C2l[cix] = (ushort_t)l16;
        }
      }
    }
  } else {
    float* C = (z == 0) ? C0 : C1;
    #pragma unroll
    for (int fi=0;fi<4;fi++){
      #pragma unroll
      for (int fj=0;fj<2;fj++){
        f32x4 v = acc[fi][fj];
        int cc = col0 + wcol0 + fj*16 + ln15;
        #pragma unroll
        for (int r=0;r<4;r++){
          size_t cix = (size_t)(row0 + wrow0 + fi*16 + lk*4 + r)*ldc + cc;
          C[cix] = v[r];
        }
      }
    }
  }
}

// ---- OLD fused SwiGLU MFMA (fp32 sources, 256 threads) ----
__global__ __launch_bounds__(256) void k_gemm_dual_mfma(
    const float* __restrict__ A, const float* __restrict__ Wg,
    const float* __restrict__ Wu, float* __restrict__ C,
    int K, int ldw, int ldc){
  __shared__ ushort_t Ah[128*32], Al[128*32];
  __shared__ ushort_t Gh[64*32], Gl[64*32], Uh[64*32], Ul[64*32];
  const int tid = threadIdx.x;
  const int row0 = blockIdx.y*128, col0 = blockIdx.x*64;
  const int lane = tid & 63;
  const int ln15 = lane & 15, lk = lane >> 4;
  const int wv = tid >> 6;
  const int wrow0 = (wv >> 1)*64, wcol0 = (wv & 1)*32;
  const int arow = tid >> 2;
  const int aks  = tid & 3;
  const int bcol = tid & 63;
  const int bks  = tid >> 6;
  f32x4 ag[4][2], au[4][2];
  #pragma unroll
  for (int i=0;i<4;i++)
    #pragma unroll
    for (int j=0;j<2;j++){ f32x4 z = {0.f,0.f,0.f,0.f}; ag[i][j] = z; au[i][j] = z; }
  for (int k0 = 0; k0 < K; k0 += 32){
    #pragma unroll
    for (int g=0; g<2; g++){
      int row = g*64 + arow;
      const float* ap = A + (size_t)(row0+row)*K + k0 + aks*8;
      float xs[8];
      #pragma unroll
      for (int i=0;i<8;i++) xs[i] = ap[i];
      u32x4 hi, lo; split8(xs, &hi, &lo);
      int base = row*32 + ((aks ^ ((row>>1)&3))*8);
      *(u32x4*)&Ah[base] = hi;
      *(u32x4*)&Al[base] = lo;
    }
    {
      int wbase = bcol*32 + ((bks ^ ((bcol>>1)&3))*8);
      const float* gp = Wg + (size_t)(k0 + bks*8)*ldw + col0 + bcol;
      float xs[8];
      #pragma unroll
      for (int i=0;i<8;i++) xs[i] = gp[(size_t)i*ldw];
      u32x4 hi, lo; split8(xs, &hi, &lo);
      *(u32x4*)&Gh[wbase] = hi;
      *(u32x4*)&Gl[wbase] = lo;
      const float* up = Wu + (size_t)(k0 + bks*8)*ldw + col0 + bcol;
      #pragma unroll
      for (int i=0;i<8;i++) xs[i] = up[(size_t)i*ldw];
      split8(xs, &hi, &lo);
      *(u32x4*)&Uh[wbase] = hi;
      *(u32x4*)&Ul[wbase] = lo;
    }
    __syncthreads();
    bf16x8 ah[4], al[4];
    #pragma unroll
    for (int fi=0;fi<4;fi++){
      int r = wrow0 + fi*16 + ln15;
      int idx = r*32 + ((lk ^ ((r>>1)&3))*8);
      ah[fi] = *(const bf16x8*)&Ah[idx];
      al[fi] = *(const bf16x8*)&Al[idx];
    }
    #pragma unroll
    for (int fj=0;fj<2;fj++){
      int c = wcol0 + fj*16 + ln15;
      int idx = c*32 + ((lk ^ ((c>>1)&3))*8);
      bf16x8 gh = *(const bf16x8*)&Gh[idx];
      bf16x8 gl = *(const bf16x8*)&Gl[idx];
      bf16x8 uh = *(const bf16x8*)&Uh[idx];
      bf16x8 ul = *(const bf16x8*)&Ul[idx];
      #pragma unroll
      for (int fi=0;fi<4;fi++){
        ag[fi][fj] = MFMA_BF16(ah[fi], gh, ag[fi][fj]);
        ag[fi][fj] = MFMA_BF16(ah[fi], gl, ag[fi][fj]);
        ag[fi][fj] = MFMA_BF16(al[fi], gh, ag[fi][fj]);
        au[fi][fj] = MFMA_BF16(ah[fi], uh, au[fi][fj]);
        au[fi][fj] = MFMA_BF16(ah[fi], ul, au[fi][fj]);
        au[fi][fj] = MFMA_BF16(al[fi], uh, au[fi][fj]);
      }
    }
    __syncthreads();
  }
  #pragma unroll
  for (int fi=0;fi<4;fi++){
    #pragma unroll
    for (int fj=0;fj<2;fj++){
      f32x4 vg = ag[fi][fj];
      f32x4 vu = au[fi][fj];
      int cc = col0 + wcol0 + fj*16 + ln15;
      #pragma unroll
      for (int r=0;r<4;r++){
        size_t cix = (size_t)(row0 + wrow0 + fi*16 + lk*4 + r)*ldc + cc;
        float gg = vg[r];
        C[cix] = (gg/(1.0f+expf(-gg))) * vu[r];
      }
    }
  }
}

// ---- NEW fused SwiGLU MFMA: planes in, 512 threads / 8 waves, register prefetch ----
__global__ __launch_bounds__(512) void k_gemm_dual_ps(
    const ushort_t* __restrict__ Ahp, const ushort_t* __restrict__ Alp, int lda,
    const ushort_t* __restrict__ Ghp, const ushort_t* __restrict__ Glp,
    const ushort_t* __restrict__ Uhp, const ushort_t* __restrict__ Ulp, int ldb,
    ushort_t* __restrict__ Chp, ushort_t* __restrict__ Clp, int K, int ldc){
  __shared__ ushort_t Ah[128*32], Al[128*32];
  __shared__ ushort_t Gh[64*32], Gl[64*32], Uh[64*32], Ul[64*32];
  const int tid = threadIdx.x;
  const int row0 = blockIdx.y*128, col0 = blockIdx.x*64;
  const int lane = tid & 63;
  const int ln15 = lane & 15, lk = lane >> 4;
  const int wv = tid >> 6;                       // 0..7
  const int wrow0 = (wv >> 1)*32, wcol0 = (wv & 1)*32;
  const int t8 = tid >> 2, ks4 = tid & 3;
  const int abase = t8*32 + ((ks4 ^ ((t8>>1)&3))*8);
  const size_t gaBase = (size_t)(row0 + t8)*lda + ks4*8;
  const int isU = (tid >= 256);
  const int t2 = tid & 255;
  const int wcolS = t2 >> 2, wksS = t2 & 3;
  const int wsbase = wcolS*32 + ((wksS ^ ((wcolS>>1)&3))*8);
  const ushort_t* Wph = isU ? Uhp : Ghp;
  const ushort_t* Wpl = isU ? Ulp : Glp;
  ushort_t* WsH = isU ? Uh : Gh;
  ushort_t* WsL = isU ? Ul : Gl;
  const size_t gwBase = (size_t)(col0 + wcolS)*ldb + wksS*8;

  f32x4 ag[2][2], au[2][2];
  #pragma unroll
  for (int i=0;i<2;i++)
    #pragma unroll
    for (int j=0;j<2;j++){ f32x4 z = {0.f,0.f,0.f,0.f}; ag[i][j] = z; au[i][j] = z; }

  u32x4 rAh = *(const u32x4*)&Ahp[gaBase];
  u32x4 rAl = *(const u32x4*)&Alp[gaBase];
  u32x4 rWh = *(const u32x4*)&Wph[gwBase];
  u32x4 rWl = *(const u32x4*)&Wpl[gwBase];

  for (int k0 = 0; k0 < K; k0 += 32){
    __syncthreads();
    *(u32x4*)&Ah[abase] = rAh;
    *(u32x4*)&Al[abase] = rAl;
    *(u32x4*)&WsH[wsbase] = rWh;
    *(u32x4*)&WsL[wsbase] = rWl;
    __syncthreads();
    if (k0 + 32 < K){
      rAh = *(const u32x4*)&Ahp[gaBase + k0 + 32];
      rAl = *(const u32x4*)&Alp[gaBase + k0 + 32];
      rWh = *(const u32x4*)&Wph[gwBase + k0 + 32];
      rWl = *(const u32x4*)&Wpl[gwBase + k0 + 32];
    }
    bf16x8 ah[2], al[2];
    #pragma unroll
    for (int fi=0;fi<2;fi++){
      int r = wrow0 + fi*16 + ln15;
      int idx = r*32 + ((lk ^ ((r>>1)&3))*8);
      ah[fi] = *(const bf16x8*)&Ah[idx];
      al[fi] = *(const bf16x8*)&Al[idx];
    }
    #pragma unroll
    for (int fj=0;fj<2;fj++){
      int c = wcol0 + fj*16 + ln15;
      int idx = c*32 + ((lk ^ ((c>>1)&3))*8);
      bf16x8 gh = *(const bf16x8*)&Gh[idx];
      bf16x8 gl = *(const bf16x8*)&Gl[idx];
      bf16x8 uh = *(const bf16x8*)&Uh[idx];
      bf16x8 ul = *(const bf16x8*)&Ul[idx];
      #pragma unroll
      for (int fi=0;fi<2;fi++){
        ag[fi][fj] = MFMA_BF16(ah[fi], gh, ag[fi][fj]);
        ag[fi][fj] = MFMA_BF16(ah[fi], gl, ag[fi][fj]);
        ag[fi][fj] = MFMA_BF16(al[fi], gh, ag[fi][fj]);
        au[fi][fj] = MFMA_BF16(ah[fi], uh, au[fi][fj]);
        au[fi][fj] = MFMA_BF16(ah[fi], ul, au[fi][fj]);
        au[fi][fj] = MFMA_BF16(al[fi], uh, au[fi][fj]);
      }
    }
  }
  #pragma unroll
  for (int fi=0;fi<2;fi++){
    #pragma unroll
    for (int fj=0;fj<2;fj++){
      f32x4 vg = ag[fi][fj];
      f32x4 vu = au[fi][fj];
      int cc = col0 + wcol0 + fj*16 + ln15;
      #pragma unroll
      for (int r=0;r<4;r++){
        size_t cix = (size_t)(row0 + wrow0 + fi*16 + lk*4 + r)*ldc + cc;
        float gg = vg[r];
        float val = (gg/(1.0f+expf(-gg))) * vu[r];
        unsigned int h16,l16; split1(val,&h16,&l16);
        Chp[cix] = (ushort_t)h16;
        Clp[cix] = (ushort_t)l16;
      }
    }
  }
}

// ---------------- prior / gating ----------------
__global__ __launch_bounds__(256) void k_dstch(const float* __restrict__ proc, const float* __restrict__ x0,
                        const float* __restrict__ ml, float* __restrict__ dst, float* __restrict__ dch){
  int tok = blockIdx.x, tid = threadIdx.x;
  const float* pp = proc + (size_t)tok*Ddim;
  const float* xp = x0 + (size_t)tok*Ddim;
  const float* mu = ml + (size_t)tok*2*Ddim;
  const float* lv = mu + Ddim;
  float s1=0.f, s2=0.f;
  for (int i=tid;i<Ddim;i+=256){
    float r = pp[i]-xp[i];
    s1 += r*r;
    float t = r - mu[i];
    float l = lv[i];
    s2 += 0.5f*(l + (1.0f + t*t)*expf(-l) - 1.0f);
  }
  __shared__ float red[256], red2[256];
  red[tid]=s1; red2[tid]=s2; __syncthreads();
  for (int st=128; st>0; st>>=1){ if (tid<st){red[tid]+=red[tid+st]; red2[tid]+=red2[tid+st];} __syncthreads(); }
  if (tid==0){ dst[tok]=red[0]/(float)Ddim; dch[tok]=red2[0]/(float)Ddim; }
}

__global__ __launch_bounds__(256) void k_dstch2(const float* __restrict__ proc, const float* __restrict__ x0,
                        const float* __restrict__ muB, const float* __restrict__ lvB,
                        float* __restrict__ dst, float* __restrict__ dch){
  int tok = blockIdx.x, tid = threadIdx.x;
  const float* pp = proc + (size_t)tok*Ddim;
  const float* xp = x0 + (size_t)tok*Ddim;
  const float* mu = muB + (size_t)tok*Ddim;
  const float* lv = lvB + (size_t)tok*Ddim;
  float s1=0.f, s2=0.f;
  for (int i=tid;i<Ddim;i+=256){
    float r = pp[i]-xp[i];
    s1 += r*r;
    float t = r - mu[i];
    float l = lv[i];
    s2 += 0.5f*(l + (1.0f + t*t)*expf(-l) - 1.0f);
  }
  __shared__ float red[256], red2[256];
  red[tid]=s1; red2[tid]=s2; __syncthreads();
  for (int st=128; st>0; st>>=1){ if (tid<st){red[tid]+=red[tid+st]; red2[tid]+=red2[tid+st];} __syncthreads(); }
  if (tid==0){ dst[tok]=red[0]/(float)Ddim; dch[tok]=red2[0]/(float)Ddim; }
}

__global__ __launch_bounds__(1024) void k_gate(const float* __restrict__ dst, const float* __restrict__ dch,
                        float* __restrict__ g){
  int tid = threadIdx.x;
  float s1=0.f, s2=0.f;
  for (int i=tid; i<Bdim*Tdim; i+=1024){ s1+=dst[i]; s2+=dch[i]; }
  __shared__ float r1[1024], r2[1024];
  r1[tid]=s1; r2[tid]=s2; __syncthreads();
  for (int st=512; st>0; st>>=1){ if(tid<st){r1[tid]+=r1[tid+st]; r2[tid]+=r2[tid+st];} __syncthreads(); }
  float m1 = r1[0]/(float)(Bdim*Tdim), m2 = r2[0]/(float)(Bdim*Tdim);
  for (int i=tid; i<Bdim*Tdim; i+=1024){
    float z = (dst[i]-m1) + (dch[i]-m2);
    g[i] = 1.0f/(1.0f+expf(-z));
  }
}

__global__ __launch_bounds__(1024) void k_select(const float* __restrict__ g, int* __restrict__ selidx,
                         float* __restrict__ selsc){
  int b = blockIdx.x, t = threadIdx.x;
  __shared__ float gs[1024];
  __shared__ int flag[1024];
  float gv = g[b*Tdim + t];
  if (!(gv == gv)) gv = -3.4e38f;
  gs[t] = gv; __syncthreads();
  float gi = gs[t];
  int rank = 0;
  for (int j=0;j<Tdim;j++){
    float gj = gs[j];
    rank += (gj > gi) || (gj == gi && j < t);
  }
  int sel = (rank < KSEL) ? 1 : 0;
  flag[t] = sel; __syncthreads();
  if (sel){
    int pos = 0;
    for (int j=0;j<t;j++) pos += flag[j];
    if (pos < KSEL){
      selidx[b*KSEL+pos] = t;
      selsc[b*KSEL+pos] = gi;
    }
  }
}

__global__ __launch_bounds__(256) void k_gather(const float* __restrict__ proc, const int* __restrict__ selidx,
                         float* __restrict__ sel){
  int j = blockIdx.x, b = blockIdx.y, tid = threadIdx.x;
  int row = clamp_row(selidx[b*KSEL+j]);
  const float* src = proc + ((size_t)b*Tdim + row)*Ddim;
  float* dst = sel + ((size_t)b*KSEL + j)*Ddim;
  for (int d=tid; d<Ddim; d+=256) dst[d]=src[d];
}

__global__ void k_out(const float* __restrict__ proc, float* __restrict__ out, int n){
  int i = blockIdx.x*blockDim.x + threadIdx.x;
  if (i<n) out[i] = proc[i];
}

__global__ __launch_bounds__(256) void k_scatter(const float* __restrict__ sel, const float* __restrict__ y,
                          const float* __restrict__ selsc, const int* __restrict__ selidx,
                          float* __restrict__ out){
  int j = blockIdx.x, b = blockIdx.y, tid = threadIdx.x;
  int row = clamp_row(selidx[b*KSEL+j]);
  float s = selsc[b*KSEL+j];
  const float* sp = sel + ((size_t)b*KSEL + j)*Ddim;
  const float* yp = y + ((size_t)b*KSEL + j)*Ddim;
  float* op = out + ((size_t)b*Tdim + row)*Ddim;
  for (int d=tid; d<Ddim; d+=256){
    op[d] = sp[d] + s*(yp[d]-sp[d]);
  }
}

// ---------------- driver ----------------
extern "C" void kernel_launch(void* const* d_in, const int* in_sizes, int n_in,
                              void* d_out, int out_size, void* d_ws, size_t ws_size,
                              hipStream_t stream){
  (void)in_sizes; (void)n_in; (void)out_size;
  const float* hidden = (const float*)d_in[0];
  const float* wq1 = (const float*)d_in[1];
  const float* wk1 = (const float*)d_in[2];
  const float* wv1 = (const float*)d_in[3];
  const float* wo1 = (const float*)d_in[4];
  const float* wq2 = (const float*)d_in[5];
  const float* wk2 = (const float*)d_in[6];
  const float* wv2 = (const float*)d_in[7];
  const float* wo2 = (const float*)d_in[8];
  const float* wg1 = (const float*)d_in[9];
  const float* wu1 = (const float*)d_in[10];
  const float* wd1 = (const float*)d_in[11];
  const float* wg2 = (const float*)d_in[12];
  const float* wu2 = (const float*)d_in[13];
  const float* wd2 = (const float*)d_in[14];
  const float* ln1_1 = (const float*)d_in[15];
  const float* ln2_1 = (const float*)d_in[16];
  const float* ln1_2 = (const float*)d_in[17];
  const float* ln2_2 = (const float*)d_in[18];
  const float* prior_norm = (const float*)d_in[19];
  const float* prior_w = (const float*)d_in[20];

  const size_t A = (size_t)Bdim*Tdim*Ddim;      // 4M floats
  const size_t Q = (size_t)Bdim*KSEL*Ddim;      // 1M floats
  const int n = (int)A;
  const int MT = Bdim*Tdim;    // 4096
  const int M2 = Bdim*KSEL;    // 1024

  const size_t WELEMS = 34u*1024*1024;          // 34M weight elems -> 68M ushorts
  size_t need_old = (4*A + 16384) * sizeof(float);
  size_t need_new = need_old + 2*WELEMS*sizeof(ushort_t);

  if (ws_size < need_old){
    k_fallback<<<(n+255)/256,256,0,stream>>>(hidden, (float*)d_out, n);
    return;
  }

  float* ws = (float*)d_ws;
  float* R0 = ws;
  float* R1 = ws + 1*A;
  float* R2 = ws + 2*A;
  float* R3 = ws + 3*A;
  float* dstb = ws + 4*A;
  float* dchb = dstb + 4096;
  float* gb   = dchb + 4096;
  float* selsc= gb + 4096;
  int*   selidx = (int*)(selsc + 1024);

  k_init_sel<<<4,256,0,stream>>>(selidx, selsc, Bdim*KSEL);

  if (ws_size >= need_new){
    // ================= NEW PATH: pre-split bf16 planes, fused qkv/prior, defer-max attn =================
    ushort_t* wpb = (ushort_t*)(ws + 4*A + 16384);
    size_t cur = 0;
    const size_t M1x1 = (size_t)1024*1024;
    const size_t M1x4 = (size_t)1024*4096;
    #define ALLOCW(nm, KN) ushort_t* nm##_h = wpb + cur; ushort_t* nm##_l = wpb + cur + (KN); cur += 2*(size_t)(KN);
    ALLOCW(pwq1, M1x1) ALLOCW(pwk1, M1x1) ALLOCW(pwv1, M1x1) ALLOCW(pwo1, M1x1)
    ALLOCW(pwq2, M1x1) ALLOCW(pwk2, M1x1) ALLOCW(pwv2, M1x1) ALLOCW(pwo2, M1x1)
    ALLOCW(pwg1, M1x4) ALLOCW(pwu1, M1x4) ALLOCW(pwd1, M1x4)
    ALLOCW(pwg2, M1x4) ALLOCW(pwu2, M1x4) ALLOCW(pwd2, M1x4)
    ALLOCW(ppw, (size_t)2048*1024)
    #undef ALLOCW

    k_split_w<<<dim3(16,16),256,0,stream>>>(wq1, pwq1_h, pwq1_l, 1024, 1024);
    k_split_w<<<dim3(16,16),256,0,stream>>>(wk1, pwk1_h, pwk1_l, 1024, 1024);
    k_split_w<<<dim3(16,16),256,0,stream>>>(wv1, pwv1_h, pwv1_l, 1024, 1024);
    k_split_w<<<dim3(16,16),256,0,stream>>>(wo1, pwo1_h, pwo1_l, 1024, 1024);
    k_split_w<<<dim3(16,16),256,0,stream>>>(wq2, pwq2_h, pwq2_l, 1024, 1024);
    k_split_w<<<dim3(16,16),256,0,stream>>>(wk2, pwk2_h, pwk2_l, 1024, 1024);
    k_split_w<<<dim3(16,16),256,0,stream>>>(wv2, pwv2_h, pwv2_l, 1024, 1024);
    k_split_w<<<dim3(16,16),256,0,stream>>>(wo2, pwo2_h, pwo2_l, 1024, 1024);
    k_split_w<<<dim3(64,16),256,0,stream>>>(wg1, pwg1_h, pwg1_l, 1024, 4096);
    k_split_w<<<dim3(64,16),256,0,stream>>>(wu1, pwu1_h, pwu1_l, 1024, 4096);
    k_split_w<<<dim3(16,64),256,0,stream>>>(wd1, pwd1_h, pwd1_l, 4096, 1024);
    k_split_w<<<dim3(64,16),256,0,stream>>>(wg2, pwg2_h, pwg2_l, 1024, 4096);
    k_split_w<<<dim3(64,16),256,0,stream>>>(wu2, pwu2_h, pwu2_l, 1024, 4096);
    k_split_w<<<dim3(16,64),256,0,stream>>>(wd2, pwd2_h, pwd2_l, 4096, 1024);
    k_split_w<<<dim3(32,16),256,0,stream>>>(prior_w, ppw_h, ppw_l, 1024, 2048);

    // ---- layer 1 ----
    ushort_t* Hh = (ushort_t*)R0; ushort_t* Hl = Hh + A;
    k_rmsnorm_sp<<<MT,256,0,stream>>>(hidden, ln1_1, Hh, Hl);
    ushort_t* Vp_h = (ushort_t*)R3; ushort_t* Vp_l = Vp_h + A;
    k_gemm_qkv<<<dim3(8, MT/128, 3),512,0,stream>>>(Hh,Hl,1024,
        pwq1_h,pwq1_l, pwk1_h,pwk1_l, pwv1_h,pwv1_l, 1024,
        R1, R2, Vp_h, Vp_l, 1024, 1024);
    int nr = MT*Hdim*32;
    ushort_t* Qp_h = (ushort_t*)R0; ushort_t* Qp_l = Qp_h + A;
    k_rope_sp<<<(nr+255)/256,256,0,stream>>>(R1, nullptr, Tdim, nr, Qp_h, Qp_l);
    ushort_t* Kp_h = (ushort_t*)R1; ushort_t* Kp_l = Kp_h + A;
    k_rope_sp<<<(nr+255)/256,256,0,stream>>>(R2, nullptr, Tdim, nr, Kp_h, Kp_l);
    ushort_t* Op_h = (ushort_t*)R2; ushort_t* Op_l = Op_h + A;
    k_attn_ps<<<dim3(Tdim/64,Hdim,Bdim),256,0,stream>>>(Qp_h,Qp_l, Kp_h,Kp_l, Vp_h,Vp_l, Op_h,Op_l, Tdim);
    k_gemm_ps<<<dim3(8, MT/128),512,0,stream>>>(Op_h,Op_l,1024, pwo1_h,pwo1_l,1024, R1, nullptr,nullptr, hidden, 1024, 1024);
    ushort_t* H2h = (ushort_t*)R0; ushort_t* H2l = H2h + A;
    k_rmsnorm_sp<<<MT,256,0,stream>>>(R1, ln2_1, H2h, H2l);
    ushort_t* ACTh = (ushort_t*)R3; ushort_t* ACTl = ACTh + A;
    for (int c = 0; c < 4; c++){
      k_gemm_dual_ps<<<dim3(16, MT/128),512,0,stream>>>(H2h,H2l,1024,
          pwg1_h + (size_t)c*M1x1, pwg1_l + (size_t)c*M1x1,
          pwu1_h + (size_t)c*M1x1, pwu1_l + (size_t)c*M1x1, 1024,
          ACTh, ACTl, 1024, 1024);
      k_gemm_ps<<<dim3(8, MT/128),512,0,stream>>>(ACTh,ACTl,1024,
          pwd1_h + (size_t)c*1024, pwd1_l + (size_t)c*1024, 4096,
          R2, nullptr,nullptr, (c==0 ? R1 : R2), 1024, 1024);
    }
    // proc = R2

    // ---- prior / gate / select ----
    ushort_t* PHh = (ushort_t*)R0; ushort_t* PHl = PHh + A;
    k_rmsnorm_sp<<<MT,256,0,stream>>>(hidden, prior_norm, PHh, PHl);
    k_gemm_qkv<<<dim3(8, MT/128, 2),512,0,stream>>>(PHh,PHl,1024,
        ppw_h,ppw_l, ppw_h + M1x1, ppw_l + M1x1, nullptr,nullptr, 1024,
        R1, R3, nullptr,nullptr, 1024, 1024);        // mu=R1, logvar=R3
    k_dstch2<<<MT,256,0,stream>>>(R2, hidden, R1, R3, dstb, dchb);
    k_gate<<<1,1024,0,stream>>>(dstb, dchb, gb);
    k_select<<<Bdim,1024,0,stream>>>(gb, selidx, selsc);
    float* SELX = R0;
    k_gather<<<dim3(KSEL,Bdim),256,0,stream>>>(R2, selidx, SELX);

    // ---- layer 2 ----
    ushort_t* h2h = (ushort_t*)R1;        ushort_t* h2l = h2h + Q;
    k_rmsnorm_sp<<<M2,256,0,stream>>>(SELX, ln1_2, h2h, h2l);
    float* q2f = R1 + Q;
    float* k2f = R1 + 2*Q;
    ushort_t* v2h = (ushort_t*)(R1 + 3*Q); ushort_t* v2l = v2h + Q;
    k_gemm_qkv<<<dim3(8, M2/128, 3),512,0,stream>>>(h2h,h2l,1024,
        pwq2_h,pwq2_l, pwk2_h,pwk2_l, pwv2_h,pwv2_l, 1024,
        q2f, k2f, v2h, v2l, 1024, 1024);
    int nr2 = M2*Hdim*32;
    ushort_t* q2ph = (ushort_t*)(R0 + Q);   ushort_t* q2pl = q2ph + Q;
    ushort_t* k2ph = (ushort_t*)(R0 + 2*Q); ushort_t* k2pl = k2ph + Q;
    k_rope_sp<<<(nr2+255)/256,256,0,stream>>>(q2f, selidx, KSEL, nr2, q2ph, q2pl);
    k_rope_sp<<<(nr2+255)/256,256,0,stream>>>(k2f, selidx, KSEL, nr2, k2ph, k2pl);
    ushort_t* o2h = (ushort_t*)(R0 + 3*Q);  ushort_t* o2l = o2h + Q;
    k_attn_ps<<<dim3(KSEL/64,Hdim,Bdim),256,0,stream>>>(q2ph,q2pl, k2ph,k2pl, v2h,v2l, o2h,o2l, KSEL);
    float* X12 = R1 + Q;
    k_gemm_ps<<<dim3(8, M2/128),512,0,stream>>>(o2h,o2l,1024, pwo2_h,pwo2_l,1024, X12, nullptr,nullptr, SELX, 1024, 1024);
    ushort_t* h22h = (ushort_t*)(R1 + 2*Q); ushort_t* h22l = h22h + Q;
    k_rmsnorm_sp<<<M2,256,0,stream>>>(X12, ln2_2, h22h, h22l);
    ushort_t* act2h = (ushort_t*)(R1 + 3*Q); ushort_t* act2l = act2h + Q;
    float* Y = R3;
    for (int c = 0; c < 4; c++){
      k_gemm_dual_ps<<<dim3(16, M2/128),512,0,stream>>>(h22h,h22l,1024,
          pwg2_h + (size_t)c*M1x1, pwg2_l + (size_t)c*M1x1,
          pwu2_h + (size_t)c*M1x1, pwu2_l + (size_t)c*M1x1, 1024,
          act2h, act2l, 1024, 1024);
      k_gemm_ps<<<dim3(8, M2/128),512,0,stream>>>(act2h,act2l,1024,
          pwd2_h + (size_t)c*1024, pwd2_l + (size_t)c*1024, 4096,
          Y, nullptr,nullptr, (c==0 ? X12 : Y), 1024, 1024);
    }
    // ---- output ----
    k_out<<<(n+255)/256,256,0,stream>>>(R2, (float*)d_out, n);
    k_scatter<<<dim3(KSEL,Bdim),256,0,stream>>>(SELX, Y, selsc, selidx, (float*)d_out);
    return;
  }

  // ================= OLD PATH (round-3, verified) =================
  k_rmsnorm<<<MT,256,0,stream>>>(hidden, ln1_1, R0);
  dim3 gD(Ddim/128, MT/128);
  k_gemm_mfma<<<gD,256,0,stream>>>(R0, wq1, R1, nullptr, Ddim, Ddim, Ddim);
  k_gemm_mfma<<<gD,256,0,stream>>>(R0, wk1, R2, nullptr, Ddim, Ddim, Ddim);
  k_gemm_mfma<<<gD,256,0,stream>>>(R0, wv1, R3, nullptr, Ddim, Ddim, Ddim);
  int nr = MT*Hdim*32;
  k_rope<<<(nr+255)/256,256,0,stream>>>(R1, nullptr, Tdim, nr);
  k_rope<<<(nr+255)/256,256,0,stream>>>(R2, nullptr, Tdim, nr);
  k_attn_mfma<<<dim3(Tdim/64,Hdim,Bdim),256,0,stream>>>(R1, R2, R3, R0, Tdim);
  k_gemm_mfma<<<gD,256,0,stream>>>(R0, wo1, R1, hidden, Ddim, Ddim, Ddim);
  k_rmsnorm<<<MT,256,0,stream>>>(R1, ln2_1, R2);
  for (int c = 0; c < 4; c++){
    k_gemm_dual_mfma<<<dim3(1024/64, MT/128),256,0,stream>>>(R2, wg1 + (size_t)c*1024, wu1 + (size_t)c*1024,
                                                  R3, Ddim, FFNdim, 1024);
    k_gemm_mfma<<<dim3(Ddim/128, MT/128),256,0,stream>>>(R3, wd1 + (size_t)c*1024*Ddim, R0,
                                             (c==0 ? R1 : R0), 1024, Ddim, Ddim);
  }
  k_rmsnorm<<<MT,256,0,stream>>>(hidden, prior_norm, R1);
  k_gemm_mfma<<<dim3(2*Ddim/128, MT/128),256,0,stream>>>(R1, prior_w, R2, nullptr, Ddim, 2*Ddim, 2*Ddim);
  k_dstch<<<MT,256,0,stream>>>(R0, hidden, R2, dstb, dchb);
  k_gate<<<1,1024,0,stream>>>(dstb, dchb, gb);
  k_select<<<Bdim,1024,0,stream>>>(gb, selidx, selsc);
  k_gather<<<dim3(KSEL,Bdim),256,0,stream>>>(R0, selidx, R1);
  k_rmsnorm<<<M2,256,0,stream>>>(R1, ln1_2, R2);
  dim3 gD2(Ddim/128, M2/128);
  k_gemm_mfma<<<gD2,256,0,stream>>>(R2, wq2, R2+Q,   nullptr, Ddim, Ddim, Ddim);
  k_gemm_mfma<<<gD2,256,0,stream>>>(R2, wk2, R2+2*Q, nullptr, Ddim, Ddim, Ddim);
  k_gemm_mfma<<<gD2,256,0,stream>>>(R2, wv2, R2+3*Q, nullptr, Ddim, Ddim, Ddim);
  int nr2 = M2*Hdim*32;
  k_rope<<<(nr2+255)/256,256,0,stream>>>(R2+Q,   nullptr, KSEL, nr2);
  k_rope<<<(nr2+255)/256,256,0,stream>>>(R2+2*Q, nullptr, KSEL, nr2);
  k_rope<<<(nr2+255)/256,256,0,stream>>>(R2+Q,   selidx, KSEL, 0);   // no-op guard
  k_attn_mfma<<<dim3(KSEL/64,Hdim,Bdim),256,0,stream>>>(R2+Q, R2+2*Q, R2+3*Q, R3, KSEL);
  k_gemm_mfma<<<gD2,256,0,stream>>>(R3, wo2, R3+Q, R1, Ddim, Ddim, Ddim);
  k_rmsnorm<<<M2,256,0,stream>>>(R3+Q, ln2_2, R3+2*Q);
  for (int c = 0; c < 4; c++){
    k_gemm_dual_mfma<<<dim3(1024/64, M2/128),256,0,stream>>>(R3+2*Q, wg2 + (size_t)c*1024, wu2 + (size_t)c*1024,
                                                  R3+3*Q, Ddim, FFNdim, 1024);
    k_gemm_mfma<<<dim3(Ddim/128, M2/128),256,0,stream>>>(R3+3*Q, wd2 + (size_t)c*1024*Ddim, R2,
                                             (c==0 ? R3+Q : R2), 1024, Ddim, Ddim);
  }
  k_out<<<(n+255)/256,256,0,stream>>>(R0, (float*)d_out, n);
  k_scatter<<<dim3(KSEL,Bdim),256,0,stream>>>(R1, R2, selsc, selidx, (float*)d_out);
}